// Round 1
// baseline (2303.966 us; speedup 1.0000x reference)
//
#include <hip/hip_runtime.h>
#include <hip/hip_bf16.h>
#include <math.h>

typedef __hip_bfloat16 bf16;

// ---------------- problem constants ----------------
#define B2   2
#define C64  64
#define C3   192
#define HEADS 6
#define DH   32
#define NWIN 2048   // 2 * 32 * 32 windows
#define XW_S 194    // padded LDS stride for 192-wide rows (bf16)
#define QK_S 33     // padded LDS stride for 32-wide rows (f32)
#define SC_S 66     // padded LDS stride for 64-wide rows (bf16)

// ---------------- param table offsets (floats) ----------------
#define P_NORMW 0
#define P_NORMB 192
#define P_QKVW  384
#define P_QKVB  110976
#define P_PROJW 111552
#define P_PROJB 148416
#define P_RPB   148608
#define P_AUXDW 149958
#define P_AUXPW 150534
#define P_CG1   154630
#define P_CG2   157702
#define P_PO    166918
#define P_GM    171014
#define P_GA    171015
#define P_GC    171016

// ---------------- workspace byte offsets ----------------
#define WS_FLAG   0
#define WS_PARAMS 256
#define WS_GAP    684544
#define WS_AMUL   685568
#define WS_CVAL   687616
#define WS_LL     689664
#define WS_DLL    (WS_LL   + 33554432)   // f32 [2][64][256][256]
#define WS_WOUT   (WS_DLL  + 33554432)   // bf16 [2048][64][192]
#define WS_DHIGH  (WS_WOUT + 50331648)   // bf16 [2][192][256][256]

// ---------------- helpers ----------------
template<bool ISF>
__device__ __forceinline__ float LD(const void* p, long i){
  if constexpr (ISF) return ((const float*)p)[i];
  else return __bfloat162float(((const bf16*)p)[i]);
}
template<bool ISF>
__device__ __forceinline__ void ST(void* p, long i, float v){
  if constexpr (ISF) ((float*)p)[i] = v;
  else ((bf16*)p)[i] = __float2bfloat16(v);
}
__device__ __forceinline__ float gelu_f(float x){
  return 0.5f * x * (1.f + erff(x * 0.70710678118654752f));
}

// ---------------- K0a: dtype detect ----------------
__global__ __launch_bounds__(256) void detect_kernel(const void* x, int* flag){
  __shared__ int wildcnt;
  if (threadIdx.x == 0) wildcnt = 0;
  __syncthreads();
  const unsigned short* u = (const unsigned short*)x;
  int wild = 0;
  for (int i = threadIdx.x; i < 2048; i += 256){
    unsigned int v = ((unsigned int)u[i]) << 16;
    float f = __uint_as_float(v);
    float a = fabsf(f);
    if (!(a < 1e8f) || (a > 0.f && a < 1e-8f)) wild++;
  }
  atomicAdd(&wildcnt, wild);
  __syncthreads();
  if (threadIdx.x == 0) *flag = (wildcnt > 100) ? 1 : 0;  // 1 = fp32 underlying
}

// ---------------- K0b: param convert ----------------
struct PP { const void* src[15]; float* dst[15]; int n[15]; };
__global__ __launch_bounds__(256) void convert_params(PP pp, const int* flag){
  const int id = blockIdx.x;
  const int n = pp.n[id];
  const void* s = pp.src[id];
  float* d = pp.dst[id];
  const bool isf = (*flag) != 0;
  for (int i = threadIdx.x; i < n; i += 256)
    d[i] = isf ? ((const float*)s)[i] : __bfloat162float(((const bf16*)s)[i]);
}

// ---------------- K1: DWT -> ll ----------------
template<bool ISF>
__device__ void k1_body(const void* xv, float* ll){
  const long total = (long)B2 * C64 * 256 * 256;
  for (long idx = (long)blockIdx.x * blockDim.x + threadIdx.x; idx < total;
       idx += (long)gridDim.x * blockDim.x){
    const int w2 = (int)(idx & 255);
    long r = idx >> 8;
    const int h2 = (int)(r & 255);
    const long plane = r >> 8;                         // b*64+c
    const long base = (plane << 18) + ((long)(2*h2) << 9) + 2*w2;
    const float a  = LD<ISF>(xv, base);
    const float bb = LD<ISF>(xv, base + 512);
    const float cr = LD<ISF>(xv, base + 1);
    const float dd = LD<ISF>(xv, base + 513);
    ll[idx] = 0.5f * (a + bb + cr + dd);
  }
}
__global__ __launch_bounds__(256) void k1_dwt(const void* xv, float* ll, const int* flag){
  if (*flag) k1_body<true>(xv, ll); else k1_body<false>(xv, ll);
}

// ---------------- K2: gap ----------------
__global__ __launch_bounds__(256) void k2_gap(const float* ll, float* gap){
  const int bc = blockIdx.x;                            // 0..127
  const float* p = ll + ((long)bc << 16);
  float s = 0.f;
  for (int i = threadIdx.x; i < 65536; i += 256) s += p[i];
  __shared__ float red[256];
  red[threadIdx.x] = s; __syncthreads();
  for (int st = 128; st > 0; st >>= 1){
    if (threadIdx.x < st) red[threadIdx.x] += red[threadIdx.x + st];
    __syncthreads();
  }
  if (threadIdx.x == 0) gap[bc] = red[0] * (1.f / 65536.f);
}

// ---------------- K3: cross MLP ----------------
__global__ __launch_bounds__(256) void k3_cross(const float* pf, const float* gap,
                                                float* amul, float* cval){
  __shared__ float t1[B2][48];
  __shared__ float g[B2][64];
  const int tid = threadIdx.x;
  if (tid < 128) g[tid >> 6][tid & 63] = gap[tid];
  __syncthreads();
  if (tid < 96){
    const int b = tid / 48, j = tid % 48;
    float s = 0.f;
    const float* w = pf + P_CG1 + j * 64;
    for (int c = 0; c < 64; ++c) s += w[c] * g[b][c];
    t1[b][j] = gelu_f(s);
  }
  __syncthreads();
  const float gm = pf[P_GM], gc = pf[P_GC];
  for (int o = tid; o < B2 * C3; o += 256){
    const int b = o / C3, ch = o % C3;
    float s = 0.f;
    const float* w = pf + P_CG2 + ch * 48;
    for (int j = 0; j < 48; ++j) s += w[j] * t1[b][j];
    const float cr = 1.f / (1.f + expf(-s));
    const float c = gc * (cr - 0.5f) * 2.f;
    cval[o] = c;
    amul[o] = gm * (1.f + c);
  }
}

// ---------------- K4: fused window attention ----------------
template<bool ISF>
__device__ void k4_body(const void* xv, const float* pf, const int* rpi, bf16* wout,
                        bf16* xw, float* qkv, bf16* sc){
  const int wid = blockIdx.x;
  const int b  = wid >> 10;
  const int wh = (wid >> 5) & 31;
  const int ww = wid & 31;
  const int tid = threadIdx.x;
  const int tk = tid >> 2;     // token 0..63
  const int l4 = tid & 3;

  // stage 1: DWT-high + LayerNorm -> xw
  {
    const int i = tk >> 3, j = tk & 7;
    const int h2 = (wh*8 + i + 4) & 255;
    const int w2 = (ww*8 + j + 4) & 255;
    const long pixbase = ((long)(2*h2) << 9) + 2*w2;
    float raw0[16], raw1[16], raw2[16];
    float sum = 0.f, sumsq = 0.f;
#pragma unroll
    for (int cc = 0; cc < 16; ++cc){
      const int c = l4*16 + cc;
      const long base = ((long)(b*64 + c) << 18) + pixbase;
      const float a  = LD<ISF>(xv, base);
      const float bb = LD<ISF>(xv, base + 512);
      const float cr = LD<ISF>(xv, base + 1);
      const float dd = LD<ISF>(xv, base + 513);
      const float h0 = 0.5f*(-a - bb + cr + dd);
      const float h1 = 0.5f*(-a + bb - cr + dd);
      const float hh = 0.5f*( a - bb - cr + dd);
      raw0[cc] = h0; raw1[cc] = h1; raw2[cc] = hh;
      sum += h0 + h1 + hh;
      sumsq += h0*h0 + h1*h1 + hh*hh;
    }
    sum   += __shfl_xor(sum, 1, 4);   sum   += __shfl_xor(sum, 2, 4);
    sumsq += __shfl_xor(sumsq, 1, 4); sumsq += __shfl_xor(sumsq, 2, 4);
    const float mean = sum * (1.f / 192.f);
    float var = sumsq * (1.f / 192.f) - mean * mean;
    var = fmaxf(var, 0.f);
    const float rstd = rsqrtf(var + 1e-6f);
#pragma unroll
    for (int cc = 0; cc < 16; ++cc){
      const int c = l4*16 + cc;
      xw[tk*XW_S + c]       = __float2bfloat16((raw0[cc]-mean)*rstd*pf[P_NORMW+c]     + pf[P_NORMB+c]);
      xw[tk*XW_S + 64 + c]  = __float2bfloat16((raw1[cc]-mean)*rstd*pf[P_NORMW+64+c]  + pf[P_NORMB+64+c]);
      xw[tk*XW_S + 128 + c] = __float2bfloat16((raw2[cc]-mean)*rstd*pf[P_NORMW+128+c] + pf[P_NORMB+128+c]);
    }
  }
  __syncthreads();

  const float scale = 0.17677669529663687f;
  for (int h = 0; h < HEADS; ++h){
    // stage 2: q,k,v for this head
    {
      const int dblk = tid >> 4, tblk = tid & 15;
      const int t0 = tblk * 4;
      float acc[4][6];
#pragma unroll
      for (int a1 = 0; a1 < 4; a1++)
#pragma unroll
        for (int a2 = 0; a2 < 6; a2++) acc[a1][a2] = 0.f;
      const float* wr[6];
#pragma unroll
      for (int kk = 0; kk < 6; kk++){
        const int col = dblk*6 + kk;
        const int mat = col >> 5, d = col & 31;
        wr[kk] = pf + P_QKVW + (long)(mat*192 + h*32 + d) * 192;
      }
      for (int ch = 0; ch < 192; ++ch){
        float xvv[4];
#pragma unroll
        for (int a1 = 0; a1 < 4; a1++) xvv[a1] = __bfloat162float(xw[(t0+a1)*XW_S + ch]);
#pragma unroll
        for (int kk = 0; kk < 6; kk++){
          const float wv = wr[kk][ch];
#pragma unroll
          for (int a1 = 0; a1 < 4; a1++) acc[a1][kk] += xvv[a1] * wv;
        }
      }
#pragma unroll
      for (int kk = 0; kk < 6; kk++){
        const int col = dblk*6 + kk;
        const int mat = col >> 5, d = col & 31;
        const float bias = pf[P_QKVB + mat*192 + h*32 + d];
#pragma unroll
        for (int a1 = 0; a1 < 4; a1++)
          qkv[(mat*64 + t0 + a1)*QK_S + d] = acc[a1][kk] + bias;
      }
    }
    __syncthreads();
    // stage 3: scores + relative position bias
    {
      const int nblk = tid >> 4, mblk = tid & 15;
      const int n0 = nblk*4, m0 = mblk*4;
      float acc[4][4];
#pragma unroll
      for (int a1 = 0; a1 < 4; a1++)
#pragma unroll
        for (int a2 = 0; a2 < 4; a2++) acc[a1][a2] = 0.f;
      for (int d = 0; d < 32; ++d){
        float qv[4], kv[4];
#pragma unroll
        for (int a1 = 0; a1 < 4; a1++) qv[a1] = qkv[(n0+a1)*QK_S + d];
#pragma unroll
        for (int a2 = 0; a2 < 4; a2++) kv[a2] = qkv[(64 + m0+a2)*QK_S + d];
#pragma unroll
        for (int a1 = 0; a1 < 4; a1++)
#pragma unroll
          for (int a2 = 0; a2 < 4; a2++) acc[a1][a2] += qv[a1] * kv[a2];
      }
#pragma unroll
      for (int a1 = 0; a1 < 4; a1++)
#pragma unroll
        for (int a2 = 0; a2 < 4; a2++){
          const int n = n0+a1, m = m0+a2;
          const int idx = rpi[n*64 + m];
          sc[n*SC_S + m] = __float2bfloat16(acc[a1][a2]*scale + pf[P_RPB + idx*6 + h]);
        }
    }
    __syncthreads();
    // stage 4: softmax per row
    {
      float vals[16];
      float mx = -1e30f;
#pragma unroll
      for (int q = 0; q < 16; q++){
        vals[q] = __bfloat162float(sc[tk*SC_S + l4*16 + q]);
        mx = fmaxf(mx, vals[q]);
      }
      mx = fmaxf(mx, __shfl_xor(mx, 1, 4));
      mx = fmaxf(mx, __shfl_xor(mx, 2, 4));
      float s = 0.f;
#pragma unroll
      for (int q = 0; q < 16; q++){ vals[q] = expf(vals[q] - mx); s += vals[q]; }
      s += __shfl_xor(s, 1, 4);
      s += __shfl_xor(s, 2, 4);
      const float inv = 1.f / s;
#pragma unroll
      for (int q = 0; q < 16; q++)
        sc[tk*SC_S + l4*16 + q] = __float2bfloat16(vals[q] * inv);
    }
    __syncthreads();
    // stage 5: out = P @ V -> wout
    {
      const int d0 = l4 * 8;
      float acc[8];
#pragma unroll
      for (int q = 0; q < 8; q++) acc[q] = 0.f;
      for (int m = 0; m < 64; ++m){
        const float sv = __bfloat162float(sc[tk*SC_S + m]);
#pragma unroll
        for (int q = 0; q < 8; q++) acc[q] += sv * qkv[(128 + m)*QK_S + d0 + q];
      }
      const long ob = ((long)wid*64 + tk)*192 + h*32 + d0;
#pragma unroll
      for (int q = 0; q < 8; q++) wout[ob + q] = __float2bfloat16(acc[q]);
    }
    __syncthreads();
  }
}
__global__ __launch_bounds__(256) void k4_attn(const void* xv, const float* pf, const int* rpi,
                                               bf16* wout, const int* flag){
  __shared__ bf16 xw[64 * XW_S];
  __shared__ float qkv[3 * 64 * QK_S];
  __shared__ bf16 sc[64 * SC_S];
  if (*flag) k4_body<true>(xv, pf, rpi, wout, xw, qkv, sc);
  else       k4_body<false>(xv, pf, rpi, wout, xw, qkv, sc);
}

// ---------------- K5: projection + combine -> dhigh ----------------
template<bool ISF>
__device__ void k5_body(const void* xv, const float* pf, const bf16* wout,
                        const float* amul, const float* cval, bf16* dhigh, bf16* wl){
  const int wid = blockIdx.x;
  const int b  = wid >> 10;
  const int wh = (wid >> 5) & 31;
  const int ww = wid & 31;
  const int tid = threadIdx.x;
  {
    const bf16* src = wout + (long)wid * 64 * 192;
    for (int idx = tid; idx < 64*192; idx += 256)
      wl[(idx/192)*XW_S + (idx%192)] = src[idx];
  }
  __syncthreads();
  const int chblk = tid >> 4, tblk = tid & 15;
  const int t0 = tblk*4, ch0 = chblk*12;
  float acc[4][12];
#pragma unroll
  for (int a1 = 0; a1 < 4; a1++)
#pragma unroll
    for (int kk = 0; kk < 12; kk++) acc[a1][kk] = 0.f;
  for (int ck = 0; ck < 192; ++ck){
    float xvv[4];
#pragma unroll
    for (int a1 = 0; a1 < 4; a1++) xvv[a1] = __bfloat162float(wl[(t0+a1)*XW_S + ck]);
#pragma unroll
    for (int kk = 0; kk < 12; kk++){
      const float wv = pf[P_PROJW + (long)(ch0+kk)*192 + ck];
#pragma unroll
      for (int a1 = 0; a1 < 4; a1++) acc[a1][kk] += xvv[a1] * wv;
    }
  }
#pragma unroll
  for (int a1 = 0; a1 < 4; a1++){
    const int t = t0 + a1;
    const int i = t >> 3, j = t & 7;
    const int h2 = (wh*8 + i + 4) & 255;
    const int w2 = (ww*8 + j + 4) & 255;
    const long pixbase = ((long)(2*h2) << 9) + 2*w2;
    const long opix = ((long)h2 << 8) + w2;
#pragma unroll
    for (int kk = 0; kk < 12; kk++){
      const int ch = ch0 + kk;
      const int band = ch >> 6, c = ch & 63;
      const long base = ((long)(b*64 + c) << 18) + pixbase;
      const float a  = LD<ISF>(xv, base);
      const float bb = LD<ISF>(xv, base + 512);
      const float cr = LD<ISF>(xv, base + 1);
      const float dd = LD<ISF>(xv, base + 513);
      float hv;
      if (band == 0)      hv = 0.5f*(-a - bb + cr + dd);
      else if (band == 1) hv = 0.5f*(-a + bb - cr + dd);
      else                hv = 0.5f*( a - bb - cr + dd);
      const float mh = acc[a1][kk] + pf[P_PROJB + ch];
      const int bc = b*192 + ch;
      dhigh[((long)bc << 16) + opix] = __float2bfloat16(amul[bc]*mh + cval[bc]*hv);
    }
  }
}
__global__ __launch_bounds__(256) void k5_proj(const void* xv, const float* pf, const bf16* wout,
                                               const float* amul, const float* cval,
                                               bf16* dhigh, const int* flag){
  __shared__ bf16 wl[64 * XW_S];
  if (*flag) k5_body<true>(xv, pf, wout, amul, cval, dhigh, wl);
  else       k5_body<false>(xv, pf, wout, amul, cval, dhigh, wl);
}

// ---------------- K6a: depthwise 3x3 + gelu ----------------
__global__ __launch_bounds__(256) void k6a_dw(const float* ll, const float* pf, float* tb){
  const long total = (long)B2 * C64 * 256 * 256;
  for (long idx = (long)blockIdx.x * blockDim.x + threadIdx.x; idx < total;
       idx += (long)gridDim.x * blockDim.x){
    const int w2 = (int)(idx & 255);
    long r = idx >> 8;
    const int h2 = (int)(r & 255);
    r >>= 8;                                 // plane = b*64+c
    const int c = (int)(r & 63);
    const float* wk = pf + P_AUXDW + c*9;
    const long pb = r << 16;
    float s = 0.f;
#pragma unroll
    for (int ky = 0; ky < 3; ky++){
      const int y = h2 + ky - 1;
      if (y < 0 || y > 255) continue;
#pragma unroll
      for (int kx = 0; kx < 3; kx++){
        const int xx = w2 + kx - 1;
        if (xx < 0 || xx > 255) continue;
        s += wk[ky*3 + kx] * ll[pb + ((long)y << 8) + xx];
      }
    }
    tb[idx] = gelu_f(s);
  }
}

// ---------------- K6b: 1x1 conv in-place (t -> dll) ----------------
__global__ __launch_bounds__(256) void k6b_pw(float* tb, const float* pf){
  __shared__ float tin[64][65];
  const int tid = threadIdx.x;
  const int pixl = tid & 63, cgrp = tid >> 6;
  const long p = (long)blockIdx.x * 64 + pixl;
  const long b = p >> 16;
  const long within = p & 65535;
#pragma unroll
  for (int cc = 0; cc < 16; ++cc){
    const int c = cgrp*16 + cc;
    tin[c][pixl] = tb[((b*64 + c) << 16) + within];
  }
  __syncthreads();
  const float ga = pf[P_GA];
  const int o0 = cgrp * 16;
  float acc[16];
#pragma unroll
  for (int q = 0; q < 16; q++) acc[q] = 0.f;
  for (int c = 0; c < 64; ++c){
    const float tv = tin[c][pixl];
#pragma unroll
    for (int q = 0; q < 16; q++) acc[q] += pf[P_AUXPW + (o0+q)*64 + c] * tv;
  }
#pragma unroll
  for (int q = 0; q < 16; q++)
    tb[((b*64 + o0 + q) << 16) + within] = ga * acc[q];
}

// ---------------- K7: IWT + output 1x1 conv ----------------
template<bool ISF>
__device__ void k7_body(const float* dll, const bf16* dhigh, const float* pf, void* out, bf16* y){
  const int tid = threadIdx.x;
  const int pixl = tid & 63, cgrp = tid >> 6;
  const long p = (long)blockIdx.x * 64 + pixl;
  const long b = p >> 16;
  const long within = p & 65535;
#pragma unroll
  for (int cc = 0; cc < 16; ++cc){
    const int c = cgrp*16 + cc;
    const float dl = dll[((b*64 + c) << 16) + within];
    const float hl = __bfloat162float(dhigh[((b*192 + c)       << 16) + within]);
    const float lh = __bfloat162float(dhigh[((b*192 + 64 + c)  << 16) + within]);
    const float hh = __bfloat162float(dhigh[((b*192 + 128 + c) << 16) + within]);
    y[(0*64 + c)*66 + pixl] = __float2bfloat16(0.5f*(dl - hl - lh + hh));
    y[(1*64 + c)*66 + pixl] = __float2bfloat16(0.5f*(dl - hl + lh - hh));
    y[(2*64 + c)*66 + pixl] = __float2bfloat16(0.5f*(dl + hl - lh - hh));
    y[(3*64 + c)*66 + pixl] = __float2bfloat16(0.5f*(dl + hl + lh + hh));
  }
  __syncthreads();
  const int h2 = (int)(within >> 8), w2 = (int)(within & 255);
  const int o0 = cgrp * 16;
  float acc[4][16];
#pragma unroll
  for (int pos = 0; pos < 4; pos++)
#pragma unroll
    for (int q = 0; q < 16; q++) acc[pos][q] = 0.f;
  for (int c = 0; c < 64; ++c){
    float yv[4];
#pragma unroll
    for (int pos = 0; pos < 4; pos++) yv[pos] = __bfloat162float(y[(pos*64 + c)*66 + pixl]);
#pragma unroll
    for (int q = 0; q < 16; q++){
      const float wv = pf[P_PO + (o0+q)*64 + c];
#pragma unroll
      for (int pos = 0; pos < 4; pos++) acc[pos][q] += wv * yv[pos];
    }
  }
#pragma unroll
  for (int q = 0; q < 16; q++){
    const int o = o0 + q;
    const long ob = ((b*64 + o)*512L + 2*h2)*512 + 2*w2;
    ST<ISF>(out, ob,       acc[0][q]);
    ST<ISF>(out, ob + 512, acc[1][q]);
    ST<ISF>(out, ob + 1,   acc[2][q]);
    ST<ISF>(out, ob + 513, acc[3][q]);
  }
}
__global__ __launch_bounds__(256) void k7_iwt(const float* dll, const bf16* dhigh,
                                              const float* pf, void* out, const int* flag){
  __shared__ bf16 y[4 * 64 * 66];
  if (*flag) k7_body<true>(dll, dhigh, pf, out, y);
  else       k7_body<false>(dll, dhigh, pf, out, y);
}

// ---------------- launcher ----------------
extern "C" void kernel_launch(void* const* d_in, const int* in_sizes, int n_in,
                              void* d_out, int out_size, void* d_ws, size_t ws_size,
                              hipStream_t stream){
  char* ws = (char*)d_ws;
  int*   flag = (int*)(ws + WS_FLAG);
  float* pf   = (float*)(ws + WS_PARAMS);
  float* gap  = (float*)(ws + WS_GAP);
  float* amul = (float*)(ws + WS_AMUL);
  float* cval = (float*)(ws + WS_CVAL);
  float* ll   = (float*)(ws + WS_LL);
  float* dll  = (float*)(ws + WS_DLL);
  bf16*  wout = (bf16*)(ws + WS_WOUT);
  bf16*  dhigh= (bf16*)(ws + WS_DHIGH);
  const int* rpi = (const int*)d_in[16];

  detect_kernel<<<1, 256, 0, stream>>>(d_in[0], flag);

  PP pp;
  const int pidx[15] = {1,2,3,4,5,6,7,8,9,10,11,12,13,14,15};
  const int poff[15] = {P_NORMW,P_NORMB,P_QKVW,P_QKVB,P_PROJW,P_PROJB,P_RPB,
                        P_AUXDW,P_AUXPW,P_CG1,P_CG2,P_PO,P_GM,P_GA,P_GC};
  for (int q = 0; q < 15; q++){
    pp.src[q] = d_in[pidx[q]];
    pp.dst[q] = pf + poff[q];
    pp.n[q]   = in_sizes[pidx[q]];
  }
  convert_params<<<15, 256, 0, stream>>>(pp, flag);

  k1_dwt <<<4096, 256, 0, stream>>>(d_in[0], ll, flag);
  k2_gap <<<128,  256, 0, stream>>>(ll, gap);
  k3_cross<<<1,   256, 0, stream>>>(pf, gap, amul, cval);
  k4_attn<<<NWIN, 256, 0, stream>>>(d_in[0], pf, rpi, wout, flag);
  k5_proj<<<NWIN, 256, 0, stream>>>(d_in[0], pf, wout, amul, cval, dhigh, flag);
  k6a_dw <<<4096, 256, 0, stream>>>(ll, pf, dll);
  k6b_pw <<<2048, 256, 0, stream>>>(dll, pf);
  k7_iwt <<<2048, 256, 0, stream>>>(dll, dhigh, pf, d_out, flag);
}

// Round 2
// 1543.541 us; speedup vs baseline: 1.4927x; 1.4927x over previous
//
#include <hip/hip_runtime.h>
#include <hip/hip_bf16.h>
#include <math.h>

typedef __hip_bfloat16 bf16;

// ---------------- problem constants ----------------
#define B2   2
#define C64  64
#define C3   192
#define HEADS 6
#define DH   32
#define NWIN 2048   // 2 * 32 * 32 windows
#define XW_S 194    // k4 LDS stride (bf16 elems) for 192-wide rows
#define XW5  196    // k5 LDS stride (8B-aligned rows for uint2 staging)
#define QK_S 33     // padded LDS stride for 32-wide rows (f32)
#define SC_S 66     // padded LDS stride for 64-wide rows (bf16)

// ---------------- param table offsets (floats) ----------------
#define P_NORMW 0
#define P_NORMB 192
#define P_QKVW  384
#define P_QKVB  110976
#define P_PROJW 111552
#define P_PROJB 148416
#define P_RPB   148608
#define P_AUXDW 149958
#define P_AUXPW 150534
#define P_CG1   154630
#define P_CG2   157702
#define P_PO    166918
#define P_GM    171014
#define P_GA    171015
#define P_GC    171016

// ---------------- workspace byte offsets ----------------
#define WS_FLAG   0
#define WS_PARAMS 256
#define WS_GAP    684544
#define WS_AMUL   685568
#define WS_CVAL   687616
#define WS_LL     689664
#define WS_DLL    (WS_LL   + 33554432)   // f32 [2][64][256][256]
#define WS_WOUT   (WS_DLL  + 33554432)   // bf16 [2048][64][192]
#define WS_HWIN   (WS_WOUT + 50331648)   // bf16 [2048][64][192]

// ---------------- helpers ----------------
template<bool ISF>
__device__ __forceinline__ float LD(const void* p, long i){
  if constexpr (ISF) return ((const float*)p)[i];
  else return __bfloat162float(((const bf16*)p)[i]);
}
template<bool ISF>
__device__ __forceinline__ void ST(void* p, long i, float v){
  if constexpr (ISF) ((float*)p)[i] = v;
  else ((bf16*)p)[i] = __float2bfloat16(v);
}
__device__ __forceinline__ float gelu_f(float x){
  return 0.5f * x * (1.f + erff(x * 0.70710678118654752f));
}
__device__ __forceinline__ unsigned pk2(float a, float b){
  return (unsigned)__bfloat16_as_ushort(__float2bfloat16(a)) |
         ((unsigned)__bfloat16_as_ushort(__float2bfloat16(b)) << 16);
}
__device__ __forceinline__ uint4 pk8(const float* v){
  uint4 r;
  r.x = pk2(v[0], v[1]); r.y = pk2(v[2], v[3]);
  r.z = pk2(v[4], v[5]); r.w = pk2(v[6], v[7]);
  return r;
}

// ---------------- K0a: dtype detect ----------------
__global__ __launch_bounds__(256) void detect_kernel(const void* x, int* flag){
  __shared__ int wildcnt;
  if (threadIdx.x == 0) wildcnt = 0;
  __syncthreads();
  const unsigned short* u = (const unsigned short*)x;
  int wild = 0;
  for (int i = threadIdx.x; i < 2048; i += 256){
    unsigned int v = ((unsigned int)u[i]) << 16;
    float f = __uint_as_float(v);
    float a = fabsf(f);
    if (!(a < 1e8f) || (a > 0.f && a < 1e-8f)) wild++;
  }
  atomicAdd(&wildcnt, wild);
  __syncthreads();
  if (threadIdx.x == 0) *flag = (wildcnt > 100) ? 1 : 0;  // 1 = fp32 underlying
}

// ---------------- K0b: param convert ----------------
struct PP { const void* src[15]; float* dst[15]; int n[15]; };
__global__ __launch_bounds__(256) void convert_params(PP pp, const int* flag){
  const int id = blockIdx.x;
  const int n = pp.n[id];
  const void* s = pp.src[id];
  float* d = pp.dst[id];
  const bool isf = (*flag) != 0;
  for (int i = threadIdx.x; i < n; i += 256)
    d[i] = isf ? ((const float*)s)[i] : __bfloat162float(((const bf16*)s)[i]);
}

// ---------------- K1: DWT -> ll ----------------
template<bool ISF>
__device__ void k1_body(const void* xv, float* ll){
  const long total = (long)B2 * C64 * 256 * 256;
  for (long idx = (long)blockIdx.x * blockDim.x + threadIdx.x; idx < total;
       idx += (long)gridDim.x * blockDim.x){
    const int w2 = (int)(idx & 255);
    long r = idx >> 8;
    const int h2 = (int)(r & 255);
    const long plane = r >> 8;                         // b*64+c
    const long base = (plane << 18) + ((long)(2*h2) << 9) + 2*w2;
    const float a  = LD<ISF>(xv, base);
    const float bb = LD<ISF>(xv, base + 512);
    const float cr = LD<ISF>(xv, base + 1);
    const float dd = LD<ISF>(xv, base + 513);
    ll[idx] = 0.5f * (a + bb + cr + dd);
  }
}
__global__ __launch_bounds__(256) void k1_dwt(const void* xv, float* ll, const int* flag){
  if (*flag) k1_body<true>(xv, ll); else k1_body<false>(xv, ll);
}

// ---------------- K2: gap ----------------
__global__ __launch_bounds__(256) void k2_gap(const float* ll, float* gap){
  const int bc = blockIdx.x;                            // 0..127
  const float* p = ll + ((long)bc << 16);
  float s = 0.f;
  for (int i = threadIdx.x; i < 65536; i += 256) s += p[i];
  __shared__ float red[256];
  red[threadIdx.x] = s; __syncthreads();
  for (int st = 128; st > 0; st >>= 1){
    if (threadIdx.x < st) red[threadIdx.x] += red[threadIdx.x + st];
    __syncthreads();
  }
  if (threadIdx.x == 0) gap[bc] = red[0] * (1.f / 65536.f);
}

// ---------------- K3: cross MLP ----------------
__global__ __launch_bounds__(256) void k3_cross(const float* pf, const float* gap,
                                                float* amul, float* cval){
  __shared__ float t1[B2][48];
  __shared__ float g[B2][64];
  const int tid = threadIdx.x;
  if (tid < 128) g[tid >> 6][tid & 63] = gap[tid];
  __syncthreads();
  if (tid < 96){
    const int b = tid / 48, j = tid % 48;
    float s = 0.f;
    const float* w = pf + P_CG1 + j * 64;
    for (int c = 0; c < 64; ++c) s += w[c] * g[b][c];
    t1[b][j] = gelu_f(s);
  }
  __syncthreads();
  const float gm = pf[P_GM], gc = pf[P_GC];
  for (int o = tid; o < B2 * C3; o += 256){
    const int b = o / C3, ch = o % C3;
    float s = 0.f;
    const float* w = pf + P_CG2 + ch * 48;
    for (int j = 0; j < 48; ++j) s += w[j] * t1[b][j];
    const float cr = 1.f / (1.f + expf(-s));
    const float c = gc * (cr - 0.5f) * 2.f;
    cval[o] = c;
    amul[o] = gm * (1.f + c);
  }
}

// ---------------- K4: fused window attention (+ hwin store) ----------------
template<bool ISF>
__device__ void k4_body(const void* xv, const float* pf, const int* rpi, bf16* wout,
                        bf16* hwin, bf16* xw, float* qkv, bf16* sc){
  const int wid = blockIdx.x;
  const int b  = wid >> 10;
  const int wh = (wid >> 5) & 31;
  const int ww = wid & 31;
  const int tid = threadIdx.x;
  const int tk = tid >> 2;     // token 0..63
  const int l4 = tid & 3;

  // stage 1: DWT-high + LayerNorm -> xw ; raw high -> hwin
  {
    const int i = tk >> 3, j = tk & 7;
    const int h2 = (wh*8 + i + 4) & 255;
    const int w2 = (ww*8 + j + 4) & 255;
    const long pixbase = ((long)(2*h2) << 9) + 2*w2;
    float raw0[16], raw1[16], raw2[16];
    float sum = 0.f, sumsq = 0.f;
#pragma unroll
    for (int cc = 0; cc < 16; ++cc){
      const int c = l4*16 + cc;
      const long base = ((long)(b*64 + c) << 18) + pixbase;
      const float a  = LD<ISF>(xv, base);
      const float bb = LD<ISF>(xv, base + 512);
      const float cr = LD<ISF>(xv, base + 1);
      const float dd = LD<ISF>(xv, base + 513);
      const float h0 = 0.5f*(-a - bb + cr + dd);
      const float h1 = 0.5f*(-a + bb - cr + dd);
      const float hh = 0.5f*( a - bb - cr + dd);
      raw0[cc] = h0; raw1[cc] = h1; raw2[cc] = hh;
      sum += h0 + h1 + hh;
      sumsq += h0*h0 + h1*h1 + hh*hh;
    }
    // raw high bands -> hwin (window layout, coalesced 16B stores)
    {
      const long hb = ((long)wid*64 + tk)*192 + l4*16;
      *(uint4*)(hwin + hb)        = pk8(raw0);
      *(uint4*)(hwin + hb + 8)    = pk8(raw0 + 8);
      *(uint4*)(hwin + hb + 64)   = pk8(raw1);
      *(uint4*)(hwin + hb + 72)   = pk8(raw1 + 8);
      *(uint4*)(hwin + hb + 128)  = pk8(raw2);
      *(uint4*)(hwin + hb + 136)  = pk8(raw2 + 8);
    }
    sum   += __shfl_xor(sum, 1, 4);   sum   += __shfl_xor(sum, 2, 4);
    sumsq += __shfl_xor(sumsq, 1, 4); sumsq += __shfl_xor(sumsq, 2, 4);
    const float mean = sum * (1.f / 192.f);
    float var = sumsq * (1.f / 192.f) - mean * mean;
    var = fmaxf(var, 0.f);
    const float rstd = rsqrtf(var + 1e-6f);
#pragma unroll
    for (int cc = 0; cc < 16; ++cc){
      const int c = l4*16 + cc;
      xw[tk*XW_S + c]       = __float2bfloat16((raw0[cc]-mean)*rstd*pf[P_NORMW+c]     + pf[P_NORMB+c]);
      xw[tk*XW_S + 64 + c]  = __float2bfloat16((raw1[cc]-mean)*rstd*pf[P_NORMW+64+c]  + pf[P_NORMB+64+c]);
      xw[tk*XW_S + 128 + c] = __float2bfloat16((raw2[cc]-mean)*rstd*pf[P_NORMW+128+c] + pf[P_NORMB+128+c]);
    }
  }
  __syncthreads();

  const float scale = 0.17677669529663687f;
  for (int h = 0; h < HEADS; ++h){
    // stage 2: q,k,v for this head
    {
      const int dblk = tid >> 4, tblk = tid & 15;
      const int t0 = tblk * 4;
      float acc[4][6];
#pragma unroll
      for (int a1 = 0; a1 < 4; a1++)
#pragma unroll
        for (int a2 = 0; a2 < 6; a2++) acc[a1][a2] = 0.f;
      const float* wr[6];
#pragma unroll
      for (int kk = 0; kk < 6; kk++){
        const int col = dblk*6 + kk;
        const int mat = col >> 5, d = col & 31;
        wr[kk] = pf + P_QKVW + (long)(mat*192 + h*32 + d) * 192;
      }
      for (int ch = 0; ch < 192; ++ch){
        float xvv[4];
#pragma unroll
        for (int a1 = 0; a1 < 4; a1++) xvv[a1] = __bfloat162float(xw[(t0+a1)*XW_S + ch]);
#pragma unroll
        for (int kk = 0; kk < 6; kk++){
          const float wv = wr[kk][ch];
#pragma unroll
          for (int a1 = 0; a1 < 4; a1++) acc[a1][kk] += xvv[a1] * wv;
        }
      }
#pragma unroll
      for (int kk = 0; kk < 6; kk++){
        const int col = dblk*6 + kk;
        const int mat = col >> 5, d = col & 31;
        const float bias = pf[P_QKVB + mat*192 + h*32 + d];
#pragma unroll
        for (int a1 = 0; a1 < 4; a1++)
          qkv[(mat*64 + t0 + a1)*QK_S + d] = acc[a1][kk] + bias;
      }
    }
    __syncthreads();
    // stage 3: scores + relative position bias
    {
      const int nblk = tid >> 4, mblk = tid & 15;
      const int n0 = nblk*4, m0 = mblk*4;
      float acc[4][4];
#pragma unroll
      for (int a1 = 0; a1 < 4; a1++)
#pragma unroll
        for (int a2 = 0; a2 < 4; a2++) acc[a1][a2] = 0.f;
      for (int d = 0; d < 32; ++d){
        float qv[4], kv[4];
#pragma unroll
        for (int a1 = 0; a1 < 4; a1++) qv[a1] = qkv[(n0+a1)*QK_S + d];
#pragma unroll
        for (int a2 = 0; a2 < 4; a2++) kv[a2] = qkv[(64 + m0+a2)*QK_S + d];
#pragma unroll
        for (int a1 = 0; a1 < 4; a1++)
#pragma unroll
          for (int a2 = 0; a2 < 4; a2++) acc[a1][a2] += qv[a1] * kv[a2];
      }
#pragma unroll
      for (int a1 = 0; a1 < 4; a1++)
#pragma unroll
        for (int a2 = 0; a2 < 4; a2++){
          const int n = n0+a1, m = m0+a2;
          const int idx = rpi[n*64 + m];
          sc[n*SC_S + m] = __float2bfloat16(acc[a1][a2]*scale + pf[P_RPB + idx*6 + h]);
        }
    }
    __syncthreads();
    // stage 4: softmax per row
    {
      float vals[16];
      float mx = -1e30f;
#pragma unroll
      for (int q = 0; q < 16; q++){
        vals[q] = __bfloat162float(sc[tk*SC_S + l4*16 + q]);
        mx = fmaxf(mx, vals[q]);
      }
      mx = fmaxf(mx, __shfl_xor(mx, 1, 4));
      mx = fmaxf(mx, __shfl_xor(mx, 2, 4));
      float s = 0.f;
#pragma unroll
      for (int q = 0; q < 16; q++){ vals[q] = expf(vals[q] - mx); s += vals[q]; }
      s += __shfl_xor(s, 1, 4);
      s += __shfl_xor(s, 2, 4);
      const float inv = 1.f / s;
#pragma unroll
      for (int q = 0; q < 16; q++)
        sc[tk*SC_S + l4*16 + q] = __float2bfloat16(vals[q] * inv);
    }
    __syncthreads();
    // stage 5: out = P @ V -> wout
    {
      const int d0 = l4 * 8;
      float acc[8];
#pragma unroll
      for (int q = 0; q < 8; q++) acc[q] = 0.f;
      for (int m = 0; m < 64; ++m){
        const float sv = __bfloat162float(sc[tk*SC_S + m]);
#pragma unroll
        for (int q = 0; q < 8; q++) acc[q] += sv * qkv[(128 + m)*QK_S + d0 + q];
      }
      const long ob = ((long)wid*64 + tk)*192 + h*32 + d0;
#pragma unroll
      for (int q = 0; q < 8; q++) wout[ob + q] = __float2bfloat16(acc[q]);
    }
    __syncthreads();
  }
}
__global__ __launch_bounds__(256) void k4_attn(const void* xv, const float* pf, const int* rpi,
                                               bf16* wout, bf16* hwin, const int* flag){
  __shared__ bf16 xw[64 * XW_S];
  __shared__ float qkv[3 * 64 * QK_S];
  __shared__ bf16 sc[64 * SC_S];
  if (*flag) k4_body<true>(xv, pf, rpi, wout, hwin, xw, qkv, sc);
  else       k4_body<false>(xv, pf, rpi, wout, hwin, xw, qkv, sc);
}

// ---------------- K5: proj + combine + IWT + output conv (fused) ----------------
template<bool ISF>
__device__ void k5f_body(const bf16* wout, const bf16* hwin, const float* pf,
                         const float* amul, const float* cval, const float* dll,
                         void* out, bf16* bufA, bf16* bufB){
  const int wid = blockIdx.x;
  const int b  = wid >> 10;
  const int wh = (wid >> 5) & 31;
  const int ww = wid & 31;
  const int tid = threadIdx.x;

  // stage A: load wout + hwin tiles into LDS (uint2 = 4 bf16 per load)
  {
    const uint2* wsrc = (const uint2*)(wout + (long)wid * 12288);
    const uint2* hsrc = (const uint2*)(hwin + (long)wid * 12288);
    for (int idx = tid; idx < 3072; idx += 256){
      const int t = idx / 48, c4 = (idx % 48) * 4;
      *(uint2*)&bufA[t*XW5 + c4] = wsrc[idx];
      *(uint2*)&bufB[t*XW5 + c4] = hsrc[idx];
    }
  }
  __syncthreads();

  // stage B: proj GEMM + combine -> dval regs
  const int chblk = tid >> 4, tblk = tid & 15;
  const int t0 = tblk*4, ch0 = chblk*12;
  float dval[4][12];
  {
    float acc[4][12];
#pragma unroll
    for (int a1 = 0; a1 < 4; a1++)
#pragma unroll
      for (int kk = 0; kk < 12; kk++) acc[a1][kk] = 0.f;
    for (int ck = 0; ck < 192; ++ck){
      float xvv[4];
#pragma unroll
      for (int a1 = 0; a1 < 4; a1++) xvv[a1] = __bfloat162float(bufA[(t0+a1)*XW5 + ck]);
#pragma unroll
      for (int kk = 0; kk < 12; kk++){
        const float wv = pf[P_PROJW + (ch0+kk)*192 + ck];
#pragma unroll
        for (int a1 = 0; a1 < 4; a1++) acc[a1][kk] += xvv[a1] * wv;
      }
    }
#pragma unroll
    for (int kk = 0; kk < 12; kk++){
      const int ch = ch0 + kk;
      const int bc = b*192 + ch;
      const float am = amul[bc], cv = cval[bc], pb = pf[P_PROJB + ch];
#pragma unroll
      for (int a1 = 0; a1 < 4; a1++){
        const float hv = __bfloat162float(bufB[(t0+a1)*XW5 + ch]);
        dval[a1][kk] = am * (acc[a1][kk] + pb) + cv * hv;
      }
    }
  }
  __syncthreads();   // all reads of bufA/bufB tiles complete

  // write combined high-delta into bufA
#pragma unroll
  for (int a1 = 0; a1 < 4; a1++)
#pragma unroll
    for (int kk = 0; kk < 12; kk++)
      bufA[(t0+a1)*XW5 + ch0 + kk] = __float2bfloat16(dval[a1][kk]);
  __syncthreads();

  // stage C: IWT per token -> y in bufB
  const int tok = tid & 63;
  const int cgrp = tid >> 6;
  const int i = tok >> 3, j = tok & 7;
  const int h2 = (wh*8 + i + 4) & 255;
  const int w2 = (ww*8 + j + 4) & 255;
  const long opix = ((long)h2 << 8) + w2;
  {
    const int c0 = cgrp * 16;
#pragma unroll
    for (int cc = 0; cc < 16; ++cc){
      const int c = c0 + cc;
      const float dl = dll[((long)(b*64 + c) << 16) + opix];
      const float hl = __bfloat162float(bufA[tok*XW5 + c]);
      const float lh = __bfloat162float(bufA[tok*XW5 + 64 + c]);
      const float hh = __bfloat162float(bufA[tok*XW5 + 128 + c]);
      bufB[(0*64 + c)*66 + tok] = __float2bfloat16(0.5f*(dl - hl - lh + hh));
      bufB[(1*64 + c)*66 + tok] = __float2bfloat16(0.5f*(dl - hl + lh - hh));
      bufB[(2*64 + c)*66 + tok] = __float2bfloat16(0.5f*(dl + hl - lh - hh));
      bufB[(3*64 + c)*66 + tok] = __float2bfloat16(0.5f*(dl + hl + lh + hh));
    }
  }
  __syncthreads();

  // stage D: output 1x1 conv, 4 sub-pixels per token
  {
    const int o0 = cgrp * 16;
    float acc[4][16];
#pragma unroll
    for (int pos = 0; pos < 4; pos++)
#pragma unroll
      for (int q = 0; q < 16; q++) acc[pos][q] = 0.f;
    for (int c = 0; c < 64; ++c){
      float yv[4];
#pragma unroll
      for (int pos = 0; pos < 4; pos++) yv[pos] = __bfloat162float(bufB[(pos*64 + c)*66 + tok]);
#pragma unroll
      for (int q = 0; q < 16; q++){
        const float wv = pf[P_PO + (o0+q)*64 + c];
#pragma unroll
        for (int pos = 0; pos < 4; pos++) acc[pos][q] += wv * yv[pos];
      }
    }
#pragma unroll
    for (int q = 0; q < 16; q++){
      const int o = o0 + q;
      const long ob = ((b*64 + o)*512L + 2*h2)*512 + 2*w2;
      ST<ISF>(out, ob,       acc[0][q]);
      ST<ISF>(out, ob + 512, acc[1][q]);
      ST<ISF>(out, ob + 1,   acc[2][q]);
      ST<ISF>(out, ob + 513, acc[3][q]);
    }
  }
}
__global__ __launch_bounds__(256) void k5_fused(const bf16* wout, const bf16* hwin,
                                                const float* pf, const float* amul,
                                                const float* cval, const float* dll,
                                                void* out, const int* flag){
  __shared__ __align__(16) bf16 bufA[64 * XW5];   // wout tile -> combined high
  __shared__ __align__(16) bf16 bufB[4 * 64 * 66];// hwin tile -> y
  if (*flag) k5f_body<true>(wout, hwin, pf, amul, cval, dll, out, bufA, bufB);
  else       k5f_body<false>(wout, hwin, pf, amul, cval, dll, out, bufA, bufB);
}

// ---------------- K6a: depthwise 3x3 + gelu ----------------
__global__ __launch_bounds__(256) void k6a_dw(const float* ll, const float* pf, float* tb){
  const long total = (long)B2 * C64 * 256 * 256;
  for (long idx = (long)blockIdx.x * blockDim.x + threadIdx.x; idx < total;
       idx += (long)gridDim.x * blockDim.x){
    const int w2 = (int)(idx & 255);
    long r = idx >> 8;
    const int h2 = (int)(r & 255);
    r >>= 8;                                 // plane = b*64+c
    const int c = (int)(r & 63);
    const float* wk = pf + P_AUXDW + c*9;
    const long pb = r << 16;
    float s = 0.f;
#pragma unroll
    for (int ky = 0; ky < 3; ky++){
      const int y = h2 + ky - 1;
      if (y < 0 || y > 255) continue;
#pragma unroll
      for (int kx = 0; kx < 3; kx++){
        const int xx = w2 + kx - 1;
        if (xx < 0 || xx > 255) continue;
        s += wk[ky*3 + kx] * ll[pb + ((long)y << 8) + xx];
      }
    }
    tb[idx] = gelu_f(s);
  }
}

// ---------------- K6b: 1x1 conv in-place (t -> dll) ----------------
__global__ __launch_bounds__(256) void k6b_pw(float* tb, const float* pf){
  __shared__ float tin[64][65];
  const int tid = threadIdx.x;
  const int pixl = tid & 63, cgrp = tid >> 6;
  const long p = (long)blockIdx.x * 64 + pixl;
  const long b = p >> 16;
  const long within = p & 65535;
#pragma unroll
  for (int cc = 0; cc < 16; ++cc){
    const int c = cgrp*16 + cc;
    tin[c][pixl] = tb[((b*64 + c) << 16) + within];
  }
  __syncthreads();
  const float ga = pf[P_GA];
  const int o0 = cgrp * 16;
  float acc[16];
#pragma unroll
  for (int q = 0; q < 16; q++) acc[q] = 0.f;
  for (int c = 0; c < 64; ++c){
    const float tv = tin[c][pixl];
#pragma unroll
    for (int q = 0; q < 16; q++) acc[q] += pf[P_AUXPW + (o0+q)*64 + c] * tv;
  }
#pragma unroll
  for (int q = 0; q < 16; q++)
    tb[((b*64 + o0 + q) << 16) + within] = ga * acc[q];
}

// ---------------- launcher ----------------
extern "C" void kernel_launch(void* const* d_in, const int* in_sizes, int n_in,
                              void* d_out, int out_size, void* d_ws, size_t ws_size,
                              hipStream_t stream){
  char* ws = (char*)d_ws;
  int*   flag = (int*)(ws + WS_FLAG);
  float* pf   = (float*)(ws + WS_PARAMS);
  float* gap  = (float*)(ws + WS_GAP);
  float* amul = (float*)(ws + WS_AMUL);
  float* cval = (float*)(ws + WS_CVAL);
  float* ll   = (float*)(ws + WS_LL);
  float* dll  = (float*)(ws + WS_DLL);
  bf16*  wout = (bf16*)(ws + WS_WOUT);
  bf16*  hwin = (bf16*)(ws + WS_HWIN);
  const int* rpi = (const int*)d_in[16];

  detect_kernel<<<1, 256, 0, stream>>>(d_in[0], flag);

  PP pp;
  const int pidx[15] = {1,2,3,4,5,6,7,8,9,10,11,12,13,14,15};
  const int poff[15] = {P_NORMW,P_NORMB,P_QKVW,P_QKVB,P_PROJW,P_PROJB,P_RPB,
                        P_AUXDW,P_AUXPW,P_CG1,P_CG2,P_PO,P_GM,P_GA,P_GC};
  for (int q = 0; q < 15; q++){
    pp.src[q] = d_in[pidx[q]];
    pp.dst[q] = pf + poff[q];
    pp.n[q]   = in_sizes[pidx[q]];
  }
  convert_params<<<15, 256, 0, stream>>>(pp, flag);

  k1_dwt <<<4096, 256, 0, stream>>>(d_in[0], ll, flag);
  k2_gap <<<128,  256, 0, stream>>>(ll, gap);
  k3_cross<<<1,   256, 0, stream>>>(pf, gap, amul, cval);
  k6a_dw <<<4096, 256, 0, stream>>>(ll, pf, dll);
  k6b_pw <<<2048, 256, 0, stream>>>(dll, pf);
  k4_attn<<<NWIN, 256, 0, stream>>>(d_in[0], pf, rpi, wout, hwin, flag);
  k5_fused<<<NWIN, 256, 0, stream>>>(wout, hwin, pf, amul, cval, dll, d_out, flag);
}

// Round 3
// 949.719 us; speedup vs baseline: 2.4259x; 1.6253x over previous
//
#include <hip/hip_runtime.h>
#include <hip/hip_bf16.h>
#include <math.h>

typedef __hip_bfloat16 bf16;
typedef short s8v __attribute__((ext_vector_type(8)));
typedef float f4v __attribute__((ext_vector_type(4)));
#define MFMA16(a,b,c) __builtin_amdgcn_mfma_f32_16x16x32_bf16(a,b,c,0,0,0)

// ---------------- problem constants ----------------
#define B2   2
#define C64  64
#define C3   192
#define HEADS 6
#define NWIN 2048   // 2 * 32 * 32 windows

// ---------------- param table offsets (floats) ----------------
#define P_NORMW 0
#define P_NORMB 192
#define P_QKVW  384
#define P_QKVB  110976
#define P_PROJW 111552
#define P_PROJB 148416
#define P_RPB   148608
#define P_AUXDW 149958
#define P_AUXPW 150534
#define P_CG1   154630
#define P_CG2   157702
#define P_PO    166918
#define P_GM    171014
#define P_GA    171015
#define P_GC    171016

// ---------------- workspace byte offsets ----------------
#define WS_FLAG   0
#define WS_PARAMS 256
#define WS_GAP    684544
#define WS_AMUL   685568
#define WS_CVAL   687616
#define WS_LL     689664
#define WS_DLL    (WS_LL   + 33554432)   // f32 [2][64][256][256]
#define WS_WOUT   (WS_DLL  + 33554432)   // bf16 [2048][64][192]
#define WS_WQKV   (WS_WOUT + 50331648)   // bf16 [576][192]
#define WS_WPROJ  (WS_WQKV + 221184)     // bf16 [192][192]
#define WS_BIAS6  (WS_WPROJ + 73728)     // f32 [6][64][64]
// end = WS_BIAS6 + 98304  (~118.5 MB, well under proven 168.5 MB)

// ---------------- helpers ----------------
template<bool ISF>
__device__ __forceinline__ float LD(const void* p, long i){
  if constexpr (ISF) return ((const float*)p)[i];
  else return __bfloat162float(((const bf16*)p)[i]);
}
template<bool ISF>
__device__ __forceinline__ void ST(void* p, long i, float v){
  if constexpr (ISF) ((float*)p)[i] = v;
  else ((bf16*)p)[i] = __float2bfloat16(v);
}
__device__ __forceinline__ float gelu_f(float x){
  return 0.5f * x * (1.f + erff(x * 0.70710678118654752f));
}
__device__ __forceinline__ unsigned pk2(float a, float b){
  return (unsigned)__bfloat16_as_ushort(__float2bfloat16(a)) |
         ((unsigned)__bfloat16_as_ushort(__float2bfloat16(b)) << 16);
}

// ---------------- K0a: dtype detect ----------------
__global__ __launch_bounds__(256) void detect_kernel(const void* x, int* flag){
  __shared__ int wildcnt;
  if (threadIdx.x == 0) wildcnt = 0;
  __syncthreads();
  const unsigned short* u = (const unsigned short*)x;
  int wild = 0;
  for (int i = threadIdx.x; i < 2048; i += 256){
    unsigned int v = ((unsigned int)u[i]) << 16;
    float f = __uint_as_float(v);
    float a = fabsf(f);
    if (!(a < 1e8f) || (a > 0.f && a < 1e-8f)) wild++;
  }
  atomicAdd(&wildcnt, wild);
  __syncthreads();
  if (threadIdx.x == 0) *flag = (wildcnt > 100) ? 1 : 0;  // 1 = fp32 underlying
}

// ---------------- K0b: param convert ----------------
struct PP { const void* src[15]; float* dst[15]; int n[15]; };
__global__ __launch_bounds__(256) void convert_params(PP pp, const int* flag){
  const int id = blockIdx.x;
  const int n = pp.n[id];
  const void* s = pp.src[id];
  float* d = pp.dst[id];
  const bool isf = (*flag) != 0;
  for (int i = threadIdx.x; i < n; i += 256)
    d[i] = isf ? ((const float*)s)[i] : __bfloat162float(((const bf16*)s)[i]);
}

// ---------------- K0c: bf16 weight tables + bias6 ----------------
__global__ __launch_bounds__(256) void kw_convert(const float* pf, const int* rpi,
                                                  bf16* wqkv, bf16* wproj, float* bias6){
  const int i = blockIdx.x*256 + threadIdx.x;
  if (i < 110592)       wqkv[i] = __float2bfloat16(pf[P_QKVW + i]);
  else if (i < 147456)  wproj[i-110592] = __float2bfloat16(pf[P_PROJW + (i-110592)]);
  else if (i < 172032){
    const int j = i - 147456;
    const int hh = j >> 12, nm = j & 4095;
    bias6[j] = pf[P_RPB + rpi[nm]*6 + hh];
  }
}

// ---------------- K1: DWT -> ll ----------------
template<bool ISF>
__device__ void k1_body(const void* xv, float* ll){
  const long total = (long)B2 * C64 * 256 * 256;
  for (long idx = (long)blockIdx.x * blockDim.x + threadIdx.x; idx < total;
       idx += (long)gridDim.x * blockDim.x){
    const int w2 = (int)(idx & 255);
    long r = idx >> 8;
    const int h2 = (int)(r & 255);
    const long plane = r >> 8;                         // b*64+c
    const long base = (plane << 18) + ((long)(2*h2) << 9) + 2*w2;
    const float a  = LD<ISF>(xv, base);
    const float bb = LD<ISF>(xv, base + 512);
    const float cr = LD<ISF>(xv, base + 1);
    const float dd = LD<ISF>(xv, base + 513);
    ll[idx] = 0.5f * (a + bb + cr + dd);
  }
}
__global__ __launch_bounds__(256) void k1_dwt(const void* xv, float* ll, const int* flag){
  if (*flag) k1_body<true>(xv, ll); else k1_body<false>(xv, ll);
}

// ---------------- K2: gap ----------------
__global__ __launch_bounds__(256) void k2_gap(const float* ll, float* gap){
  const int bc = blockIdx.x;                            // 0..127
  const float* p = ll + ((long)bc << 16);
  float s = 0.f;
  for (int i = threadIdx.x; i < 65536; i += 256) s += p[i];
  __shared__ float red[256];
  red[threadIdx.x] = s; __syncthreads();
  for (int st = 128; st > 0; st >>= 1){
    if (threadIdx.x < st) red[threadIdx.x] += red[threadIdx.x + st];
    __syncthreads();
  }
  if (threadIdx.x == 0) gap[bc] = red[0] * (1.f / 65536.f);
}

// ---------------- K3: cross MLP ----------------
__global__ __launch_bounds__(256) void k3_cross(const float* pf, const float* gap,
                                                float* amul, float* cval){
  __shared__ float t1[B2][48];
  __shared__ float g[B2][64];
  const int tid = threadIdx.x;
  if (tid < 128) g[tid >> 6][tid & 63] = gap[tid];
  __syncthreads();
  if (tid < 96){
    const int b = tid / 48, j = tid % 48;
    float s = 0.f;
    const float* w = pf + P_CG1 + j * 64;
    for (int c = 0; c < 64; ++c) s += w[c] * g[b][c];
    t1[b][j] = gelu_f(s);
  }
  __syncthreads();
  const float gm = pf[P_GM], gc = pf[P_GC];
  for (int o = tid; o < B2 * C3; o += 256){
    const int b = o / C3, ch = o % C3;
    float s = 0.f;
    const float* w = pf + P_CG2 + ch * 48;
    for (int j = 0; j < 48; ++j) s += w[j] * t1[b][j];
    const float cr = 1.f / (1.f + expf(-s));
    const float c = gc * (cr - 0.5f) * 2.f;
    cval[o] = c;
    amul[o] = gm * (1.f + c);
  }
}

// ---------------- K4: LN + MFMA window attention ----------------
// 3 blocks per window (head pairs). LDS map (bytes):
//  xw [64][200] bf16 @0 (25600)
//  region rp (rp=0,1) @25600 + rp*14336:
//    bq [64][40] @+0 (5120), bk [64][40] @+5120, VT swizzled [32][64] @+10240 (4096)
//    bp [64][72] overlays bq/bk (@+0, 9216)
template<bool ISF>
__device__ void k4_body(const void* xv, const float* pf, const bf16* wqkv,
                        const float* bias6, bf16* wout, char* sm){
  const int blk = blockIdx.x;
  const int wid = blk / 3;
  const int hp  = blk - wid*3;
  const int b  = wid >> 10;
  const int wh = (wid >> 5) & 31;
  const int ww = wid & 31;
  const int tid = threadIdx.x;
  bf16* xw = (bf16*)sm;

  // ---- stage 1: DWT-high + LayerNorm -> xw ----
  {
    const int tk = tid >> 2, l4 = tid & 3;
    const int wi = tk >> 3, wj = tk & 7;
    const int h2 = (wh*8 + wi + 4) & 255;
    const int w2 = (ww*8 + wj + 4) & 255;
    const long pixbase = ((long)(2*h2) << 9) + 2*w2;
    float raw0[16], raw1[16], raw2[16];
    float sum = 0.f, sumsq = 0.f;
#pragma unroll
    for (int cc = 0; cc < 16; ++cc){
      const int c = l4*16 + cc;
      const long base = ((long)(b*64 + c) << 18) + pixbase;
      const float a  = LD<ISF>(xv, base);
      const float bb = LD<ISF>(xv, base + 512);
      const float cr = LD<ISF>(xv, base + 1);
      const float dd = LD<ISF>(xv, base + 513);
      const float h0 = 0.5f*(-a - bb + cr + dd);
      const float h1 = 0.5f*(-a + bb - cr + dd);
      const float hh = 0.5f*( a - bb - cr + dd);
      raw0[cc]=h0; raw1[cc]=h1; raw2[cc]=hh;
      sum += h0+h1+hh; sumsq += h0*h0+h1*h1+hh*hh;
    }
    sum   += __shfl_xor(sum,1,4);   sum   += __shfl_xor(sum,2,4);
    sumsq += __shfl_xor(sumsq,1,4); sumsq += __shfl_xor(sumsq,2,4);
    const float mean = sum*(1.f/192.f);
    float var = sumsq*(1.f/192.f) - mean*mean;
    var = fmaxf(var, 0.f);
    const float rstd = rsqrtf(var + 1e-6f);
#pragma unroll
    for (int cc = 0; cc < 16; cc += 2){
      const int c = l4*16 + cc;
      float v0 = (raw0[cc]-mean)*rstd*pf[P_NORMW+c]     + pf[P_NORMB+c];
      float v1 = (raw0[cc+1]-mean)*rstd*pf[P_NORMW+c+1] + pf[P_NORMB+c+1];
      *(unsigned*)(xw + tk*200 + c) = pk2(v0, v1);
      v0 = (raw1[cc]-mean)*rstd*pf[P_NORMW+64+c]     + pf[P_NORMB+64+c];
      v1 = (raw1[cc+1]-mean)*rstd*pf[P_NORMW+64+c+1] + pf[P_NORMB+64+c+1];
      *(unsigned*)(xw + tk*200 + 64 + c) = pk2(v0, v1);
      v0 = (raw2[cc]-mean)*rstd*pf[P_NORMW+128+c]     + pf[P_NORMB+128+c];
      v1 = (raw2[cc+1]-mean)*rstd*pf[P_NORMW+128+c+1] + pf[P_NORMB+128+c+1];
      *(unsigned*)(xw + tk*200 + 128 + c) = pk2(v0, v1);
    }
  }
  __syncthreads();

  const int wv = tid >> 6;
  const int l  = tid & 63;
  const int lr = l & 15, lg = l >> 4;
  const int h  = hp*2 + (wv >> 1);     // head
  const int mh = wv & 1;               // M-half
  const int mt0 = mh*2;
  char* reg = sm + 25600 + (wv>>1)*14336;
  bf16* bq  = (bf16*)reg;
  bf16* bk  = (bf16*)(reg + 5120);
  char* vtb = reg + 10240;
  bf16* bp  = (bf16*)reg;
  const f4v fz = {0.f, 0.f, 0.f, 0.f};

  // ---- qkv GEMM: 2 M-tiles x (q,k,v)x2 N-tiles, K=192 ----
  f4v acc[3][2][2];
#pragma unroll
  for (int p=0;p<3;p++)
#pragma unroll
    for (int nn=0;nn<2;nn++){ acc[p][nn][0]=fz; acc[p][nn][1]=fz; }
#pragma unroll
  for (int ks = 0; ks < 6; ++ks){
    const int k0 = ks*32;
    const s8v a0 = *(const s8v*)(xw + (mt0*16+lr)*200 + k0 + lg*8);
    const s8v a1 = *(const s8v*)(xw + (mt0*16+16+lr)*200 + k0 + lg*8);
#pragma unroll
    for (int p = 0; p < 3; ++p)
#pragma unroll
      for (int nn = 0; nn < 2; ++nn){
        const int ocol = p*192 + h*32 + nn*16 + lr;
        const s8v bfr = *(const s8v*)(wqkv + ocol*192 + k0 + lg*8);
        acc[p][nn][0] = MFMA16(a0, bfr, acc[p][nn][0]);
        acc[p][nn][1] = MFMA16(a1, bfr, acc[p][nn][1]);
      }
  }
  const float scale = 0.17677669529663687f;
#pragma unroll
  for (int p = 0; p < 3; ++p)
#pragma unroll
    for (int nn = 0; nn < 2; ++nn){
      const int ocol = p*192 + h*32 + nn*16 + lr;
      const float bias = pf[P_QKVB + ocol];
#pragma unroll
      for (int mt = 0; mt < 2; ++mt)
#pragma unroll
        for (int i = 0; i < 4; ++i){
          const int row = (mt0+mt)*16 + lg*4 + i;
          const float v = acc[p][nn][mt][i] + bias;
          if (p == 0)      bq[row*40 + nn*16 + lr] = __float2bfloat16(v*scale);
          else if (p == 1) bk[row*40 + nn*16 + lr] = __float2bfloat16(v);
          else {
            const int d = nn*16 + lr;
            *(bf16*)(vtb + ((d*128 + row*2) ^ ((d&7)<<4))) = __float2bfloat16(v);
          }
        }
    }
  __syncthreads();

  // ---- S = q~ k^T + bias6; softmax in regs ----
  f4v sacc[2][4];
#pragma unroll
  for (int mt=0;mt<2;mt++)
#pragma unroll
    for (int nt=0;nt<4;nt++) sacc[mt][nt]=fz;
  {
    const s8v a0 = *(const s8v*)(bq + (mt0*16+lr)*40 + lg*8);
    const s8v a1 = *(const s8v*)(bq + (mt0*16+16+lr)*40 + lg*8);
#pragma unroll
    for (int nt = 0; nt < 4; ++nt){
      const s8v bfr = *(const s8v*)(bk + (nt*16+lr)*40 + lg*8);
      sacc[0][nt] = MFMA16(a0, bfr, sacc[0][nt]);
      sacc[1][nt] = MFMA16(a1, bfr, sacc[1][nt]);
    }
  }
  float pv[2][4][4];
#pragma unroll
  for (int mt = 0; mt < 2; ++mt)
#pragma unroll
    for (int i = 0; i < 4; ++i){
      const int row = (mt0+mt)*16 + lg*4 + i;
      float v[4]; float mx = -1e30f;
#pragma unroll
      for (int nt = 0; nt < 4; ++nt){
        v[nt] = sacc[mt][nt][i] + bias6[h*4096 + row*64 + nt*16 + lr];
        mx = fmaxf(mx, v[nt]);
      }
      mx = fmaxf(mx, __shfl_xor(mx, 1, 16));
      mx = fmaxf(mx, __shfl_xor(mx, 2, 16));
      mx = fmaxf(mx, __shfl_xor(mx, 4, 16));
      mx = fmaxf(mx, __shfl_xor(mx, 8, 16));
      float s = 0.f;
#pragma unroll
      for (int nt = 0; nt < 4; ++nt){ v[nt] = expf(v[nt]-mx); s += v[nt]; }
      s += __shfl_xor(s, 1, 16);
      s += __shfl_xor(s, 2, 16);
      s += __shfl_xor(s, 4, 16);
      s += __shfl_xor(s, 8, 16);
      const float inv = 1.f/s;
#pragma unroll
      for (int nt = 0; nt < 4; ++nt) pv[mt][nt][i] = v[nt]*inv;
    }
  __syncthreads();   // all q/k reads complete before P overlays them

  // ---- write P; PV; wout ----
#pragma unroll
  for (int mt = 0; mt < 2; ++mt)
#pragma unroll
    for (int i = 0; i < 4; ++i){
      const int row = (mt0+mt)*16 + lg*4 + i;
#pragma unroll
      for (int nt = 0; nt < 4; ++nt)
        bp[row*72 + nt*16 + lr] = __float2bfloat16(pv[mt][nt][i]);
    }
  f4v oacc[2][2];
#pragma unroll
  for (int mt=0;mt<2;mt++){ oacc[mt][0]=fz; oacc[mt][1]=fz; }
#pragma unroll
  for (int ks2 = 0; ks2 < 2; ++ks2){
    const s8v a0 = *(const s8v*)(bp + (mt0*16+lr)*72 + ks2*32 + lg*8);
    const s8v a1 = *(const s8v*)(bp + (mt0*16+16+lr)*72 + ks2*32 + lg*8);
#pragma unroll
    for (int nn = 0; nn < 2; ++nn){
      const int d = nn*16 + lr;
      const s8v bfr = *(const s8v*)(vtb + ((d*128 + (ks2*32+lg*8)*2) ^ ((d&7)<<4)));
      oacc[0][nn] = MFMA16(a0, bfr, oacc[0][nn]);
      oacc[1][nn] = MFMA16(a1, bfr, oacc[1][nn]);
    }
  }
#pragma unroll
  for (int mt = 0; mt < 2; ++mt)
#pragma unroll
    for (int nn = 0; nn < 2; ++nn)
#pragma unroll
      for (int i = 0; i < 4; ++i){
        const int row = (mt0+mt)*16 + lg*4 + i;
        wout[((long)wid*64 + row)*192 + h*32 + nn*16 + lr] = __float2bfloat16(oacc[mt][nn][i]);
      }
}
__global__ __launch_bounds__(256,3) void k4_attn(const void* xv, const float* pf,
                                                 const bf16* wqkv, const float* bias6,
                                                 bf16* wout, const int* flag){
  __shared__ __align__(16) char sm[54272];
  if (*flag) k4_body<true>(xv, pf, wqkv, bias6, wout, sm);
  else       k4_body<false>(xv, pf, wqkv, bias6, wout, sm);
}

// ---------------- K5: high-recompute + proj MFMA + combine + IWT + out conv ----------------
template<bool ISF>
__device__ void k5f_body(const void* xv, const bf16* wout, const bf16* wproj,
                         const float* pf, const float* amul, const float* cval,
                         const float* dll, void* out, char* sm){
  bf16* bufA = (bf16*)sm;            // [64][200]
  bf16* bufC = (bf16*)(sm + 25600);  // [64][192] high staging, then [256][66] y
  const int wid = blockIdx.x;
  const int b  = wid >> 10;
  const int wh = (wid >> 5) & 31;
  const int ww = wid & 31;
  const int tid = threadIdx.x;

  // stage 0: recompute raw high bands -> bufC [64][192]
  {
    const int tk = tid >> 2, l4 = tid & 3;
    const int wi = tk >> 3, wj = tk & 7;
    const int h2 = (wh*8 + wi + 4) & 255;
    const int w2 = (ww*8 + wj + 4) & 255;
    const long pixbase = ((long)(2*h2) << 9) + 2*w2;
#pragma unroll
    for (int cc = 0; cc < 16; ++cc){
      const int c = l4*16 + cc;
      const long base = ((long)(b*64 + c) << 18) + pixbase;
      const float a  = LD<ISF>(xv, base);
      const float bb = LD<ISF>(xv, base + 512);
      const float cr = LD<ISF>(xv, base + 1);
      const float dd = LD<ISF>(xv, base + 513);
      bufC[tk*192 + c]       = __float2bfloat16(0.5f*(-a - bb + cr + dd));
      bufC[tk*192 + 64 + c]  = __float2bfloat16(0.5f*(-a + bb - cr + dd));
      bufC[tk*192 + 128 + c] = __float2bfloat16(0.5f*( a - bb - cr + dd));
    }
  }
  // stage A: wout tile -> bufA
  {
    const uint4* wsrc = (const uint4*)(wout + (long)wid * 12288);
    for (int i2 = tid; i2 < 1536; i2 += 256){
      const int t = i2/24, c8 = (i2%24)*8;
      *(uint4*)(bufA + t*200 + c8) = wsrc[i2];
    }
  }
  __syncthreads();

  const int wv = tid >> 6;
  const int l  = tid & 63;
  const int lr = l & 15, lg = l >> 4;
  const f4v fz = {0.f,0.f,0.f,0.f};

  // stage B: proj MFMA (wave wv: cols 48*wv .. +47)
  f4v acc[3][4];
#pragma unroll
  for (int nt=0;nt<3;nt++)
#pragma unroll
    for (int mt=0;mt<4;mt++) acc[nt][mt]=fz;
#pragma unroll
  for (int ks = 0; ks < 6; ++ks){
    const int k0 = ks*32;
    s8v a[4];
#pragma unroll
    for (int mt = 0; mt < 4; ++mt)
      a[mt] = *(const s8v*)(bufA + (mt*16+lr)*200 + k0 + lg*8);
#pragma unroll
    for (int nt = 0; nt < 3; ++nt){
      const int ocol = (wv*3+nt)*16 + lr;
      const s8v bfr = *(const s8v*)(wproj + ocol*192 + k0 + lg*8);
#pragma unroll
      for (int mt = 0; mt < 4; ++mt) acc[nt][mt] = MFMA16(a[mt], bfr, acc[nt][mt]);
    }
  }
  // combine with amul/cval + raw high
  float dval[3][4][4];
#pragma unroll
  for (int nt = 0; nt < 3; ++nt){
    const int col = (wv*3+nt)*16 + lr;
    const int bc = b*192 + col;
    const float am = amul[bc], cv = cval[bc], pb = pf[P_PROJB + col];
#pragma unroll
    for (int mt = 0; mt < 4; ++mt)
#pragma unroll
      for (int i = 0; i < 4; ++i){
        const int row = mt*16 + lg*4 + i;
        const float hv = __bfloat162float(bufC[row*192 + col]);
        dval[nt][mt][i] = am*(acc[nt][mt][i] + pb) + cv*hv;
      }
  }
  __syncthreads();
#pragma unroll
  for (int nt = 0; nt < 3; ++nt){
    const int col = (wv*3+nt)*16 + lr;
#pragma unroll
    for (int mt = 0; mt < 4; ++mt)
#pragma unroll
      for (int i = 0; i < 4; ++i)
        bufA[(mt*16+lg*4+i)*200 + col] = __float2bfloat16(dval[nt][mt][i]);
  }
  __syncthreads();

  // stage C: IWT per token -> y in bufC [256][66]
  const int tok = tid & 63;
  const int cgrp = tid >> 6;
  const int wi = tok >> 3, wj = tok & 7;
  const int h2 = (wh*8 + wi + 4) & 255;
  const int w2 = (ww*8 + wj + 4) & 255;
  const long opix = ((long)h2 << 8) + w2;
  {
    const int c0 = cgrp*16;
#pragma unroll
    for (int cc = 0; cc < 16; ++cc){
      const int c = c0 + cc;
      const float dl = dll[((long)(b*64 + c) << 16) + opix];
      const float hl = __bfloat162float(bufA[tok*200 + c]);
      const float lh = __bfloat162float(bufA[tok*200 + 64 + c]);
      const float hh = __bfloat162float(bufA[tok*200 + 128 + c]);
      bufC[(0*64 + c)*66 + tok] = __float2bfloat16(0.5f*(dl - hl - lh + hh));
      bufC[(1*64 + c)*66 + tok] = __float2bfloat16(0.5f*(dl - hl + lh - hh));
      bufC[(2*64 + c)*66 + tok] = __float2bfloat16(0.5f*(dl + hl - lh - hh));
      bufC[(3*64 + c)*66 + tok] = __float2bfloat16(0.5f*(dl + hl + lh + hh));
    }
  }
  __syncthreads();

  // stage D: output 1x1 conv, 4 sub-pixels per token
  {
    const int o0 = cgrp * 16;
    float acc2[4][16];
#pragma unroll
    for (int pos = 0; pos < 4; pos++)
#pragma unroll
      for (int q = 0; q < 16; q++) acc2[pos][q] = 0.f;
    for (int c = 0; c < 64; ++c){
      float yv[4];
#pragma unroll
      for (int pos = 0; pos < 4; pos++) yv[pos] = __bfloat162float(bufC[(pos*64 + c)*66 + tok]);
#pragma unroll
      for (int q = 0; q < 16; q++){
        const float wt = pf[P_PO + (o0+q)*64 + c];
#pragma unroll
        for (int pos = 0; pos < 4; pos++) acc2[pos][q] += wt * yv[pos];
      }
    }
#pragma unroll
    for (int q = 0; q < 16; q++){
      const int o = o0 + q;
      const long ob = ((b*64 + o)*512L + 2*h2)*512 + 2*w2;
      ST<ISF>(out, ob,       acc2[0][q]);
      ST<ISF>(out, ob + 512, acc2[1][q]);
      ST<ISF>(out, ob + 1,   acc2[2][q]);
      ST<ISF>(out, ob + 513, acc2[3][q]);
    }
  }
}
__global__ __launch_bounds__(256,2) void k5_fused(const void* xv, const bf16* wout,
                                                  const bf16* wproj, const float* pf,
                                                  const float* amul, const float* cval,
                                                  const float* dll, void* out, const int* flag){
  __shared__ __align__(16) char sm5[59392];
  if (*flag) k5f_body<true>(xv, wout, wproj, pf, amul, cval, dll, out, sm5);
  else       k5f_body<false>(xv, wout, wproj, pf, amul, cval, dll, out, sm5);
}

// ---------------- K6a: depthwise 3x3 + gelu ----------------
__global__ __launch_bounds__(256) void k6a_dw(const float* ll, const float* pf, float* tb){
  const long total = (long)B2 * C64 * 256 * 256;
  for (long idx = (long)blockIdx.x * blockDim.x + threadIdx.x; idx < total;
       idx += (long)gridDim.x * blockDim.x){
    const int w2 = (int)(idx & 255);
    long r = idx >> 8;
    const int h2 = (int)(r & 255);
    r >>= 8;                                 // plane = b*64+c
    const int c = (int)(r & 63);
    const float* wk = pf + P_AUXDW + c*9;
    const long pb = r << 16;
    float s = 0.f;
#pragma unroll
    for (int ky = 0; ky < 3; ky++){
      const int y = h2 + ky - 1;
      if (y < 0 || y > 255) continue;
#pragma unroll
      for (int kx = 0; kx < 3; kx++){
        const int xx = w2 + kx - 1;
        if (xx < 0 || xx > 255) continue;
        s += wk[ky*3 + kx] * ll[pb + ((long)y << 8) + xx];
      }
    }
    tb[idx] = gelu_f(s);
  }
}

// ---------------- K6b: 1x1 conv in-place (t -> dll) ----------------
__global__ __launch_bounds__(256) void k6b_pw(float* tb, const float* pf){
  __shared__ float tin[64][65];
  const int tid = threadIdx.x;
  const int pixl = tid & 63, cgrp = tid >> 6;
  const long p = (long)blockIdx.x * 64 + pixl;
  const long b = p >> 16;
  const long within = p & 65535;
#pragma unroll
  for (int cc = 0; cc < 16; ++cc){
    const int c = cgrp*16 + cc;
    tin[c][pixl] = tb[((b*64 + c) << 16) + within];
  }
  __syncthreads();
  const float ga = pf[P_GA];
  const int o0 = cgrp * 16;
  float acc[16];
#pragma unroll
  for (int q = 0; q < 16; q++) acc[q] = 0.f;
  for (int c = 0; c < 64; ++c){
    const float tv = tin[c][pixl];
#pragma unroll
    for (int q = 0; q < 16; q++) acc[q] += pf[P_AUXPW + (o0+q)*64 + c] * tv;
  }
#pragma unroll
  for (int q = 0; q < 16; q++)
    tb[((b*64 + o0 + q) << 16) + within] = ga * acc[q];
}

// ---------------- launcher ----------------
extern "C" void kernel_launch(void* const* d_in, const int* in_sizes, int n_in,
                              void* d_out, int out_size, void* d_ws, size_t ws_size,
                              hipStream_t stream){
  char* ws = (char*)d_ws;
  int*   flag = (int*)(ws + WS_FLAG);
  float* pf   = (float*)(ws + WS_PARAMS);
  float* gap  = (float*)(ws + WS_GAP);
  float* amul = (float*)(ws + WS_AMUL);
  float* cval = (float*)(ws + WS_CVAL);
  float* ll   = (float*)(ws + WS_LL);
  float* dll  = (float*)(ws + WS_DLL);
  bf16*  wout = (bf16*)(ws + WS_WOUT);
  bf16*  wqkv = (bf16*)(ws + WS_WQKV);
  bf16*  wproj= (bf16*)(ws + WS_WPROJ);
  float* bias6= (float*)(ws + WS_BIAS6);
  const int* rpi = (const int*)d_in[16];

  detect_kernel<<<1, 256, 0, stream>>>(d_in[0], flag);

  PP pp;
  const int pidx[15] = {1,2,3,4,5,6,7,8,9,10,11,12,13,14,15};
  const int poff[15] = {P_NORMW,P_NORMB,P_QKVW,P_QKVB,P_PROJW,P_PROJB,P_RPB,
                        P_AUXDW,P_AUXPW,P_CG1,P_CG2,P_PO,P_GM,P_GA,P_GC};
  for (int q = 0; q < 15; q++){
    pp.src[q] = d_in[pidx[q]];
    pp.dst[q] = pf + poff[q];
    pp.n[q]   = in_sizes[pidx[q]];
  }
  convert_params<<<15, 256, 0, stream>>>(pp, flag);
  kw_convert<<<672, 256, 0, stream>>>(pf, rpi, wqkv, wproj, bias6);

  k1_dwt <<<4096, 256, 0, stream>>>(d_in[0], ll, flag);
  k2_gap <<<128,  256, 0, stream>>>(ll, gap);
  k3_cross<<<1,   256, 0, stream>>>(pf, gap, amul, cval);
  k6a_dw <<<4096, 256, 0, stream>>>(ll, pf, dll);
  k6b_pw <<<2048, 256, 0, stream>>>(dll, pf);
  k4_attn<<<NWIN*3, 256, 0, stream>>>(d_in[0], pf, wqkv, bias6, wout, flag);
  k5_fused<<<NWIN, 256, 0, stream>>>(d_in[0], wout, wproj, pf, amul, cval, dll, d_out, flag);
}

// Round 4
// 823.691 us; speedup vs baseline: 2.7971x; 1.1530x over previous
//
#include <hip/hip_runtime.h>
#include <hip/hip_bf16.h>
#include <math.h>

typedef __hip_bfloat16 bf16;
typedef short s8v __attribute__((ext_vector_type(8)));
typedef float f4v __attribute__((ext_vector_type(4)));
#define MFMA16(a,b,c) __builtin_amdgcn_mfma_f32_16x16x32_bf16(a,b,c,0,0,0)

// ---------------- problem constants ----------------
#define B2   2
#define C64  64
#define C3   192
#define HEADS 6
#define NWIN 2048   // 2 * 32 * 32 windows

// ---------------- param table offsets (floats) ----------------
#define P_NORMW 0
#define P_NORMB 192
#define P_QKVW  384
#define P_QKVB  110976
#define P_PROJW 111552
#define P_PROJB 148416
#define P_RPB   148608
#define P_AUXDW 149958
#define P_AUXPW 150534
#define P_CG1   154630
#define P_CG2   157702
#define P_PO    166918
#define P_GM    171014
#define P_GA    171015
#define P_GC    171016

// ---------------- workspace byte offsets ----------------
#define WS_FLAG   0
#define WS_PARAMS 256
#define WS_GAP    684544
#define WS_AMUL   685568
#define WS_CVAL   687616
#define WS_LL     689664                  // bf16 [2][64][256][256] (16.7 MB)
#define WS_DLL    (WS_LL   + 16777216)    // f32  [2][64][256][256]
#define WS_WOUT   (WS_DLL  + 33554432)    // bf16 [2048][64][192]
#define WS_HRAW   (WS_WOUT + 50331648)    // bf16 [2048][64][192]
#define WS_WQKV   (WS_HRAW + 50331648)    // bf16 [576][192]
#define WS_WPROJ  (WS_WQKV + 221184)      // bf16 [192][192]
#define WS_BIAS6  (WS_WPROJ + 73728)      // f32 [6][64][64]
// end = WS_BIAS6 + 98304 = 152,077,824  (< 168.5 MB proven)

// ---------------- helpers ----------------
template<bool ISF>
__device__ __forceinline__ float LD(const void* p, long i){
  if constexpr (ISF) return ((const float*)p)[i];
  else return __bfloat162float(((const bf16*)p)[i]);
}
template<bool ISF>
__device__ __forceinline__ void ST(void* p, long i, float v){
  if constexpr (ISF) ((float*)p)[i] = v;
  else ((bf16*)p)[i] = __float2bfloat16(v);
}
__device__ __forceinline__ float gelu_f(float x){
  return 0.5f * x * (1.f + erff(x * 0.70710678118654752f));
}
__device__ __forceinline__ float bfu(unsigned short u){
  return __uint_as_float(((unsigned)u) << 16);
}
__device__ __forceinline__ unsigned pk2(float a, float b){
  return (unsigned)__bfloat16_as_ushort(__float2bfloat16(a)) |
         ((unsigned)__bfloat16_as_ushort(__float2bfloat16(b)) << 16);
}
__device__ __forceinline__ uint4 pk8(const float* v){
  uint4 r;
  r.x = pk2(v[0], v[1]); r.y = pk2(v[2], v[3]);
  r.z = pk2(v[4], v[5]); r.w = pk2(v[6], v[7]);
  return r;
}

// ---------------- K0a: dtype detect ----------------
__global__ __launch_bounds__(256) void detect_kernel(const void* x, int* flag){
  __shared__ int wildcnt;
  if (threadIdx.x == 0) wildcnt = 0;
  __syncthreads();
  const unsigned short* u = (const unsigned short*)x;
  int wild = 0;
  for (int i = threadIdx.x; i < 2048; i += 256){
    unsigned int v = ((unsigned int)u[i]) << 16;
    float f = __uint_as_float(v);
    float a = fabsf(f);
    if (!(a < 1e8f) || (a > 0.f && a < 1e-8f)) wild++;
  }
  atomicAdd(&wildcnt, wild);
  __syncthreads();
  if (threadIdx.x == 0) *flag = (wildcnt > 100) ? 1 : 0;  // 1 = fp32 underlying
}

// ---------------- K0b: param convert ----------------
struct PP { const void* src[15]; float* dst[15]; int n[15]; };
__global__ __launch_bounds__(256) void convert_params(PP pp, const int* flag){
  const int id = blockIdx.x;
  const int n = pp.n[id];
  const void* s = pp.src[id];
  float* d = pp.dst[id];
  const bool isf = (*flag) != 0;
  for (int i = threadIdx.x; i < n; i += 256)
    d[i] = isf ? ((const float*)s)[i] : __bfloat162float(((const bf16*)s)[i]);
}

// ---------------- K0c: bf16 weight tables + bias6 ----------------
__global__ __launch_bounds__(256) void kw_convert(const float* pf, const int* rpi,
                                                  bf16* wqkv, bf16* wproj, float* bias6){
  const int i = blockIdx.x*256 + threadIdx.x;
  if (i < 110592)       wqkv[i] = __float2bfloat16(pf[P_QKVW + i]);
  else if (i < 147456)  wproj[i-110592] = __float2bfloat16(pf[P_PROJW + (i-110592)]);
  else if (i < 172032){
    const int j = i - 147456;
    const int hh = j >> 12, nm = j & 4095;
    bias6[j] = pf[P_RPB + rpi[nm]*6 + hh];
  }
}

// ---------------- K1f: single-pass DWT -> ll(bf16) + hraw(window bf16) ----------------
template<bool ISF>
__device__ void k1f_body(const void* xv, bf16* llb, bf16* hraw){
  const int wid = blockIdx.x;
  const int b  = wid >> 10;
  const int wh = (wid >> 5) & 31;
  const int ww = wid & 31;
  const int tid = threadIdx.x;
  const int tk = tid >> 2, l4 = tid & 3;
  const int wi = tk >> 3, wj = tk & 7;
  const int h2 = (wh*8 + wi + 4) & 255;
  const int w2 = (ww*8 + wj + 4) & 255;
  const long pixbase = ((long)(2*h2) << 9) + 2*w2;
  const long llpix = ((long)h2 << 8) + w2;
  float raw0[16], raw1[16], raw2[16];
#pragma unroll
  for (int cc = 0; cc < 16; ++cc){
    const int c = l4*16 + cc;
    const long base = ((long)(b*64 + c) << 18) + pixbase;
    const float a  = LD<ISF>(xv, base);
    const float bb = LD<ISF>(xv, base + 512);
    const float cr = LD<ISF>(xv, base + 1);
    const float dd = LD<ISF>(xv, base + 513);
    llb[((long)(b*64 + c) << 16) + llpix] = __float2bfloat16(0.5f*(a + bb + cr + dd));
    raw0[cc] = 0.5f*(-a - bb + cr + dd);
    raw1[cc] = 0.5f*(-a + bb - cr + dd);
    raw2[cc] = 0.5f*( a - bb - cr + dd);
  }
  const long hb = ((long)wid*64 + tk)*192 + l4*16;
  *(uint4*)(hraw + hb)       = pk8(raw0);
  *(uint4*)(hraw + hb + 8)   = pk8(raw0 + 8);
  *(uint4*)(hraw + hb + 64)  = pk8(raw1);
  *(uint4*)(hraw + hb + 72)  = pk8(raw1 + 8);
  *(uint4*)(hraw + hb + 128) = pk8(raw2);
  *(uint4*)(hraw + hb + 136) = pk8(raw2 + 8);
}
__global__ __launch_bounds__(256,4) void k1f_dwt(const void* xv, bf16* llb, bf16* hraw,
                                                 const int* flag){
  if (*flag) k1f_body<true>(xv, llb, hraw);
  else       k1f_body<false>(xv, llb, hraw);
}

// ---------------- K2: gap (bf16 ll, vectorized) ----------------
__global__ __launch_bounds__(256) void k2_gap(const bf16* llb, float* gap){
  const int bc = blockIdx.x;                            // 0..127
  const uint4* p = (const uint4*)(llb + ((long)bc << 16));
  float s = 0.f;
  for (int i = threadIdx.x; i < 8192; i += 256){
    const uint4 v = p[i];
    s += __uint_as_float(v.x << 16) + __uint_as_float(v.x & 0xffff0000u);
    s += __uint_as_float(v.y << 16) + __uint_as_float(v.y & 0xffff0000u);
    s += __uint_as_float(v.z << 16) + __uint_as_float(v.z & 0xffff0000u);
    s += __uint_as_float(v.w << 16) + __uint_as_float(v.w & 0xffff0000u);
  }
  __shared__ float red[256];
  red[threadIdx.x] = s; __syncthreads();
  for (int st = 128; st > 0; st >>= 1){
    if (threadIdx.x < st) red[threadIdx.x] += red[threadIdx.x + st];
    __syncthreads();
  }
  if (threadIdx.x == 0) gap[bc] = red[0] * (1.f / 65536.f);
}

// ---------------- K3: cross MLP ----------------
__global__ __launch_bounds__(256) void k3_cross(const float* pf, const float* gap,
                                                float* amul, float* cval){
  __shared__ float t1[B2][48];
  __shared__ float g[B2][64];
  const int tid = threadIdx.x;
  if (tid < 128) g[tid >> 6][tid & 63] = gap[tid];
  __syncthreads();
  if (tid < 96){
    const int b = tid / 48, j = tid % 48;
    float s = 0.f;
    const float* w = pf + P_CG1 + j * 64;
    for (int c = 0; c < 64; ++c) s += w[c] * g[b][c];
    t1[b][j] = gelu_f(s);
  }
  __syncthreads();
  const float gm = pf[P_GM], gc = pf[P_GC];
  for (int o = tid; o < B2 * C3; o += 256){
    const int b = o / C3, ch = o % C3;
    float s = 0.f;
    const float* w = pf + P_CG2 + ch * 48;
    for (int j = 0; j < 48; ++j) s += w[j] * t1[b][j];
    const float cr = 1.f / (1.f + expf(-s));
    const float c = gc * (cr - 0.5f) * 2.f;
    cval[o] = c;
    amul[o] = gm * (1.f + c);
  }
}

// ---------------- K4: MFMA window attention (hraw -> LN -> attn -> wout) ----------------
// 3 blocks per window (head pairs), XCD-swizzled so a window's 3 blocks share an XCD L2.
// LDS map (bytes):
//  xw [64][200] bf16 @0 (25600)
//  rawt [64][200] bf16 @25600 (25600, transient; overlaps reg regions)
//  region rp (rp=0,1) @25600 + rp*14336:
//    bq [64][40] @+0, bk [64][40] @+5120, VT swizzled @+10240 (4096)
//    bp [64][72] overlays bq/bk
__global__ __launch_bounds__(256,3) void k4_attn(const bf16* hraw, const float* pf,
                                                 const bf16* wqkv, const float* bias6,
                                                 bf16* wout){
  __shared__ __align__(16) char sm[54272];
  const int g = blockIdx.x;
  const int xcd = g & 7, slot = g >> 3;
  const int wid = (slot/3)*8 + xcd;
  const int hp  = slot - (slot/3)*3;
  const int tid = threadIdx.x;
  bf16* xw   = (bf16*)sm;
  bf16* rawt = (bf16*)(sm + 25600);

  // stage A: hraw tile -> LDS
  {
    const uint4* hsrc = (const uint4*)(hraw + (long)wid * 12288);
    for (int i2 = tid; i2 < 1536; i2 += 256)
      *(uint4*)(rawt + (i2/24)*200 + (i2%24)*8) = hsrc[i2];
  }
  __syncthreads();

  // stage B: LayerNorm from LDS -> xw
  {
    const int tk = tid >> 2, l4 = tid & 3;
    float rv[48];
    float sum = 0.f, sumsq = 0.f;
#pragma unroll
    for (int bd = 0; bd < 3; ++bd)
#pragma unroll
      for (int hf = 0; hf < 2; ++hf){
        const s8v v8 = *(const s8v*)(rawt + tk*200 + bd*64 + l4*16 + hf*8);
#pragma unroll
        for (int q = 0; q < 8; ++q){
          const float f = bfu((unsigned short)v8[q]);
          rv[bd*16 + hf*8 + q] = f; sum += f; sumsq += f*f;
        }
      }
    sum   += __shfl_xor(sum,1,4);   sum   += __shfl_xor(sum,2,4);
    sumsq += __shfl_xor(sumsq,1,4); sumsq += __shfl_xor(sumsq,2,4);
    const float mean = sum*(1.f/192.f);
    float var = sumsq*(1.f/192.f) - mean*mean;
    var = fmaxf(var, 0.f);
    const float rstd = rsqrtf(var + 1e-6f);
#pragma unroll
    for (int bd = 0; bd < 3; ++bd)
#pragma unroll
      for (int cc = 0; cc < 16; cc += 2){
        const int c = bd*64 + l4*16 + cc;
        const float v0 = (rv[bd*16+cc]  -mean)*rstd*pf[P_NORMW+c]   + pf[P_NORMB+c];
        const float v1 = (rv[bd*16+cc+1]-mean)*rstd*pf[P_NORMW+c+1] + pf[P_NORMB+c+1];
        *(unsigned*)(xw + tk*200 + c) = pk2(v0, v1);
      }
  }
  __syncthreads();

  const int wv = tid >> 6;
  const int l  = tid & 63;
  const int lr = l & 15, lg = l >> 4;
  const int h  = hp*2 + (wv >> 1);     // head
  const int mh = wv & 1;               // M-half
  const int mt0 = mh*2;
  char* reg = sm + 25600 + (wv>>1)*14336;
  bf16* bq  = (bf16*)reg;
  bf16* bk  = (bf16*)(reg + 5120);
  char* vtb = reg + 10240;
  bf16* bp  = (bf16*)reg;
  const f4v fz = {0.f, 0.f, 0.f, 0.f};

  // ---- qkv GEMM: 2 M-tiles x (q,k,v)x2 N-tiles, K=192 ----
  f4v acc[3][2][2];
#pragma unroll
  for (int p=0;p<3;p++)
#pragma unroll
    for (int nn=0;nn<2;nn++){ acc[p][nn][0]=fz; acc[p][nn][1]=fz; }
#pragma unroll
  for (int ks = 0; ks < 6; ++ks){
    const int k0 = ks*32;
    const s8v a0 = *(const s8v*)(xw + (mt0*16+lr)*200 + k0 + lg*8);
    const s8v a1 = *(const s8v*)(xw + (mt0*16+16+lr)*200 + k0 + lg*8);
#pragma unroll
    for (int p = 0; p < 3; ++p)
#pragma unroll
      for (int nn = 0; nn < 2; ++nn){
        const int ocol = p*192 + h*32 + nn*16 + lr;
        const s8v bfr = *(const s8v*)(wqkv + ocol*192 + k0 + lg*8);
        acc[p][nn][0] = MFMA16(a0, bfr, acc[p][nn][0]);
        acc[p][nn][1] = MFMA16(a1, bfr, acc[p][nn][1]);
      }
  }
  const float scale = 0.17677669529663687f;
#pragma unroll
  for (int p = 0; p < 3; ++p)
#pragma unroll
    for (int nn = 0; nn < 2; ++nn){
      const int ocol = p*192 + h*32 + nn*16 + lr;
      const float bias = pf[P_QKVB + ocol];
#pragma unroll
      for (int mt = 0; mt < 2; ++mt)
#pragma unroll
        for (int i = 0; i < 4; ++i){
          const int row = (mt0+mt)*16 + lg*4 + i;
          const float v = acc[p][nn][mt][i] + bias;
          if (p == 0)      bq[row*40 + nn*16 + lr] = __float2bfloat16(v*scale);
          else if (p == 1) bk[row*40 + nn*16 + lr] = __float2bfloat16(v);
          else {
            const int d = nn*16 + lr;
            *(bf16*)(vtb + ((d*128 + row*2) ^ ((d&7)<<4))) = __float2bfloat16(v);
          }
        }
    }
  __syncthreads();

  // ---- S = q~ k^T + bias6; softmax in regs ----
  f4v sacc[2][4];
#pragma unroll
  for (int mt=0;mt<2;mt++)
#pragma unroll
    for (int nt=0;nt<4;nt++) sacc[mt][nt]=fz;
  {
    const s8v a0 = *(const s8v*)(bq + (mt0*16+lr)*40 + lg*8);
    const s8v a1 = *(const s8v*)(bq + (mt0*16+16+lr)*40 + lg*8);
#pragma unroll
    for (int nt = 0; nt < 4; ++nt){
      const s8v bfr = *(const s8v*)(bk + (nt*16+lr)*40 + lg*8);
      sacc[0][nt] = MFMA16(a0, bfr, sacc[0][nt]);
      sacc[1][nt] = MFMA16(a1, bfr, sacc[1][nt]);
    }
  }
  float pv[2][4][4];
#pragma unroll
  for (int mt = 0; mt < 2; ++mt)
#pragma unroll
    for (int i = 0; i < 4; ++i){
      const int row = (mt0+mt)*16 + lg*4 + i;
      float v[4]; float mx = -1e30f;
#pragma unroll
      for (int nt = 0; nt < 4; ++nt){
        v[nt] = sacc[mt][nt][i] + bias6[h*4096 + row*64 + nt*16 + lr];
        mx = fmaxf(mx, v[nt]);
      }
      mx = fmaxf(mx, __shfl_xor(mx, 1, 16));
      mx = fmaxf(mx, __shfl_xor(mx, 2, 16));
      mx = fmaxf(mx, __shfl_xor(mx, 4, 16));
      mx = fmaxf(mx, __shfl_xor(mx, 8, 16));
      float s = 0.f;
#pragma unroll
      for (int nt = 0; nt < 4; ++nt){ v[nt] = __expf(v[nt]-mx); s += v[nt]; }
      s += __shfl_xor(s, 1, 16);
      s += __shfl_xor(s, 2, 16);
      s += __shfl_xor(s, 4, 16);
      s += __shfl_xor(s, 8, 16);
      const float inv = 1.f/s;
#pragma unroll
      for (int nt = 0; nt < 4; ++nt) pv[mt][nt][i] = v[nt]*inv;
    }
  __syncthreads();   // all q/k reads complete before P overlays them

  // ---- write P; PV; wout ----
#pragma unroll
  for (int mt = 0; mt < 2; ++mt)
#pragma unroll
    for (int i = 0; i < 4; ++i){
      const int row = (mt0+mt)*16 + lg*4 + i;
#pragma unroll
      for (int nt = 0; nt < 4; ++nt)
        bp[row*72 + nt*16 + lr] = __float2bfloat16(pv[mt][nt][i]);
    }
  f4v oacc[2][2];
#pragma unroll
  for (int mt=0;mt<2;mt++){ oacc[mt][0]=fz; oacc[mt][1]=fz; }
#pragma unroll
  for (int ks2 = 0; ks2 < 2; ++ks2){
    const s8v a0 = *(const s8v*)(bp + (mt0*16+lr)*72 + ks2*32 + lg*8);
    const s8v a1 = *(const s8v*)(bp + (mt0*16+16+lr)*72 + ks2*32 + lg*8);
#pragma unroll
    for (int nn = 0; nn < 2; ++nn){
      const int d = nn*16 + lr;
      const s8v bfr = *(const s8v*)(vtb + ((d*128 + (ks2*32+lg*8)*2) ^ ((d&7)<<4)));
      oacc[0][nn] = MFMA16(a0, bfr, oacc[0][nn]);
      oacc[1][nn] = MFMA16(a1, bfr, oacc[1][nn]);
    }
  }
#pragma unroll
  for (int mt = 0; mt < 2; ++mt)
#pragma unroll
    for (int nn = 0; nn < 2; ++nn)
#pragma unroll
      for (int i = 0; i < 4; ++i){
        const int row = (mt0+mt)*16 + lg*4 + i;
        wout[((long)wid*64 + row)*192 + h*32 + nn*16 + lr] = __float2bfloat16(oacc[mt][nn][i]);
      }
}

// ---------------- K5: proj MFMA + combine + IWT + out conv ----------------
template<bool ISF>
__device__ void k5f_body(const bf16* wout, const bf16* hraw, const bf16* wproj,
                         const float* pf, const float* amul, const float* cval,
                         const float* dll, void* out, char* sm){
  bf16* bufA = (bf16*)sm;            // [64][200] wout tile -> combined high delta
  bf16* bufC = (bf16*)(sm + 25600);  // [64][200] hraw staging, then [256][66] y
  const int wid = blockIdx.x;
  const int b  = wid >> 10;
  const int wh = (wid >> 5) & 31;
  const int ww = wid & 31;
  const int tid = threadIdx.x;

  // stage 0/A: load hraw + wout tiles into LDS
  {
    const uint4* hsrc = (const uint4*)(hraw + (long)wid * 12288);
    const uint4* wsrc = (const uint4*)(wout + (long)wid * 12288);
    for (int i2 = tid; i2 < 1536; i2 += 256){
      const int t = i2/24, c8 = (i2%24)*8;
      *(uint4*)(bufC + t*200 + c8) = hsrc[i2];
      *(uint4*)(bufA + t*200 + c8) = wsrc[i2];
    }
  }
  __syncthreads();

  const int wv = tid >> 6;
  const int l  = tid & 63;
  const int lr = l & 15, lg = l >> 4;
  const f4v fz = {0.f,0.f,0.f,0.f};

  // stage B: proj MFMA (wave wv: cols 48*wv .. +47)
  f4v acc[3][4];
#pragma unroll
  for (int nt=0;nt<3;nt++)
#pragma unroll
    for (int mt=0;mt<4;mt++) acc[nt][mt]=fz;
#pragma unroll
  for (int ks = 0; ks < 6; ++ks){
    const int k0 = ks*32;
    s8v a[4];
#pragma unroll
    for (int mt = 0; mt < 4; ++mt)
      a[mt] = *(const s8v*)(bufA + (mt*16+lr)*200 + k0 + lg*8);
#pragma unroll
    for (int nt = 0; nt < 3; ++nt){
      const int ocol = (wv*3+nt)*16 + lr;
      const s8v bfr = *(const s8v*)(wproj + ocol*192 + k0 + lg*8);
#pragma unroll
      for (int mt = 0; mt < 4; ++mt) acc[nt][mt] = MFMA16(a[mt], bfr, acc[nt][mt]);
    }
  }
  // combine with amul/cval + raw high
  float dval[3][4][4];
#pragma unroll
  for (int nt = 0; nt < 3; ++nt){
    const int col = (wv*3+nt)*16 + lr;
    const int bc = b*192 + col;
    const float am = amul[bc], cv = cval[bc], pb = pf[P_PROJB + col];
#pragma unroll
    for (int mt = 0; mt < 4; ++mt)
#pragma unroll
      for (int i = 0; i < 4; ++i){
        const int row = mt*16 + lg*4 + i;
        const float hv = __bfloat162float(bufC[row*200 + col]);
        dval[nt][mt][i] = am*(acc[nt][mt][i] + pb) + cv*hv;
      }
  }
  __syncthreads();
#pragma unroll
  for (int nt = 0; nt < 3; ++nt){
    const int col = (wv*3+nt)*16 + lr;
#pragma unroll
    for (int mt = 0; mt < 4; ++mt)
#pragma unroll
      for (int i = 0; i < 4; ++i)
        bufA[(mt*16+lg*4+i)*200 + col] = __float2bfloat16(dval[nt][mt][i]);
  }
  __syncthreads();

  // stage C: IWT per token -> y in bufC [256][66]
  const int tok = tid & 63;
  const int cgrp = tid >> 6;
  const int wi = tok >> 3, wj = tok & 7;
  const int h2 = (wh*8 + wi + 4) & 255;
  const int w2 = (ww*8 + wj + 4) & 255;
  const long opix = ((long)h2 << 8) + w2;
  {
    const int c0 = cgrp*16;
#pragma unroll
    for (int cc = 0; cc < 16; ++cc){
      const int c = c0 + cc;
      const float dl = dll[((long)(b*64 + c) << 16) + opix];
      const float hl = __bfloat162float(bufA[tok*200 + c]);
      const float lh = __bfloat162float(bufA[tok*200 + 64 + c]);
      const float hh = __bfloat162float(bufA[tok*200 + 128 + c]);
      bufC[(0*64 + c)*66 + tok] = __float2bfloat16(0.5f*(dl - hl - lh + hh));
      bufC[(1*64 + c)*66 + tok] = __float2bfloat16(0.5f*(dl - hl + lh - hh));
      bufC[(2*64 + c)*66 + tok] = __float2bfloat16(0.5f*(dl + hl - lh - hh));
      bufC[(3*64 + c)*66 + tok] = __float2bfloat16(0.5f*(dl + hl + lh + hh));
    }
  }
  __syncthreads();

  // stage D: output 1x1 conv, 4 sub-pixels per token
  {
    const int o0 = cgrp * 16;
    float acc2[4][16];
#pragma unroll
    for (int pos = 0; pos < 4; pos++)
#pragma unroll
      for (int q = 0; q < 16; q++) acc2[pos][q] = 0.f;
    for (int c = 0; c < 64; ++c){
      float yv[4];
#pragma unroll
      for (int pos = 0; pos < 4; pos++) yv[pos] = __bfloat162float(bufC[(pos*64 + c)*66 + tok]);
#pragma unroll
      for (int q = 0; q < 16; q++){
        const float wt = pf[P_PO + (o0+q)*64 + c];
#pragma unroll
        for (int pos = 0; pos < 4; pos++) acc2[pos][q] += wt * yv[pos];
      }
    }
#pragma unroll
    for (int q = 0; q < 16; q++){
      const int o = o0 + q;
      const long ob = ((b*64 + o)*512L + 2*h2)*512 + 2*w2;
      ST<ISF>(out, ob,       acc2[0][q]);
      ST<ISF>(out, ob + 512, acc2[1][q]);
      ST<ISF>(out, ob + 1,   acc2[2][q]);
      ST<ISF>(out, ob + 513, acc2[3][q]);
    }
  }
}
__global__ __launch_bounds__(256,2) void k5_fused(const bf16* wout, const bf16* hraw,
                                                  const bf16* wproj, const float* pf,
                                                  const float* amul, const float* cval,
                                                  const float* dll, void* out, const int* flag){
  __shared__ __align__(16) char sm5[59392];
  if (*flag) k5f_body<true>(wout, hraw, wproj, pf, amul, cval, dll, out, sm5);
  else       k5f_body<false>(wout, hraw, wproj, pf, amul, cval, dll, out, sm5);
}

// ---------------- K6a: depthwise 3x3 + gelu (bf16 ll in, f32 out) ----------------
__global__ __launch_bounds__(256) void k6a_dw(const bf16* llb, const float* pf, float* tb){
  const long total = (long)B2 * C64 * 256 * 256;
  for (long idx = (long)blockIdx.x * blockDim.x + threadIdx.x; idx < total;
       idx += (long)gridDim.x * blockDim.x){
    const int w2 = (int)(idx & 255);
    long r = idx >> 8;
    const int h2 = (int)(r & 255);
    r >>= 8;                                 // plane = b*64+c
    const int c = (int)(r & 63);
    const float* wk = pf + P_AUXDW + c*9;
    const long pb = r << 16;
    float s = 0.f;
#pragma unroll
    for (int ky = 0; ky < 3; ky++){
      const int y = h2 + ky - 1;
      if (y < 0 || y > 255) continue;
#pragma unroll
      for (int kx = 0; kx < 3; kx++){
        const int xx = w2 + kx - 1;
        if (xx < 0 || xx > 255) continue;
        s += wk[ky*3 + kx] * __bfloat162float(llb[pb + ((long)y << 8) + xx]);
      }
    }
    tb[idx] = gelu_f(s);
  }
}

// ---------------- K6b: 1x1 conv in-place (t -> dll) ----------------
__global__ __launch_bounds__(256) void k6b_pw(float* tb, const float* pf){
  __shared__ float tin[64][65];
  const int tid = threadIdx.x;
  const int pixl = tid & 63, cgrp = tid >> 6;
  const long p = (long)blockIdx.x * 64 + pixl;
  const long b = p >> 16;
  const long within = p & 65535;
#pragma unroll
  for (int cc = 0; cc < 16; ++cc){
    const int c = cgrp*16 + cc;
    tin[c][pixl] = tb[((b*64 + c) << 16) + within];
  }
  __syncthreads();
  const float ga = pf[P_GA];
  const int o0 = cgrp * 16;
  float acc[16];
#pragma unroll
  for (int q = 0; q < 16; q++) acc[q] = 0.f;
  for (int c = 0; c < 64; ++c){
    const float tv = tin[c][pixl];
#pragma unroll
    for (int q = 0; q < 16; q++) acc[q] += pf[P_AUXPW + (o0+q)*64 + c] * tv;
  }
#pragma unroll
  for (int q = 0; q < 16; q++)
    tb[((b*64 + o0 + q) << 16) + within] = ga * acc[q];
}

// ---------------- launcher ----------------
extern "C" void kernel_launch(void* const* d_in, const int* in_sizes, int n_in,
                              void* d_out, int out_size, void* d_ws, size_t ws_size,
                              hipStream_t stream){
  char* ws = (char*)d_ws;
  int*   flag = (int*)(ws + WS_FLAG);
  float* pf   = (float*)(ws + WS_PARAMS);
  float* gap  = (float*)(ws + WS_GAP);
  float* amul = (float*)(ws + WS_AMUL);
  float* cval = (float*)(ws + WS_CVAL);
  bf16*  llb  = (bf16*)(ws + WS_LL);
  float* dll  = (float*)(ws + WS_DLL);
  bf16*  wout = (bf16*)(ws + WS_WOUT);
  bf16*  hraw = (bf16*)(ws + WS_HRAW);
  bf16*  wqkv = (bf16*)(ws + WS_WQKV);
  bf16*  wproj= (bf16*)(ws + WS_WPROJ);
  float* bias6= (float*)(ws + WS_BIAS6);
  const int* rpi = (const int*)d_in[16];

  detect_kernel<<<1, 256, 0, stream>>>(d_in[0], flag);

  PP pp;
  const int pidx[15] = {1,2,3,4,5,6,7,8,9,10,11,12,13,14,15};
  const int poff[15] = {P_NORMW,P_NORMB,P_QKVW,P_QKVB,P_PROJW,P_PROJB,P_RPB,
                        P_AUXDW,P_AUXPW,P_CG1,P_CG2,P_PO,P_GM,P_GA,P_GC};
  for (int q = 0; q < 15; q++){
    pp.src[q] = d_in[pidx[q]];
    pp.dst[q] = pf + poff[q];
    pp.n[q]   = in_sizes[pidx[q]];
  }
  convert_params<<<15, 256, 0, stream>>>(pp, flag);
  kw_convert<<<672, 256, 0, stream>>>(pf, rpi, wqkv, wproj, bias6);

  k1f_dwt<<<NWIN, 256, 0, stream>>>(d_in[0], llb, hraw, flag);
  k2_gap <<<128,  256, 0, stream>>>(llb, gap);
  k3_cross<<<1,   256, 0, stream>>>(pf, gap, amul, cval);
  k6a_dw <<<4096, 256, 0, stream>>>(llb, pf, dll);
  k6b_pw <<<2048, 256, 0, stream>>>(dll, pf);
  k4_attn<<<NWIN*3, 256, 0, stream>>>(hraw, pf, wqkv, bias6, wout);
  k5_fused<<<NWIN, 256, 0, stream>>>(wout, hraw, wproj, pf, amul, cval, dll, d_out, flag);
}

// Round 5
// 763.663 us; speedup vs baseline: 3.0170x; 1.0786x over previous
//
#include <hip/hip_runtime.h>
#include <hip/hip_bf16.h>
#include <math.h>

typedef __hip_bfloat16 bf16;
typedef short s8v __attribute__((ext_vector_type(8)));
typedef float f4v __attribute__((ext_vector_type(4)));
#define MFMA16(a,b,c) __builtin_amdgcn_mfma_f32_16x16x32_bf16(a,b,c,0,0,0)

// ---------------- problem constants ----------------
#define B2   2
#define C64  64
#define C3   192
#define HEADS 6
#define NWIN 2048   // 2 * 32 * 32 windows

// ---------------- param table offsets (floats) ----------------
#define P_NORMW 0
#define P_NORMB 192
#define P_QKVW  384
#define P_QKVB  110976
#define P_PROJW 111552
#define P_PROJB 148416
#define P_RPB   148608
#define P_AUXDW 149958
#define P_AUXPW 150534
#define P_CG1   154630
#define P_CG2   157702
#define P_PO    166918
#define P_GM    171014
#define P_GA    171015
#define P_GC    171016

// ---------------- workspace byte offsets ----------------
#define WS_FLAG   0
#define WS_PARAMS 256
#define WS_GAP    684544
#define WS_AMUL   685568
#define WS_CVAL   687616
#define WS_TSTAT  689664                   // float2 [2048*64]
#define WS_LL     1738240                  // bf16 [2][64][256][256]
#define WS_DLLW   18515456                 // bf16 [2048][64][64]  (window layout)
#define WS_WOUT   35292672                 // bf16 [2048][64][192]
#define WS_HRAW   85624320                 // bf16 [2048][64][192]
#define WS_WQKV   135955968                // bf16 [576][192]  (LN-folded)
#define WS_WPROJ  136177152                // bf16 [192][192]
#define WS_WPW    136250880                // bf16 [64][64]
#define WS_WPO    136259072                // bf16 [64][64]
#define WS_S12    136267264                // f32 S1[576], S2[576]
#define WS_BIAS6  136271872                // f32 [6][64][64]
// end = 136,370,176  (< 152 MB proven)

// ---------------- helpers ----------------
template<bool ISF>
__device__ __forceinline__ float LD(const void* p, long i){
  if constexpr (ISF) return ((const float*)p)[i];
  else return __bfloat162float(((const bf16*)p)[i]);
}
template<bool ISF>
__device__ __forceinline__ void ST(void* p, long i, float v){
  if constexpr (ISF) ((float*)p)[i] = v;
  else ((bf16*)p)[i] = __float2bfloat16(v);
}
__device__ __forceinline__ float gelu_f(float x){
  return 0.5f * x * (1.f + erff(x * 0.70710678118654752f));
}
__device__ __forceinline__ float bfu(unsigned short u){
  return __uint_as_float(((unsigned)u) << 16);
}
__device__ __forceinline__ unsigned pk2(float a, float b){
  return (unsigned)__bfloat16_as_ushort(__float2bfloat16(a)) |
         ((unsigned)__bfloat16_as_ushort(__float2bfloat16(b)) << 16);
}
__device__ __forceinline__ uint4 pk8(const float* v){
  uint4 r;
  r.x = pk2(v[0], v[1]); r.y = pk2(v[2], v[3]);
  r.z = pk2(v[4], v[5]); r.w = pk2(v[6], v[7]);
  return r;
}

// ---------------- K0a: dtype detect ----------------
__global__ __launch_bounds__(256) void detect_kernel(const void* x, int* flag){
  __shared__ int wildcnt;
  if (threadIdx.x == 0) wildcnt = 0;
  __syncthreads();
  const unsigned short* u = (const unsigned short*)x;
  int wild = 0;
  for (int i = threadIdx.x; i < 2048; i += 256){
    unsigned int v = ((unsigned int)u[i]) << 16;
    float f = __uint_as_float(v);
    float a = fabsf(f);
    if (!(a < 1e8f) || (a > 0.f && a < 1e-8f)) wild++;
  }
  atomicAdd(&wildcnt, wild);
  __syncthreads();
  if (threadIdx.x == 0) *flag = (wildcnt > 100) ? 1 : 0;  // 1 = fp32 underlying
}

// ---------------- K0b: param convert ----------------
struct PP { const void* src[15]; float* dst[15]; int n[15]; };
__global__ __launch_bounds__(256) void convert_params(PP pp, const int* flag){
  const int id = blockIdx.x;
  const int n = pp.n[id];
  const void* s = pp.src[id];
  float* d = pp.dst[id];
  const bool isf = (*flag) != 0;
  for (int i = threadIdx.x; i < n; i += 256)
    d[i] = isf ? ((const float*)s)[i] : __bfloat162float(((const bf16*)s)[i]);
}

// ---------------- K0c: bf16 weight tables (LN-folded) + bias6 ----------------
__global__ __launch_bounds__(256) void kw_convert(const float* pf, const int* rpi,
                                                  bf16* wqkvF, bf16* wproj,
                                                  bf16* wpw, bf16* wpo, float* bias6){
  const int i = blockIdx.x*256 + threadIdx.x;
  if (i < 110592){
    const int c = i % 192;
    wqkvF[i] = __float2bfloat16(pf[P_QKVW + i] * pf[P_NORMW + c]);
  } else if (i < 147456)  wproj[i-110592] = __float2bfloat16(pf[P_PROJW + (i-110592)]);
  else if (i < 151552)    wpw[i-147456]   = __float2bfloat16(pf[P_AUXPW + (i-147456)]);
  else if (i < 155648)    wpo[i-151552]   = __float2bfloat16(pf[P_PO + (i-151552)]);
  else if (i < 180224){
    const int j = i - 155648;
    const int hh = j >> 12, nm = j & 4095;
    bias6[j] = pf[P_RPB + rpi[nm]*6 + hh];
  }
}

// ---------------- K0d: S1/S2 rank-1 LN correction ----------------
__global__ __launch_bounds__(256) void k0d_s12(const float* pf, float* s12){
  const int o = blockIdx.x*256 + threadIdx.x;
  if (o >= 576) return;
  float s1 = 0.f, s2 = 0.f;
  for (int c = 0; c < 192; ++c){
    const float w = pf[P_QKVW + o*192 + c];
    s1 += w * pf[P_NORMW + c];
    s2 += w * pf[P_NORMB + c];
  }
  s12[o] = s1;
  s12[576 + o] = s2 + pf[P_QKVB + o];
}

// ---------------- K1f: single-pass DWT -> ll(bf16) + hraw + tstat ----------------
template<bool ISF>
__device__ void k1f_body(const void* xv, bf16* llb, bf16* hraw, float2* tstat){
  const int wid = blockIdx.x;
  const int b  = wid >> 10;
  const int wh = (wid >> 5) & 31;
  const int ww = wid & 31;
  const int tid = threadIdx.x;
  const int tk = tid >> 2, l4 = tid & 3;
  const int wi = tk >> 3, wj = tk & 7;
  const int h2 = (wh*8 + wi + 4) & 255;
  const int w2 = (ww*8 + wj + 4) & 255;
  const long pixbase = ((long)(2*h2) << 9) + 2*w2;
  const long llpix = ((long)h2 << 8) + w2;
  float raw0[16], raw1[16], raw2[16];
  float sum = 0.f, sumsq = 0.f;
#pragma unroll
  for (int cc = 0; cc < 16; ++cc){
    const int c = l4*16 + cc;
    const long base = ((long)(b*64 + c) << 18) + pixbase;
    const float a  = LD<ISF>(xv, base);
    const float bb = LD<ISF>(xv, base + 512);
    const float cr = LD<ISF>(xv, base + 1);
    const float dd = LD<ISF>(xv, base + 513);
    llb[((long)(b*64 + c) << 16) + llpix] = __float2bfloat16(0.5f*(a + bb + cr + dd));
    const float h0 = 0.5f*(-a - bb + cr + dd);
    const float h1 = 0.5f*(-a + bb - cr + dd);
    const float hh = 0.5f*( a - bb - cr + dd);
    raw0[cc] = h0; raw1[cc] = h1; raw2[cc] = hh;
    sum += h0 + h1 + hh;
    sumsq += h0*h0 + h1*h1 + hh*hh;
  }
  const long hb = ((long)wid*64 + tk)*192 + l4*16;
  *(uint4*)(hraw + hb)       = pk8(raw0);
  *(uint4*)(hraw + hb + 8)   = pk8(raw0 + 8);
  *(uint4*)(hraw + hb + 64)  = pk8(raw1);
  *(uint4*)(hraw + hb + 72)  = pk8(raw1 + 8);
  *(uint4*)(hraw + hb + 128) = pk8(raw2);
  *(uint4*)(hraw + hb + 136) = pk8(raw2 + 8);
  sum   += __shfl_xor(sum,1,4);   sum   += __shfl_xor(sum,2,4);
  sumsq += __shfl_xor(sumsq,1,4); sumsq += __shfl_xor(sumsq,2,4);
  if (l4 == 0){
    const float mean = sum * (1.f/192.f);
    float var = sumsq * (1.f/192.f) - mean*mean;
    var = fmaxf(var, 0.f);
    const float rstd = rsqrtf(var + 1e-6f);
    float2 st; st.x = rstd; st.y = mean * rstd;
    tstat[wid*64 + tk] = st;
  }
}
__global__ __launch_bounds__(256,4) void k1f_dwt(const void* xv, bf16* llb, bf16* hraw,
                                                 float2* tstat, const int* flag){
  if (*flag) k1f_body<true>(xv, llb, hraw, tstat);
  else       k1f_body<false>(xv, llb, hraw, tstat);
}

// ---------------- K2: gap (bf16 ll, vectorized) ----------------
__global__ __launch_bounds__(256) void k2_gap(const bf16* llb, float* gap){
  const int bc = blockIdx.x;                            // 0..127
  const uint4* p = (const uint4*)(llb + ((long)bc << 16));
  float s = 0.f;
  for (int i = threadIdx.x; i < 8192; i += 256){
    const uint4 v = p[i];
    s += __uint_as_float(v.x << 16) + __uint_as_float(v.x & 0xffff0000u);
    s += __uint_as_float(v.y << 16) + __uint_as_float(v.y & 0xffff0000u);
    s += __uint_as_float(v.z << 16) + __uint_as_float(v.z & 0xffff0000u);
    s += __uint_as_float(v.w << 16) + __uint_as_float(v.w & 0xffff0000u);
  }
  __shared__ float red[256];
  red[threadIdx.x] = s; __syncthreads();
  for (int st = 128; st > 0; st >>= 1){
    if (threadIdx.x < st) red[threadIdx.x] += red[threadIdx.x + st];
    __syncthreads();
  }
  if (threadIdx.x == 0) gap[bc] = red[0] * (1.f / 65536.f);
}

// ---------------- K3: cross MLP ----------------
__global__ __launch_bounds__(256) void k3_cross(const float* pf, const float* gap,
                                                float* amul, float* cval){
  __shared__ float t1[B2][48];
  __shared__ float g[B2][64];
  const int tid = threadIdx.x;
  if (tid < 128) g[tid >> 6][tid & 63] = gap[tid];
  __syncthreads();
  if (tid < 96){
    const int b = tid / 48, j = tid % 48;
    float s = 0.f;
    const float* w = pf + P_CG1 + j * 64;
    for (int c = 0; c < 64; ++c) s += w[c] * g[b][c];
    t1[b][j] = gelu_f(s);
  }
  __syncthreads();
  const float gm = pf[P_GM], gc = pf[P_GC];
  for (int o = tid; o < B2 * C3; o += 256){
    const int b = o / C3, ch = o % C3;
    float s = 0.f;
    const float* w = pf + P_CG2 + ch * 48;
    for (int j = 0; j < 48; ++j) s += w[j] * t1[b][j];
    const float cr = 1.f / (1.f + expf(-s));
    const float c = gc * (cr - 0.5f) * 2.f;
    cval[o] = c;
    amul[o] = gm * (1.f + c);
  }
}

// ---------------- K6f: fused dwconv3+gelu + 1x1 MFMA -> dllw (window layout) ----------------
__global__ __launch_bounds__(256,4) void k6f_aux(const bf16* llb, const float* pf,
                                                 const bf16* wpw, bf16* dllw){
  __shared__ __align__(16) bf16 t[64*72];
  const int wid = blockIdx.x;
  const int b  = wid >> 10;
  const int wh = (wid >> 5) & 31;
  const int ww = wid & 31;
  const int tid = threadIdx.x;
  const int tok = tid & 63, cgrp = tid >> 6;
  const int wi = tok >> 3, wj = tok & 7;
  const int h2 = (wh*8 + wi + 4) & 255;
  const int w2 = (ww*8 + wj + 4) & 255;
#pragma unroll
  for (int cc = 0; cc < 16; ++cc){
    const int c = cgrp*16 + cc;
    const float* wk = pf + P_AUXDW + c*9;
    const long plane = (long)(b*64 + c) << 16;
    float s = 0.f;
#pragma unroll
    for (int ky = 0; ky < 3; ++ky){
      const int y = h2 + ky - 1;
      if (y < 0 || y > 255) continue;
#pragma unroll
      for (int kx = 0; kx < 3; ++kx){
        const int xx = w2 + kx - 1;
        if (xx < 0 || xx > 255) continue;
        s += wk[ky*3 + kx] * __bfloat162float(llb[plane + ((long)y << 8) + xx]);
      }
    }
    t[tok*72 + c] = __float2bfloat16(gelu_f(s));
  }
  __syncthreads();
  const int wv = tid >> 6, l = tid & 63, lr = l & 15, lg = l >> 4;
  const f4v fz = {0.f,0.f,0.f,0.f};
  f4v acc[4];
#pragma unroll
  for (int nt = 0; nt < 4; ++nt) acc[nt] = fz;
#pragma unroll
  for (int ks = 0; ks < 2; ++ks){
    const s8v a = *(const s8v*)(t + (wv*16+lr)*72 + ks*32 + lg*8);
#pragma unroll
    for (int nt = 0; nt < 4; ++nt){
      const s8v bfr = *(const s8v*)(wpw + (nt*16+lr)*64 + ks*32 + lg*8);
      acc[nt] = MFMA16(a, bfr, acc[nt]);
    }
  }
  const float ga = pf[P_GA];
#pragma unroll
  for (int nt = 0; nt < 4; ++nt)
#pragma unroll
    for (int i = 0; i < 4; ++i){
      const int row = wv*16 + lg*4 + i;
      dllw[((long)wid*64 + row)*64 + nt*16 + lr] = __float2bfloat16(ga * acc[nt][i]);
    }
}

// ---------------- K4: MFMA window attention (LN folded into weights) ----------------
// One block per window, heads sequential. LDS (40448 B -> 4 blocks/CU):
//  rawt [64][200] @0 (25600)
//  bq [64][40] @25600, bk [64][40] @30720, vtb swizzled [32][64] @35840 (4096)
//  bp [64][72] overlays bq/bk @25600
//  sstat float2[64] @39936
__global__ __launch_bounds__(256,4) void k4_attn(const bf16* hraw, const float2* tstat,
                                                 const bf16* wqkvF, const float* s12,
                                                 const float* bias6, bf16* wout){
  __shared__ __align__(16) char sm[40448];
  bf16* rawt = (bf16*)sm;
  bf16* bq   = (bf16*)(sm + 25600);
  bf16* bk   = (bf16*)(sm + 30720);
  char* vtb  = sm + 35840;
  bf16* bp   = (bf16*)(sm + 25600);
  float2* sstat = (float2*)(sm + 39936);
  const int wid = blockIdx.x;
  const int tid = threadIdx.x;

  {
    const uint4* hsrc = (const uint4*)(hraw + (long)wid * 12288);
    for (int i2 = tid; i2 < 1536; i2 += 256)
      *(uint4*)(rawt + (i2/24)*200 + (i2%24)*8) = hsrc[i2];
    if (tid < 64) sstat[tid] = tstat[wid*64 + tid];
  }
  __syncthreads();

  const int wv = tid >> 6, l = tid & 63, lr = l & 15, lg = l >> 4;
  const int mh = wv & 1, nh = wv >> 1;
  const f4v fz = {0.f,0.f,0.f,0.f};
  const float scale = 0.17677669529663687f;

  for (int h = 0; h < HEADS; ++h){
    // ---- qkv GEMM on raw high, wave (mh, nh) ----
    f4v acc[3][2];
#pragma unroll
    for (int p = 0; p < 3; ++p){ acc[p][0] = fz; acc[p][1] = fz; }
#pragma unroll
    for (int ks = 0; ks < 6; ++ks){
      const int k0 = ks*32;
      const s8v a0 = *(const s8v*)(rawt + (mh*32+lr)*200 + k0 + lg*8);
      const s8v a1 = *(const s8v*)(rawt + (mh*32+16+lr)*200 + k0 + lg*8);
#pragma unroll
      for (int p = 0; p < 3; ++p){
        const int ocol = p*192 + h*32 + nh*16 + lr;
        const s8v bfr = *(const s8v*)(wqkvF + ocol*192 + k0 + lg*8);
        acc[p][0] = MFMA16(a0, bfr, acc[p][0]);
        acc[p][1] = MFMA16(a1, bfr, acc[p][1]);
      }
    }
    // epilogue: v = rstd*acc - mu*rstd*S1 + S2
#pragma unroll
    for (int p = 0; p < 3; ++p){
      const int ocol = p*192 + h*32 + nh*16 + lr;
      const float s1v = s12[ocol], s2v = s12[576 + ocol];
#pragma unroll
      for (int mt = 0; mt < 2; ++mt)
#pragma unroll
        for (int i = 0; i < 4; ++i){
          const int row = mh*32 + mt*16 + lg*4 + i;
          const float2 st = sstat[row];
          const float v = st.x*acc[p][mt][i] - st.y*s1v + s2v;
          if (p == 0)      bq[row*40 + nh*16 + lr] = __float2bfloat16(v*scale);
          else if (p == 1) bk[row*40 + nh*16 + lr] = __float2bfloat16(v);
          else {
            const int d = nh*16 + lr;
            *(bf16*)(vtb + ((d*128 + row*2) ^ ((d&7)<<4))) = __float2bfloat16(v);
          }
        }
    }
    __syncthreads();

    // ---- S + softmax, wave -> M-tile wv ----
    f4v sacc[4];
    {
      const s8v a = *(const s8v*)(bq + (wv*16+lr)*40 + lg*8);
#pragma unroll
      for (int nt = 0; nt < 4; ++nt){
        const s8v bfr = *(const s8v*)(bk + (nt*16+lr)*40 + lg*8);
        sacc[nt] = MFMA16(a, bfr, fz);
      }
    }
    float pvv[4][4];
#pragma unroll
    for (int i = 0; i < 4; ++i){
      const int row = wv*16 + lg*4 + i;
      float v[4]; float mx = -1e30f;
#pragma unroll
      for (int nt = 0; nt < 4; ++nt){
        v[nt] = sacc[nt][i] + bias6[h*4096 + row*64 + nt*16 + lr];
        mx = fmaxf(mx, v[nt]);
      }
      mx = fmaxf(mx, __shfl_xor(mx, 1, 16));
      mx = fmaxf(mx, __shfl_xor(mx, 2, 16));
      mx = fmaxf(mx, __shfl_xor(mx, 4, 16));
      mx = fmaxf(mx, __shfl_xor(mx, 8, 16));
      float s = 0.f;
#pragma unroll
      for (int nt = 0; nt < 4; ++nt){ v[nt] = __expf(v[nt]-mx); s += v[nt]; }
      s += __shfl_xor(s, 1, 16);
      s += __shfl_xor(s, 2, 16);
      s += __shfl_xor(s, 4, 16);
      s += __shfl_xor(s, 8, 16);
      const float inv = 1.f/s;
#pragma unroll
      for (int nt = 0; nt < 4; ++nt) pvv[i][nt] = v[nt]*inv;
    }
    __syncthreads();   // bq/bk reads done before P overlays

    // ---- P write + PV, wave -> M-tile wv ----
#pragma unroll
    for (int i = 0; i < 4; ++i){
      const int row = wv*16 + lg*4 + i;
#pragma unroll
      for (int nt = 0; nt < 4; ++nt)
        bp[row*72 + nt*16 + lr] = __float2bfloat16(pvv[i][nt]);
    }
    f4v oacc[2] = {fz, fz};
#pragma unroll
    for (int ks2 = 0; ks2 < 2; ++ks2){
      const s8v a = *(const s8v*)(bp + (wv*16+lr)*72 + ks2*32 + lg*8);
#pragma unroll
      for (int nn = 0; nn < 2; ++nn){
        const int d = nn*16 + lr;
        const s8v bfr = *(const s8v*)(vtb + ((d*128 + (ks2*32+lg*8)*2) ^ ((d&7)<<4)));
        oacc[nn] = MFMA16(a, bfr, oacc[nn]);
      }
    }
#pragma unroll
    for (int nn = 0; nn < 2; ++nn)
#pragma unroll
      for (int i = 0; i < 4; ++i){
        const int row = wv*16 + lg*4 + i;
        wout[((long)wid*64 + row)*192 + h*32 + nn*16 + lr] = __float2bfloat16(oacc[nn][i]);
      }
    __syncthreads();   // before next head overwrites bq/bk/vtb
  }
}

// ---------------- K5: proj MFMA + combine + IWT + out-conv MFMA ----------------
template<bool ISF>
__device__ void k5f_body(const bf16* wout, const bf16* hraw, const bf16* wproj,
                         const float* pf, const float* amul, const float* cval,
                         const bf16* dllw, const bf16* wpo, void* out, char* sm){
  bf16* bufA = (bf16*)sm;            // [64][200] wout tile -> combined high delta
  bf16* bufC = (bf16*)(sm + 25600);  // [64][200] hraw staging (consumed in combine)
  bf16* yb   = (bf16*)(sm + 25600);  // [256][72] y (overlays bufC after sync)
  const int wid = blockIdx.x;
  const int b  = wid >> 10;
  const int wh = (wid >> 5) & 31;
  const int ww = wid & 31;
  const int tid = threadIdx.x;

  {
    const uint4* hsrc = (const uint4*)(hraw + (long)wid * 12288);
    const uint4* wsrc = (const uint4*)(wout + (long)wid * 12288);
    for (int i2 = tid; i2 < 1536; i2 += 256){
      const int t = i2/24, c8 = (i2%24)*8;
      *(uint4*)(bufC + t*200 + c8) = hsrc[i2];
      *(uint4*)(bufA + t*200 + c8) = wsrc[i2];
    }
  }
  __syncthreads();

  const int wv = tid >> 6, l = tid & 63, lr = l & 15, lg = l >> 4;
  const f4v fz = {0.f,0.f,0.f,0.f};

  // proj MFMA (wave wv: cols 48*wv .. +47)
  f4v acc[3][4];
#pragma unroll
  for (int nt = 0; nt < 3; ++nt)
#pragma unroll
    for (int mt = 0; mt < 4; ++mt) acc[nt][mt] = fz;
#pragma unroll
  for (int ks = 0; ks < 6; ++ks){
    const int k0 = ks*32;
    s8v a[4];
#pragma unroll
    for (int mt = 0; mt < 4; ++mt)
      a[mt] = *(const s8v*)(bufA + (mt*16+lr)*200 + k0 + lg*8);
#pragma unroll
    for (int nt = 0; nt < 3; ++nt){
      const int ocol = (wv*3+nt)*16 + lr;
      const s8v bfr = *(const s8v*)(wproj + ocol*192 + k0 + lg*8);
#pragma unroll
      for (int mt = 0; mt < 4; ++mt) acc[nt][mt] = MFMA16(a[mt], bfr, acc[nt][mt]);
    }
  }
  // combine with amul/cval + raw high
  float dval[3][4][4];
#pragma unroll
  for (int nt = 0; nt < 3; ++nt){
    const int col = (wv*3+nt)*16 + lr;
    const int bc = b*192 + col;
    const float am = amul[bc], cv = cval[bc], pb = pf[P_PROJB + col];
#pragma unroll
    for (int mt = 0; mt < 4; ++mt)
#pragma unroll
      for (int i = 0; i < 4; ++i){
        const int row = mt*16 + lg*4 + i;
        const float hv = __bfloat162float(bufC[row*200 + col]);
        dval[nt][mt][i] = am*(acc[nt][mt][i] + pb) + cv*hv;
      }
  }
  __syncthreads();
#pragma unroll
  for (int nt = 0; nt < 3; ++nt){
    const int col = (wv*3+nt)*16 + lr;
#pragma unroll
    for (int mt = 0; mt < 4; ++mt)
#pragma unroll
      for (int i = 0; i < 4; ++i)
        bufA[(mt*16+lg*4+i)*200 + col] = __float2bfloat16(dval[nt][mt][i]);
  }
  __syncthreads();

  // IWT per token -> y [256][72] (rows m = pos*64 + tok)
  const int tok = tid & 63;
  const int cgrp = tid >> 6;
  {
    const int c0 = cgrp*16;
#pragma unroll
    for (int cc = 0; cc < 16; cc += 2){
      const int c = c0 + cc;
      float e[4][2];
#pragma unroll
      for (int j = 0; j < 2; ++j){
        const float dl = __bfloat162float(dllw[((long)wid*64 + tok)*64 + c + j]);
        const float hl = __bfloat162float(bufA[tok*200 + c + j]);
        const float lh = __bfloat162float(bufA[tok*200 + 64 + c + j]);
        const float hh = __bfloat162float(bufA[tok*200 + 128 + c + j]);
        e[0][j] = 0.5f*(dl - hl - lh + hh);
        e[1][j] = 0.5f*(dl - hl + lh - hh);
        e[2][j] = 0.5f*(dl + hl - lh - hh);
        e[3][j] = 0.5f*(dl + hl + lh + hh);
      }
#pragma unroll
      for (int pos = 0; pos < 4; ++pos)
        *(unsigned*)(yb + (pos*64 + tok)*72 + c) = pk2(e[pos][0], e[pos][1]);
    }
  }
  __syncthreads();

  // out-conv MFMA: [256 x 64] = y[256 x 64] * po^T, wave -> 4 M-tiles
  f4v oacc[4][4];
#pragma unroll
  for (int mtl = 0; mtl < 4; ++mtl)
#pragma unroll
    for (int nt = 0; nt < 4; ++nt) oacc[mtl][nt] = fz;
#pragma unroll
  for (int ks = 0; ks < 2; ++ks){
    const int k0 = ks*32;
    s8v a[4];
#pragma unroll
    for (int mtl = 0; mtl < 4; ++mtl)
      a[mtl] = *(const s8v*)(yb + ((wv*4+mtl)*16+lr)*72 + k0 + lg*8);
#pragma unroll
    for (int nt = 0; nt < 4; ++nt){
      const s8v bfr = *(const s8v*)(wpo + (nt*16+lr)*64 + k0 + lg*8);
#pragma unroll
      for (int mtl = 0; mtl < 4; ++mtl) oacc[mtl][nt] = MFMA16(a[mtl], bfr, oacc[mtl][nt]);
    }
  }
#pragma unroll
  for (int mtl = 0; mtl < 4; ++mtl)
#pragma unroll
    for (int i = 0; i < 4; ++i){
      const int m = (wv*4+mtl)*16 + lg*4 + i;
      const int pos = m >> 6, tk = m & 63;
      const int wi = tk >> 3, wj = tk & 7;
      const int h2 = (wh*8 + wi + 4) & 255;
      const int w2 = (ww*8 + wj + 4) & 255;
      const long pb = ((long)(b*64)*512 + 2*h2 + (pos & 1))*512 + 2*w2 + (pos >> 1);
#pragma unroll
      for (int nt = 0; nt < 4; ++nt){
        const int o = nt*16 + lr;
        ST<ISF>(out, pb + (long)o*262144, oacc[mtl][nt][i]);
      }
    }
}
__global__ __launch_bounds__(256,2) void k5_fused(const bf16* wout, const bf16* hraw,
                                                  const bf16* wproj, const float* pf,
                                                  const float* amul, const float* cval,
                                                  const bf16* dllw, const bf16* wpo,
                                                  void* out, const int* flag){
  __shared__ __align__(16) char sm5[62464];
  if (*flag) k5f_body<true>(wout, hraw, wproj, pf, amul, cval, dllw, wpo, out, sm5);
  else       k5f_body<false>(wout, hraw, wproj, pf, amul, cval, dllw, wpo, out, sm5);
}

// ---------------- launcher ----------------
extern "C" void kernel_launch(void* const* d_in, const int* in_sizes, int n_in,
                              void* d_out, int out_size, void* d_ws, size_t ws_size,
                              hipStream_t stream){
  char* ws = (char*)d_ws;
  int*   flag = (int*)(ws + WS_FLAG);
  float* pf   = (float*)(ws + WS_PARAMS);
  float* gap  = (float*)(ws + WS_GAP);
  float* amul = (float*)(ws + WS_AMUL);
  float* cval = (float*)(ws + WS_CVAL);
  float2* tstat=(float2*)(ws + WS_TSTAT);
  bf16*  llb  = (bf16*)(ws + WS_LL);
  bf16*  dllw = (bf16*)(ws + WS_DLLW);
  bf16*  wout = (bf16*)(ws + WS_WOUT);
  bf16*  hraw = (bf16*)(ws + WS_HRAW);
  bf16*  wqkvF= (bf16*)(ws + WS_WQKV);
  bf16*  wproj= (bf16*)(ws + WS_WPROJ);
  bf16*  wpw  = (bf16*)(ws + WS_WPW);
  bf16*  wpo  = (bf16*)(ws + WS_WPO);
  float* s12  = (float*)(ws + WS_S12);
  float* bias6= (float*)(ws + WS_BIAS6);
  const int* rpi = (const int*)d_in[16];

  detect_kernel<<<1, 256, 0, stream>>>(d_in[0], flag);

  PP pp;
  const int pidx[15] = {1,2,3,4,5,6,7,8,9,10,11,12,13,14,15};
  const int poff[15] = {P_NORMW,P_NORMB,P_QKVW,P_QKVB,P_PROJW,P_PROJB,P_RPB,
                        P_AUXDW,P_AUXPW,P_CG1,P_CG2,P_PO,P_GM,P_GA,P_GC};
  for (int q = 0; q < 15; q++){
    pp.src[q] = d_in[pidx[q]];
    pp.dst[q] = pf + poff[q];
    pp.n[q]   = in_sizes[pidx[q]];
  }
  convert_params<<<15, 256, 0, stream>>>(pp, flag);
  kw_convert<<<704, 256, 0, stream>>>(pf, rpi, wqkvF, wproj, wpw, wpo, bias6);
  k0d_s12  <<<3,   256, 0, stream>>>(pf, s12);

  k1f_dwt<<<NWIN, 256, 0, stream>>>(d_in[0], llb, hraw, tstat, flag);
  k2_gap <<<128,  256, 0, stream>>>(llb, gap);
  k3_cross<<<1,   256, 0, stream>>>(pf, gap, amul, cval);
  k6f_aux<<<NWIN, 256, 0, stream>>>(llb, pf, wpw, dllw);
  k4_attn<<<NWIN, 256, 0, stream>>>(hraw, tstat, wqkvF, s12, bias6, wout);
  k5_fused<<<NWIN, 256, 0, stream>>>(wout, hraw, wproj, pf, amul, cval, dllw, wpo, d_out, flag);
}

// Round 6
// 610.873 us; speedup vs baseline: 3.7716x; 1.2501x over previous
//
#include <hip/hip_runtime.h>
#include <hip/hip_bf16.h>
#include <math.h>

typedef __hip_bfloat16 bf16;
typedef short s8v __attribute__((ext_vector_type(8)));
typedef float f4v __attribute__((ext_vector_type(4)));
#define MFMA16(a,b,c) __builtin_amdgcn_mfma_f32_16x16x32_bf16(a,b,c,0,0,0)

// ---------------- problem constants ----------------
#define B2   2
#define C64  64
#define C3   192
#define HEADS 6
#define NWIN 2048   // 2 * 32 * 32 windows

// ---------------- param table offsets (floats) ----------------
#define P_NORMW 0
#define P_NORMB 192
#define P_QKVW  384
#define P_QKVB  110976
#define P_PROJW 111552
#define P_PROJB 148416
#define P_RPB   148608
#define P_AUXDW 149958
#define P_AUXPW 150534
#define P_CG1   154630
#define P_CG2   157702
#define P_PO    166918
#define P_GM    171014
#define P_GA    171015
#define P_GC    171016

// ---------------- workspace byte offsets ----------------
#define WS_FLAG   0
#define WS_PARAMS 256
#define WS_GAP    684544
#define WS_AMUL   685568
#define WS_CVAL   687616
#define WS_TSTAT  689664                   // float2 [2048*64]
#define WS_LL     1738240                  // bf16 [2][64][256][256]
#define WS_DLLW   18515456                 // bf16 [2048][64][64]  (window layout)
#define WS_WOUT   35292672                 // bf16 [2048][64][192] (-> dval in place)
#define WS_HRAW   85624320                 // bf16 [2048][64][192]
#define WS_WQKV   135955968                // bf16 [576][192]  (LN-folded)
#define WS_WPROJ  136177152                // bf16 [192][192]
#define WS_WPW    136250880                // bf16 [64][64]
#define WS_WPO    136259072                // bf16 [64][64]
#define WS_S12    136267264                // f32 S1[576], S2[576]
#define WS_BIAS6  136271872                // f32 [6][64][64]
// end = 136,370,176  (< 168.5 MB proven)

// ---------------- helpers ----------------
template<bool ISF>
__device__ __forceinline__ float LD(const void* p, long i){
  if constexpr (ISF) return ((const float*)p)[i];
  else return __bfloat162float(((const bf16*)p)[i]);
}
template<bool ISF>
__device__ __forceinline__ void ST(void* p, long i, float v){
  if constexpr (ISF) ((float*)p)[i] = v;
  else ((bf16*)p)[i] = __float2bfloat16(v);
}
__device__ __forceinline__ float gelu_f(float x){
  return 0.5f * x * (1.f + erff(x * 0.70710678118654752f));
}
__device__ __forceinline__ float bfu(unsigned short u){
  return __uint_as_float(((unsigned)u) << 16);
}
__device__ __forceinline__ unsigned pk2(float a, float b){
  return (unsigned)__bfloat16_as_ushort(__float2bfloat16(a)) |
         ((unsigned)__bfloat16_as_ushort(__float2bfloat16(b)) << 16);
}
__device__ __forceinline__ uint4 pk8(const float* v){
  uint4 r;
  r.x = pk2(v[0], v[1]); r.y = pk2(v[2], v[3]);
  r.z = pk2(v[4], v[5]); r.w = pk2(v[6], v[7]);
  return r;
}

// ---------------- K0a: dtype detect ----------------
__global__ __launch_bounds__(256) void detect_kernel(const void* x, int* flag){
  __shared__ int wildcnt;
  if (threadIdx.x == 0) wildcnt = 0;
  __syncthreads();
  const unsigned short* u = (const unsigned short*)x;
  int wild = 0;
  for (int i = threadIdx.x; i < 2048; i += 256){
    unsigned int v = ((unsigned int)u[i]) << 16;
    float f = __uint_as_float(v);
    float a = fabsf(f);
    if (!(a < 1e8f) || (a > 0.f && a < 1e-8f)) wild++;
  }
  atomicAdd(&wildcnt, wild);
  __syncthreads();
  if (threadIdx.x == 0) *flag = (wildcnt > 100) ? 1 : 0;  // 1 = fp32 underlying
}

// ---------------- K0b: param convert ----------------
struct PP { const void* src[15]; float* dst[15]; int n[15]; };
__global__ __launch_bounds__(256) void convert_params(PP pp, const int* flag){
  const int id = blockIdx.x;
  const int n = pp.n[id];
  const void* s = pp.src[id];
  float* d = pp.dst[id];
  const bool isf = (*flag) != 0;
  for (int i = threadIdx.x; i < n; i += 256)
    d[i] = isf ? ((const float*)s)[i] : __bfloat162float(((const bf16*)s)[i]);
}

// ---------------- K0c: bf16 weight tables (LN-folded) + bias6 ----------------
__global__ __launch_bounds__(256) void kw_convert(const float* pf, const int* rpi,
                                                  bf16* wqkvF, bf16* wproj,
                                                  bf16* wpw, bf16* wpo, float* bias6){
  const int i = blockIdx.x*256 + threadIdx.x;
  if (i < 110592){
    const int c = i % 192;
    wqkvF[i] = __float2bfloat16(pf[P_QKVW + i] * pf[P_NORMW + c]);
  } else if (i < 147456)  wproj[i-110592] = __float2bfloat16(pf[P_PROJW + (i-110592)]);
  else if (i < 151552)    wpw[i-147456]   = __float2bfloat16(pf[P_AUXPW + (i-147456)]);
  else if (i < 155648)    wpo[i-151552]   = __float2bfloat16(pf[P_PO + (i-151552)]);
  else if (i < 180224){
    const int j = i - 155648;
    const int hh = j >> 12, nm = j & 4095;
    bias6[j] = pf[P_RPB + rpi[nm]*6 + hh];
  }
}

// ---------------- K0d: S1/S2 rank-1 LN correction ----------------
__global__ __launch_bounds__(256) void k0d_s12(const float* pf, float* s12){
  const int o = blockIdx.x*256 + threadIdx.x;
  if (o >= 576) return;
  float s1 = 0.f, s2 = 0.f;
  for (int c = 0; c < 192; ++c){
    const float w = pf[P_QKVW + o*192 + c];
    s1 += w * pf[P_NORMW + c];
    s2 += w * pf[P_NORMB + c];
  }
  s12[o] = s1;
  s12[576 + o] = s2 + pf[P_QKVB + o];
}

// ---------------- K1f: single-pass DWT -> ll(bf16) + hraw + tstat ----------------
template<bool ISF>
__device__ void k1f_body(const void* xv, bf16* llb, bf16* hraw, float2* tstat){
  const int wid = blockIdx.x;
  const int b  = wid >> 10;
  const int wh = (wid >> 5) & 31;
  const int ww = wid & 31;
  const int tid = threadIdx.x;
  const int tk = tid >> 2, l4 = tid & 3;
  const int wi = tk >> 3, wj = tk & 7;
  const int h2 = (wh*8 + wi + 4) & 255;
  const int w2 = (ww*8 + wj + 4) & 255;
  const long pixbase = ((long)(2*h2) << 9) + 2*w2;
  const long llpix = ((long)h2 << 8) + w2;
  float raw0[16], raw1[16], raw2[16];
  float sum = 0.f, sumsq = 0.f;
#pragma unroll
  for (int cc = 0; cc < 16; ++cc){
    const int c = l4*16 + cc;
    const long base = ((long)(b*64 + c) << 18) + pixbase;
    const float a  = LD<ISF>(xv, base);
    const float bb = LD<ISF>(xv, base + 512);
    const float cr = LD<ISF>(xv, base + 1);
    const float dd = LD<ISF>(xv, base + 513);
    llb[((long)(b*64 + c) << 16) + llpix] = __float2bfloat16(0.5f*(a + bb + cr + dd));
    const float h0 = 0.5f*(-a - bb + cr + dd);
    const float h1 = 0.5f*(-a + bb - cr + dd);
    const float hh = 0.5f*( a - bb - cr + dd);
    raw0[cc] = h0; raw1[cc] = h1; raw2[cc] = hh;
    sum += h0 + h1 + hh;
    sumsq += h0*h0 + h1*h1 + hh*hh;
  }
  const long hb = ((long)wid*64 + tk)*192 + l4*16;
  *(uint4*)(hraw + hb)       = pk8(raw0);
  *(uint4*)(hraw + hb + 8)   = pk8(raw0 + 8);
  *(uint4*)(hraw + hb + 64)  = pk8(raw1);
  *(uint4*)(hraw + hb + 72)  = pk8(raw1 + 8);
  *(uint4*)(hraw + hb + 128) = pk8(raw2);
  *(uint4*)(hraw + hb + 136) = pk8(raw2 + 8);
  sum   += __shfl_xor(sum,1,4);   sum   += __shfl_xor(sum,2,4);
  sumsq += __shfl_xor(sumsq,1,4); sumsq += __shfl_xor(sumsq,2,4);
  if (l4 == 0){
    const float mean = sum * (1.f/192.f);
    float var = sumsq * (1.f/192.f) - mean*mean;
    var = fmaxf(var, 0.f);
    const float rstd = rsqrtf(var + 1e-6f);
    float2 st; st.x = rstd; st.y = mean * rstd;
    tstat[wid*64 + tk] = st;
  }
}
__global__ __launch_bounds__(256,4) void k1f_dwt(const void* xv, bf16* llb, bf16* hraw,
                                                 float2* tstat, const int* flag){
  if (*flag) k1f_body<true>(xv, llb, hraw, tstat);
  else       k1f_body<false>(xv, llb, hraw, tstat);
}

// ---------------- K2: gap (bf16 ll, vectorized) ----------------
__global__ __launch_bounds__(256) void k2_gap(const bf16* llb, float* gap){
  const int bc = blockIdx.x;                            // 0..127
  const uint4* p = (const uint4*)(llb + ((long)bc << 16));
  float s = 0.f;
  for (int i = threadIdx.x; i < 8192; i += 256){
    const uint4 v = p[i];
    s += __uint_as_float(v.x << 16) + __uint_as_float(v.x & 0xffff0000u);
    s += __uint_as_float(v.y << 16) + __uint_as_float(v.y & 0xffff0000u);
    s += __uint_as_float(v.z << 16) + __uint_as_float(v.z & 0xffff0000u);
    s += __uint_as_float(v.w << 16) + __uint_as_float(v.w & 0xffff0000u);
  }
  __shared__ float red[256];
  red[threadIdx.x] = s; __syncthreads();
  for (int st = 128; st > 0; st >>= 1){
    if (threadIdx.x < st) red[threadIdx.x] += red[threadIdx.x + st];
    __syncthreads();
  }
  if (threadIdx.x == 0) gap[bc] = red[0] * (1.f / 65536.f);
}

// ---------------- K3: cross MLP ----------------
__global__ __launch_bounds__(256) void k3_cross(const float* pf, const float* gap,
                                                float* amul, float* cval){
  __shared__ float t1[B2][48];
  __shared__ float g[B2][64];
  const int tid = threadIdx.x;
  if (tid < 128) g[tid >> 6][tid & 63] = gap[tid];
  __syncthreads();
  if (tid < 96){
    const int b = tid / 48, j = tid % 48;
    float s = 0.f;
    const float* w = pf + P_CG1 + j * 64;
    for (int c = 0; c < 64; ++c) s += w[c] * g[b][c];
    t1[b][j] = gelu_f(s);
  }
  __syncthreads();
  const float gm = pf[P_GM], gc = pf[P_GC];
  for (int o = tid; o < B2 * C3; o += 256){
    const int b = o / C3, ch = o % C3;
    float s = 0.f;
    const float* w = pf + P_CG2 + ch * 48;
    for (int j = 0; j < 48; ++j) s += w[j] * t1[b][j];
    const float cr = 1.f / (1.f + expf(-s));
    const float c = gc * (cr - 0.5f) * 2.f;
    cval[o] = c;
    amul[o] = gm * (1.f + c);
  }
}

// ---------------- K6f: fused dwconv3+gelu + 1x1 MFMA -> dllw (window layout) ----------------
__global__ __launch_bounds__(256,4) void k6f_aux(const bf16* llb, const float* pf,
                                                 const bf16* wpw, bf16* dllw){
  __shared__ __align__(16) bf16 t[64*72];
  const int wid = blockIdx.x;
  const int b  = wid >> 10;
  const int wh = (wid >> 5) & 31;
  const int ww = wid & 31;
  const int tid = threadIdx.x;
  const int tok = tid & 63, cgrp = tid >> 6;
  const int wi = tok >> 3, wj = tok & 7;
  const int h2 = (wh*8 + wi + 4) & 255;
  const int w2 = (ww*8 + wj + 4) & 255;
#pragma unroll
  for (int cc = 0; cc < 16; ++cc){
    const int c = cgrp*16 + cc;
    const float* wk = pf + P_AUXDW + c*9;
    const long plane = (long)(b*64 + c) << 16;
    float s = 0.f;
#pragma unroll
    for (int ky = 0; ky < 3; ++ky){
      const int y = h2 + ky - 1;
      if (y < 0 || y > 255) continue;
#pragma unroll
      for (int kx = 0; kx < 3; ++kx){
        const int xx = w2 + kx - 1;
        if (xx < 0 || xx > 255) continue;
        s += wk[ky*3 + kx] * __bfloat162float(llb[plane + ((long)y << 8) + xx]);
      }
    }
    t[tok*72 + c] = __float2bfloat16(gelu_f(s));
  }
  __syncthreads();
  const int wv = tid >> 6, l = tid & 63, lr = l & 15, lg = l >> 4;
  const f4v fz = {0.f,0.f,0.f,0.f};
  f4v acc[4];
#pragma unroll
  for (int nt = 0; nt < 4; ++nt) acc[nt] = fz;
#pragma unroll
  for (int ks = 0; ks < 2; ++ks){
    const s8v a = *(const s8v*)(t + (wv*16+lr)*72 + ks*32 + lg*8);
#pragma unroll
    for (int nt = 0; nt < 4; ++nt){
      const s8v bfr = *(const s8v*)(wpw + (nt*16+lr)*64 + ks*32 + lg*8);
      acc[nt] = MFMA16(a, bfr, acc[nt]);
    }
  }
  const float ga = pf[P_GA];
#pragma unroll
  for (int nt = 0; nt < 4; ++nt)
#pragma unroll
    for (int i = 0; i < 4; ++i){
      const int row = wv*16 + lg*4 + i;
      dllw[((long)wid*64 + row)*64 + nt*16 + lr] = __float2bfloat16(ga * acc[nt][i]);
    }
}

// ---------------- K4: MFMA window attention (LN folded into weights) ----------------
__global__ __launch_bounds__(256,4) void k4_attn(const bf16* hraw, const float2* tstat,
                                                 const bf16* wqkvF, const float* s12,
                                                 const float* bias6, bf16* wout){
  __shared__ __align__(16) char sm[40448];
  bf16* rawt = (bf16*)sm;
  bf16* bq   = (bf16*)(sm + 25600);
  bf16* bk   = (bf16*)(sm + 30720);
  char* vtb  = sm + 35840;
  bf16* bp   = (bf16*)(sm + 25600);
  float2* sstat = (float2*)(sm + 39936);
  const int wid = blockIdx.x;
  const int tid = threadIdx.x;

  {
    const uint4* hsrc = (const uint4*)(hraw + (long)wid * 12288);
    for (int i2 = tid; i2 < 1536; i2 += 256)
      *(uint4*)(rawt + (i2/24)*200 + (i2%24)*8) = hsrc[i2];
    if (tid < 64) sstat[tid] = tstat[wid*64 + tid];
  }
  __syncthreads();

  const int wv = tid >> 6, l = tid & 63, lr = l & 15, lg = l >> 4;
  const int mh = wv & 1, nh = wv >> 1;
  const f4v fz = {0.f,0.f,0.f,0.f};
  const float scale = 0.17677669529663687f;

  for (int h = 0; h < HEADS; ++h){
    f4v acc[3][2];
#pragma unroll
    for (int p = 0; p < 3; ++p){ acc[p][0] = fz; acc[p][1] = fz; }
#pragma unroll
    for (int ks = 0; ks < 6; ++ks){
      const int k0 = ks*32;
      const s8v a0 = *(const s8v*)(rawt + (mh*32+lr)*200 + k0 + lg*8);
      const s8v a1 = *(const s8v*)(rawt + (mh*32+16+lr)*200 + k0 + lg*8);
#pragma unroll
      for (int p = 0; p < 3; ++p){
        const int ocol = p*192 + h*32 + nh*16 + lr;
        const s8v bfr = *(const s8v*)(wqkvF + ocol*192 + k0 + lg*8);
        acc[p][0] = MFMA16(a0, bfr, acc[p][0]);
        acc[p][1] = MFMA16(a1, bfr, acc[p][1]);
      }
    }
#pragma unroll
    for (int p = 0; p < 3; ++p){
      const int ocol = p*192 + h*32 + nh*16 + lr;
      const float s1v = s12[ocol], s2v = s12[576 + ocol];
#pragma unroll
      for (int mt = 0; mt < 2; ++mt)
#pragma unroll
        for (int i = 0; i < 4; ++i){
          const int row = mh*32 + mt*16 + lg*4 + i;
          const float2 st = sstat[row];
          const float v = st.x*acc[p][mt][i] - st.y*s1v + s2v;
          if (p == 0)      bq[row*40 + nh*16 + lr] = __float2bfloat16(v*scale);
          else if (p == 1) bk[row*40 + nh*16 + lr] = __float2bfloat16(v);
          else {
            const int d = nh*16 + lr;
            *(bf16*)(vtb + ((d*128 + row*2) ^ ((d&7)<<4))) = __float2bfloat16(v);
          }
        }
    }
    __syncthreads();

    f4v sacc[4];
    {
      const s8v a = *(const s8v*)(bq + (wv*16+lr)*40 + lg*8);
#pragma unroll
      for (int nt = 0; nt < 4; ++nt){
        const s8v bfr = *(const s8v*)(bk + (nt*16+lr)*40 + lg*8);
        sacc[nt] = MFMA16(a, bfr, fz);
      }
    }
    float pvv[4][4];
#pragma unroll
    for (int i = 0; i < 4; ++i){
      const int row = wv*16 + lg*4 + i;
      float v[4]; float mx = -1e30f;
#pragma unroll
      for (int nt = 0; nt < 4; ++nt){
        v[nt] = sacc[nt][i] + bias6[h*4096 + row*64 + nt*16 + lr];
        mx = fmaxf(mx, v[nt]);
      }
      mx = fmaxf(mx, __shfl_xor(mx, 1, 16));
      mx = fmaxf(mx, __shfl_xor(mx, 2, 16));
      mx = fmaxf(mx, __shfl_xor(mx, 4, 16));
      mx = fmaxf(mx, __shfl_xor(mx, 8, 16));
      float s = 0.f;
#pragma unroll
      for (int nt = 0; nt < 4; ++nt){ v[nt] = __expf(v[nt]-mx); s += v[nt]; }
      s += __shfl_xor(s, 1, 16);
      s += __shfl_xor(s, 2, 16);
      s += __shfl_xor(s, 4, 16);
      s += __shfl_xor(s, 8, 16);
      const float inv = 1.f/s;
#pragma unroll
      for (int nt = 0; nt < 4; ++nt) pvv[i][nt] = v[nt]*inv;
    }
    __syncthreads();

#pragma unroll
    for (int i = 0; i < 4; ++i){
      const int row = wv*16 + lg*4 + i;
#pragma unroll
      for (int nt = 0; nt < 4; ++nt)
        bp[row*72 + nt*16 + lr] = __float2bfloat16(pvv[i][nt]);
    }
    f4v oacc[2] = {fz, fz};
#pragma unroll
    for (int ks2 = 0; ks2 < 2; ++ks2){
      const s8v a = *(const s8v*)(bp + (wv*16+lr)*72 + ks2*32 + lg*8);
#pragma unroll
      for (int nn = 0; nn < 2; ++nn){
        const int d = nn*16 + lr;
        const s8v bfr = *(const s8v*)(vtb + ((d*128 + (ks2*32+lg*8)*2) ^ ((d&7)<<4)));
        oacc[nn] = MFMA16(a, bfr, oacc[nn]);
      }
    }
#pragma unroll
    for (int nn = 0; nn < 2; ++nn)
#pragma unroll
      for (int i = 0; i < 4; ++i){
        const int row = wv*16 + lg*4 + i;
        wout[((long)wid*64 + row)*192 + h*32 + nn*16 + lr] = __float2bfloat16(oacc[nn][i]);
      }
    __syncthreads();
  }
}

// ---------------- K5: proj MFMA + combine -> dval in-place (window layout) ----------------
__global__ __launch_bounds__(256,3) void k5_proj(bf16* wout, const bf16* hraw,
                                                 const bf16* wproj, const float* pf,
                                                 const float* amul, const float* cval){
  __shared__ __align__(16) bf16 bufA[64*200];   // wout tile
  __shared__ __align__(16) bf16 bufC[64*200];   // hraw tile
  const int wid = blockIdx.x;
  const int b  = wid >> 10;
  const int tid = threadIdx.x;

  {
    const uint4* hsrc = (const uint4*)(hraw + (long)wid * 12288);
    const uint4* wsrc = (const uint4*)(wout + (long)wid * 12288);
    for (int i2 = tid; i2 < 1536; i2 += 256){
      const int t = i2/24, c8 = (i2%24)*8;
      *(uint4*)(bufC + t*200 + c8) = hsrc[i2];
      *(uint4*)(bufA + t*200 + c8) = wsrc[i2];
    }
  }
  __syncthreads();

  const int wv = tid >> 6, l = tid & 63, lr = l & 15, lg = l >> 4;
  const f4v fz = {0.f,0.f,0.f,0.f};

  f4v acc[3][4];
#pragma unroll
  for (int nt = 0; nt < 3; ++nt)
#pragma unroll
    for (int mt = 0; mt < 4; ++mt) acc[nt][mt] = fz;
#pragma unroll
  for (int ks = 0; ks < 6; ++ks){
    const int k0 = ks*32;
    s8v a[4];
#pragma unroll
    for (int mt = 0; mt < 4; ++mt)
      a[mt] = *(const s8v*)(bufA + (mt*16+lr)*200 + k0 + lg*8);
#pragma unroll
    for (int nt = 0; nt < 3; ++nt){
      const int ocol = (wv*3+nt)*16 + lr;
      const s8v bfr = *(const s8v*)(wproj + ocol*192 + k0 + lg*8);
#pragma unroll
      for (int mt = 0; mt < 4; ++mt) acc[nt][mt] = MFMA16(a[mt], bfr, acc[nt][mt]);
    }
  }
  // combine + write dval in place (safe: only this block's tile, loads drained at barrier)
#pragma unroll
  for (int nt = 0; nt < 3; ++nt){
    const int col = (wv*3+nt)*16 + lr;
    const int bc = b*192 + col;
    const float am = amul[bc], cv = cval[bc], pb = pf[P_PROJB + col];
#pragma unroll
    for (int mt = 0; mt < 4; ++mt)
#pragma unroll
      for (int i = 0; i < 4; ++i){
        const int row = mt*16 + lg*4 + i;
        const float hv = __bfloat162float(bufC[row*200 + col]);
        wout[(long)wid*12288 + row*192 + col] =
          __float2bfloat16(am*(acc[nt][mt][i] + pb) + cv*hv);
      }
  }
}

// ---------------- K7: gather + IWT + out-conv MFMA + coalesced store ----------------
// block = (b, output row hh, half): 256 output pixels x 64 channels.
template<bool ISF>
__device__ void k7_body(const bf16* dvalw, const bf16* dllw, const bf16* wpo,
                        void* out, char* yp){
  const int blk = blockIdx.x;
  const int b = blk >> 10, hh = (blk >> 1) & 511, half = blk & 1;
  const int h2 = hh >> 1, posH = hh & 1;
  const int th = (h2 + 252) & 255;
  const int wh = th >> 3, wi = th & 7;
  const int tid = threadIdx.x;
  const int j = tid & 7;                  // 16B chunk (8 channels)
  // stage 256 pixels -> ypix [256][64] bf16, XOR-swizzled
#pragma unroll
  for (int pass = 0; pass < 8; ++pass){
    const int p = pass*32 + (tid >> 3);
    const int ww2 = half*256 + p;
    const int w2 = ww2 >> 1, posW = ww2 & 1;
    const int tw = (w2 + 252) & 255;
    const int ww = tw >> 3, wj = tw & 7;
    const int wid = b*1024 + wh*32 + ww;
    const int tok = wi*8 + wj;
    const long dvb = ((long)wid*64 + tok)*192 + j*8;
    const s8v hl8 = *(const s8v*)(dvalw + dvb);
    const s8v lh8 = *(const s8v*)(dvalw + dvb + 64);
    const s8v hh8 = *(const s8v*)(dvalw + dvb + 128);
    const s8v dl8 = *(const s8v*)(dllw + ((long)wid*64 + tok)*64 + j*8);
    const float s1 = posW ? 0.5f : -0.5f;
    const float s2 = posH ? 0.5f : -0.5f;
    const float s3 = posW == posH ? 0.5f : -0.5f;
    float e[8];
#pragma unroll
    for (int q = 0; q < 8; ++q)
      e[q] = 0.5f*bfu((unsigned short)dl8[q]) + s1*bfu((unsigned short)hl8[q])
           + s2*bfu((unsigned short)lh8[q]) + s3*bfu((unsigned short)hh8[q]);
    *(uint4*)(yp + ((p*128 + j*16) ^ ((p&7)<<4))) = pk8(e);
  }
  __syncthreads();
  // out-conv: A = wpo (channels), B = ypix (pixels); wave wv -> pixels [wv*64, +64)
  const int wv = tid >> 6, l = tid & 63, lr = l & 15, lg = l >> 4;
  const f4v fz = {0.f,0.f,0.f,0.f};
  f4v acc[4][4];
#pragma unroll
  for (int mt = 0; mt < 4; ++mt)
#pragma unroll
    for (int nt = 0; nt < 4; ++nt) acc[mt][nt] = fz;
#pragma unroll
  for (int ks = 0; ks < 2; ++ks){
    const int k0 = ks*32;
    s8v a[4];
#pragma unroll
    for (int mt = 0; mt < 4; ++mt)
      a[mt] = *(const s8v*)(wpo + (mt*16+lr)*64 + k0 + lg*8);
#pragma unroll
    for (int nt = 0; nt < 4; ++nt){
      const int prow = wv*64 + nt*16 + lr;
      const s8v bfr = *(const s8v*)(yp + ((prow*128 + (k0+lg*8)*2) ^ ((prow&7)<<4)));
#pragma unroll
      for (int mt = 0; mt < 4; ++mt) acc[mt][nt] = MFMA16(a[mt], bfr, acc[mt][nt]);
    }
  }
  const int px0 = half*256 + wv*64;
#pragma unroll
  for (int mt = 0; mt < 4; ++mt)
#pragma unroll
    for (int nt = 0; nt < 4; ++nt)
#pragma unroll
      for (int i = 0; i < 4; ++i){
        const int c = mt*16 + lg*4 + i;
        const long ob = ((long)(b*64 + c)*512 + hh)*512 + px0 + nt*16 + lr;
        ST<ISF>(out, ob, acc[mt][nt][i]);
      }
}
__global__ __launch_bounds__(256,4) void k7_out(const bf16* dvalw, const bf16* dllw,
                                                const bf16* wpo, void* out, const int* flag){
  __shared__ __align__(16) char yp[32768];
  if (*flag) k7_body<true>(dvalw, dllw, wpo, out, yp);
  else       k7_body<false>(dvalw, dllw, wpo, out, yp);
}

// ---------------- launcher ----------------
extern "C" void kernel_launch(void* const* d_in, const int* in_sizes, int n_in,
                              void* d_out, int out_size, void* d_ws, size_t ws_size,
                              hipStream_t stream){
  char* ws = (char*)d_ws;
  int*   flag = (int*)(ws + WS_FLAG);
  float* pf   = (float*)(ws + WS_PARAMS);
  float* gap  = (float*)(ws + WS_GAP);
  float* amul = (float*)(ws + WS_AMUL);
  float* cval = (float*)(ws + WS_CVAL);
  float2* tstat=(float2*)(ws + WS_TSTAT);
  bf16*  llb  = (bf16*)(ws + WS_LL);
  bf16*  dllw = (bf16*)(ws + WS_DLLW);
  bf16*  wout = (bf16*)(ws + WS_WOUT);
  bf16*  hraw = (bf16*)(ws + WS_HRAW);
  bf16*  wqkvF= (bf16*)(ws + WS_WQKV);
  bf16*  wproj= (bf16*)(ws + WS_WPROJ);
  bf16*  wpw  = (bf16*)(ws + WS_WPW);
  bf16*  wpo  = (bf16*)(ws + WS_WPO);
  float* s12  = (float*)(ws + WS_S12);
  float* bias6= (float*)(ws + WS_BIAS6);
  const int* rpi = (const int*)d_in[16];

  detect_kernel<<<1, 256, 0, stream>>>(d_in[0], flag);

  PP pp;
  const int pidx[15] = {1,2,3,4,5,6,7,8,9,10,11,12,13,14,15};
  const int poff[15] = {P_NORMW,P_NORMB,P_QKVW,P_QKVB,P_PROJW,P_PROJB,P_RPB,
                        P_AUXDW,P_AUXPW,P_CG1,P_CG2,P_PO,P_GM,P_GA,P_GC};
  for (int q = 0; q < 15; q++){
    pp.src[q] = d_in[pidx[q]];
    pp.dst[q] = pf + poff[q];
    pp.n[q]   = in_sizes[pidx[q]];
  }
  convert_params<<<15, 256, 0, stream>>>(pp, flag);
  kw_convert<<<704, 256, 0, stream>>>(pf, rpi, wqkvF, wproj, wpw, wpo, bias6);
  k0d_s12  <<<3,   256, 0, stream>>>(pf, s12);

  k1f_dwt<<<NWIN, 256, 0, stream>>>(d_in[0], llb, hraw, tstat, flag);
  k2_gap <<<128,  256, 0, stream>>>(llb, gap);
  k3_cross<<<1,   256, 0, stream>>>(pf, gap, amul, cval);
  k6f_aux<<<NWIN, 256, 0, stream>>>(llb, pf, wpw, dllw);
  k4_attn<<<NWIN, 256, 0, stream>>>(hraw, tstat, wqkvF, s12, bias6, wout);
  k5_proj<<<NWIN, 256, 0, stream>>>(wout, hraw, wproj, pf, amul, cval);
  k7_out <<<2048, 256, 0, stream>>>(wout, dllw, wpo, d_out, flag);
}

// Round 7
// 470.548 us; speedup vs baseline: 4.8963x; 1.2982x over previous
//
#include <hip/hip_runtime.h>
#include <hip/hip_bf16.h>
#include <math.h>

typedef __hip_bfloat16 bf16;
typedef short s8v __attribute__((ext_vector_type(8)));
typedef float f4v __attribute__((ext_vector_type(4)));
#define MFMA16(a,b,c) __builtin_amdgcn_mfma_f32_16x16x32_bf16(a,b,c,0,0,0)

// ---------------- problem constants ----------------
#define B2   2
#define C64  64
#define C3   192
#define HEADS 6
#define NWIN 2048   // 2 * 32 * 32 windows

// ---------------- param table offsets (floats) ----------------
#define P_NORMW 0
#define P_NORMB 192
#define P_QKVW  384
#define P_QKVB  110976
#define P_PROJW 111552
#define P_PROJB 148416
#define P_RPB   148608
#define P_AUXDW 149958
#define P_AUXPW 150534
#define P_CG1   154630
#define P_CG2   157702
#define P_PO    166918
#define P_GM    171014
#define P_GA    171015
#define P_GC    171016

// ---------------- workspace byte offsets ----------------
#define WS_FLAG   0
#define WS_PARAMS 256
#define WS_GAP    684544
#define WS_AMUL   685568
#define WS_CVAL   687616
#define WS_TSTAT  689664                   // float2 [2048*64]
#define WS_LL     1738240                  // bf16 [2][64][256][256]
#define WS_DLLW   18515456                 // bf16 [2048][64][64]  (window layout)
#define WS_WOUT   35292672                 // bf16 [2048][64][192] (-> dval in place)
#define WS_HRAW   85624320                 // bf16 [2048][64][192]
#define WS_WQKV   135955968                // bf16 [576][192]  (LN-folded)
#define WS_WPROJ  136177152                // bf16 [192][192]
#define WS_WPW    136250880                // bf16 [64][64]
#define WS_WPO    136259072                // bf16 [64][64]
#define WS_S12    136267264                // f32 S1[576], S2[576]
#define WS_BIAS6  136271872                // f32 [6][64][64]
// end = 136,370,176  (< 168.5 MB proven)

// ---------------- helpers ----------------
template<bool ISF>
__device__ __forceinline__ float LD(const void* p, long i){
  if constexpr (ISF) return ((const float*)p)[i];
  else return __bfloat162float(((const bf16*)p)[i]);
}
template<bool ISF>
__device__ __forceinline__ float2 LD2(const void* p, long i){   // elems i, i+1 (i even)
  if constexpr (ISF) return *(const float2*)((const float*)p + i);
  else {
    const ushort2 u = *(const ushort2*)((const bf16*)p + i);
    float2 r; r.x = __uint_as_float(((unsigned)u.x) << 16);
    r.y = __uint_as_float(((unsigned)u.y) << 16);
    return r;
  }
}
template<bool ISF>
__device__ __forceinline__ void ST(void* p, long i, float v){
  if constexpr (ISF) ((float*)p)[i] = v;
  else ((bf16*)p)[i] = __float2bfloat16(v);
}
__device__ __forceinline__ float gelu_f(float x){
  return 0.5f * x * (1.f + erff(x * 0.70710678118654752f));
}
__device__ __forceinline__ float bfu(unsigned short u){
  return __uint_as_float(((unsigned)u) << 16);
}
__device__ __forceinline__ unsigned pk2(float a, float b){
  return (unsigned)__bfloat16_as_ushort(__float2bfloat16(a)) |
         ((unsigned)__bfloat16_as_ushort(__float2bfloat16(b)) << 16);
}
__device__ __forceinline__ uint4 pk8(const float* v){
  uint4 r;
  r.x = pk2(v[0], v[1]); r.y = pk2(v[2], v[3]);
  r.z = pk2(v[4], v[5]); r.w = pk2(v[6], v[7]);
  return r;
}

// ---------------- K0a: dtype detect ----------------
__global__ __launch_bounds__(256) void detect_kernel(const void* x, int* flag){
  __shared__ int wildcnt;
  if (threadIdx.x == 0) wildcnt = 0;
  __syncthreads();
  const unsigned short* u = (const unsigned short*)x;
  int wild = 0;
  for (int i = threadIdx.x; i < 2048; i += 256){
    unsigned int v = ((unsigned int)u[i]) << 16;
    float f = __uint_as_float(v);
    float a = fabsf(f);
    if (!(a < 1e8f) || (a > 0.f && a < 1e-8f)) wild++;
  }
  atomicAdd(&wildcnt, wild);
  __syncthreads();
  if (threadIdx.x == 0) *flag = (wildcnt > 100) ? 1 : 0;  // 1 = fp32 underlying
}

// ---------------- K0b: param convert (grid-strided over all params) ----------------
struct PP { const void* src[15]; float* dst[15]; int n[15]; };
__global__ __launch_bounds__(256) void convert_params(PP pp, const int* flag){
  const bool isf = (*flag) != 0;
  const int gid = blockIdx.x*256 + threadIdx.x;
  const int gsz = gridDim.x*256;
#pragma unroll
  for (int q = 0; q < 15; q++){
    const int n = pp.n[q];
    const void* s = pp.src[q];
    float* d = pp.dst[q];
    for (int i = gid; i < n; i += gsz)
      d[i] = isf ? ((const float*)s)[i] : __bfloat162float(((const bf16*)s)[i]);
  }
}

// ---------------- K0c: bf16 weight tables (LN-folded) + bias6 ----------------
__global__ __launch_bounds__(256) void kw_convert(const float* pf, const int* rpi,
                                                  bf16* wqkvF, bf16* wproj,
                                                  bf16* wpw, bf16* wpo, float* bias6){
  const int i = blockIdx.x*256 + threadIdx.x;
  if (i < 110592){
    const int c = i % 192;
    wqkvF[i] = __float2bfloat16(pf[P_QKVW + i] * pf[P_NORMW + c]);
  } else if (i < 147456)  wproj[i-110592] = __float2bfloat16(pf[P_PROJW + (i-110592)]);
  else if (i < 151552)    wpw[i-147456]   = __float2bfloat16(pf[P_AUXPW + (i-147456)]);
  else if (i < 155648)    wpo[i-151552]   = __float2bfloat16(pf[P_PO + (i-151552)]);
  else if (i < 180224){
    const int j = i - 155648;
    const int hh = j >> 12, nm = j & 4095;
    bias6[j] = pf[P_RPB + rpi[nm]*6 + hh];
  }
}

// ---------------- K0d: S1/S2 rank-1 LN correction (16-lane groups) ----------------
__global__ __launch_bounds__(256) void k0d_s12(const float* pf, float* s12){
  const int o = blockIdx.x*16 + (threadIdx.x >> 4);
  const int lane = threadIdx.x & 15;
  if (o >= 576) return;
  float s1 = 0.f, s2 = 0.f;
  for (int c = lane; c < 192; c += 16){
    const float w = pf[P_QKVW + o*192 + c];
    s1 += w * pf[P_NORMW + c];
    s2 += w * pf[P_NORMB + c];
  }
  s1 += __shfl_xor(s1,1,16); s1 += __shfl_xor(s1,2,16);
  s1 += __shfl_xor(s1,4,16); s1 += __shfl_xor(s1,8,16);
  s2 += __shfl_xor(s2,1,16); s2 += __shfl_xor(s2,2,16);
  s2 += __shfl_xor(s2,4,16); s2 += __shfl_xor(s2,8,16);
  if (lane == 0){
    s12[o] = s1;
    s12[576 + o] = s2 + pf[P_QKVB + o];
  }
}

// ---------------- K1f: single-pass DWT -> ll(bf16) + hraw + tstat ----------------
template<bool ISF>
__device__ void k1f_body(const void* xv, bf16* llb, bf16* hraw, float2* tstat){
  const int wid = blockIdx.x;
  const int b  = wid >> 10;
  const int wh = (wid >> 5) & 31;
  const int ww = wid & 31;
  const int tid = threadIdx.x;
  const int tk = tid >> 2, l4 = tid & 3;
  const int wi = tk >> 3, wj = tk & 7;
  const int h2 = (wh*8 + wi + 4) & 255;
  const int w2 = (ww*8 + wj + 4) & 255;
  const long pixbase = ((long)(2*h2) << 9) + 2*w2;
  const long llpix = ((long)h2 << 8) + w2;
  float raw0[16], raw1[16], raw2[16];
  float sum = 0.f, sumsq = 0.f;
#pragma unroll
  for (int cc = 0; cc < 16; ++cc){
    const int c = l4*16 + cc;
    const long base = ((long)(b*64 + c) << 18) + pixbase;
    const float2 t0 = LD2<ISF>(xv, base);        // a, cr
    const float2 t1 = LD2<ISF>(xv, base + 512);  // bb, dd
    const float a = t0.x, cr = t0.y, bb = t1.x, dd = t1.y;
    llb[((long)(b*64 + c) << 16) + llpix] = __float2bfloat16(0.5f*(a + bb + cr + dd));
    const float h0 = 0.5f*(-a - bb + cr + dd);
    const float h1 = 0.5f*(-a + bb - cr + dd);
    const float hh = 0.5f*( a - bb - cr + dd);
    raw0[cc] = h0; raw1[cc] = h1; raw2[cc] = hh;
    sum += h0 + h1 + hh;
    sumsq += h0*h0 + h1*h1 + hh*hh;
  }
  const long hb = ((long)wid*64 + tk)*192 + l4*16;
  *(uint4*)(hraw + hb)       = pk8(raw0);
  *(uint4*)(hraw + hb + 8)   = pk8(raw0 + 8);
  *(uint4*)(hraw + hb + 64)  = pk8(raw1);
  *(uint4*)(hraw + hb + 72)  = pk8(raw1 + 8);
  *(uint4*)(hraw + hb + 128) = pk8(raw2);
  *(uint4*)(hraw + hb + 136) = pk8(raw2 + 8);
  sum   += __shfl_xor(sum,1,4);   sum   += __shfl_xor(sum,2,4);
  sumsq += __shfl_xor(sumsq,1,4); sumsq += __shfl_xor(sumsq,2,4);
  if (l4 == 0){
    const float mean = sum * (1.f/192.f);
    float var = sumsq * (1.f/192.f) - mean*mean;
    var = fmaxf(var, 0.f);
    const float rstd = rsqrtf(var + 1e-6f);
    float2 st; st.x = rstd; st.y = mean * rstd;
    tstat[wid*64 + tk] = st;
  }
}
__global__ __launch_bounds__(256,4) void k1f_dwt(const void* xv, bf16* llb, bf16* hraw,
                                                 float2* tstat, const int* flag){
  if (*flag) k1f_body<true>(xv, llb, hraw, tstat);
  else       k1f_body<false>(xv, llb, hraw, tstat);
}

// ---------------- K2: gap (bf16 ll, vectorized) ----------------
__global__ __launch_bounds__(256) void k2_gap(const bf16* llb, float* gap){
  const int bc = blockIdx.x;                            // 0..127
  const uint4* p = (const uint4*)(llb + ((long)bc << 16));
  float s = 0.f;
  for (int i = threadIdx.x; i < 8192; i += 256){
    const uint4 v = p[i];
    s += __uint_as_float(v.x << 16) + __uint_as_float(v.x & 0xffff0000u);
    s += __uint_as_float(v.y << 16) + __uint_as_float(v.y & 0xffff0000u);
    s += __uint_as_float(v.z << 16) + __uint_as_float(v.z & 0xffff0000u);
    s += __uint_as_float(v.w << 16) + __uint_as_float(v.w & 0xffff0000u);
  }
  __shared__ float red[256];
  red[threadIdx.x] = s; __syncthreads();
  for (int st = 128; st > 0; st >>= 1){
    if (threadIdx.x < st) red[threadIdx.x] += red[threadIdx.x + st];
    __syncthreads();
  }
  if (threadIdx.x == 0) gap[bc] = red[0] * (1.f / 65536.f);
}

// ---------------- K3: cross MLP ----------------
__global__ __launch_bounds__(256) void k3_cross(const float* pf, const float* gap,
                                                float* amul, float* cval){
  __shared__ float t1[B2][48];
  __shared__ float g[B2][64];
  const int tid = threadIdx.x;
  if (tid < 128) g[tid >> 6][tid & 63] = gap[tid];
  __syncthreads();
  if (tid < 96){
    const int b = tid / 48, j = tid % 48;
    float s = 0.f;
    const float* w = pf + P_CG1 + j * 64;
    for (int c = 0; c < 64; ++c) s += w[c] * g[b][c];
    t1[b][j] = gelu_f(s);
  }
  __syncthreads();
  const float gm = pf[P_GM], gc = pf[P_GC];
  for (int o = tid; o < B2 * C3; o += 256){
    const int b = o / C3, ch = o % C3;
    float s = 0.f;
    const float* w = pf + P_CG2 + ch * 48;
    for (int j = 0; j < 48; ++j) s += w[j] * t1[b][j];
    const float cr = 1.f / (1.f + expf(-s));
    const float c = gc * (cr - 0.5f) * 2.f;
    cval[o] = c;
    amul[o] = gm * (1.f + c);
  }
}

// ---------------- K6f: fused dwconv3+gelu + 1x1 MFMA -> dllw (window layout) ----------------
__global__ __launch_bounds__(256,4) void k6f_aux(const bf16* llb, const float* pf,
                                                 const bf16* wpw, bf16* dllw){
  __shared__ __align__(16) bf16 t[64*72];
  const int wid = blockIdx.x;
  const int b  = wid >> 10;
  const int wh = (wid >> 5) & 31;
  const int ww = wid & 31;
  const int tid = threadIdx.x;
  const int tok = tid & 63, cgrp = tid >> 6;
  const int wi = tok >> 3, wj = tok & 7;
  const int h2 = (wh*8 + wi + 4) & 255;
  const int w2 = (ww*8 + wj + 4) & 255;
#pragma unroll
  for (int cc = 0; cc < 16; ++cc){
    const int c = cgrp*16 + cc;
    const float* wk = pf + P_AUXDW + c*9;
    const long plane = (long)(b*64 + c) << 16;
    float s = 0.f;
#pragma unroll
    for (int ky = 0; ky < 3; ++ky){
      const int y = h2 + ky - 1;
      if (y < 0 || y > 255) continue;
#pragma unroll
      for (int kx = 0; kx < 3; ++kx){
        const int xx = w2 + kx - 1;
        if (xx < 0 || xx > 255) continue;
        s += wk[ky*3 + kx] * __bfloat162float(llb[plane + ((long)y << 8) + xx]);
      }
    }
    t[tok*72 + c] = __float2bfloat16(gelu_f(s));
  }
  __syncthreads();
  const int wv = tid >> 6, l = tid & 63, lr = l & 15, lg = l >> 4;
  const f4v fz = {0.f,0.f,0.f,0.f};
  f4v acc[4];
#pragma unroll
  for (int nt = 0; nt < 4; ++nt) acc[nt] = fz;
#pragma unroll
  for (int ks = 0; ks < 2; ++ks){
    const s8v a = *(const s8v*)(t + (wv*16+lr)*72 + ks*32 + lg*8);
#pragma unroll
    for (int nt = 0; nt < 4; ++nt){
      const s8v bfr = *(const s8v*)(wpw + (nt*16+lr)*64 + ks*32 + lg*8);
      acc[nt] = MFMA16(a, bfr, acc[nt]);
    }
  }
  const float ga = pf[P_GA];
#pragma unroll
  for (int nt = 0; nt < 4; ++nt)
#pragma unroll
    for (int i = 0; i < 4; ++i){
      const int row = wv*16 + lg*4 + i;
      dllw[((long)wid*64 + row)*64 + nt*16 + lr] = __float2bfloat16(ga * acc[nt][i]);
    }
}

// ---------------- K4: MFMA window attention, 3 blocks/window (head pairs) ----------------
// LDS (54272 B -> 3 blocks/CU):
//  rawt [64][200] @0 (25600)
//  region rp=(wv>>1) @25600 + rp*14336:
//    bq [64][40] @+0, bk [64][40] @+5120, vtb swizzled [32][64] @+10240 (4096)
//    bp [64][72] overlays bq/bk (@+0, 9216)
__global__ __launch_bounds__(256,3) void k4_attn(const bf16* hraw, const float2* tstat,
                                                 const bf16* wqkvF, const float* s12,
                                                 const float* bias6, bf16* wout){
  __shared__ __align__(16) char sm[54272];
  bf16* rawt = (bf16*)sm;
  const int g = blockIdx.x;
  const int xcd = g & 7, slot = g >> 3;
  const int wid = (slot/3)*8 + xcd;     // 3 blocks of a window share an XCD
  const int hp  = slot - (slot/3)*3;
  const int tid = threadIdx.x;

  {
    const uint4* hsrc = (const uint4*)(hraw + (long)wid * 12288);
    for (int i2 = tid; i2 < 1536; i2 += 256)
      *(uint4*)(rawt + (i2/24)*200 + (i2%24)*8) = hsrc[i2];
  }
  __syncthreads();

  const int wv = tid >> 6, l = tid & 63, lr = l & 15, lg = l >> 4;
  const int h  = hp*2 + (wv >> 1);      // head
  const int mh = wv & 1, mt0 = mh*2;    // M-half
  char* reg = sm + 25600 + (wv>>1)*14336;
  bf16* bq  = (bf16*)reg;
  bf16* bk  = (bf16*)(reg + 5120);
  char* vtb = reg + 10240;
  bf16* bp  = (bf16*)reg;
  const f4v fz = {0.f,0.f,0.f,0.f};
  const float scale = 0.17677669529663687f;

  // per-row LN stats for this wave's 8 rows
  float2 st8[2][4];
#pragma unroll
  for (int mt = 0; mt < 2; ++mt)
#pragma unroll
    for (int i = 0; i < 4; ++i)
      st8[mt][i] = tstat[wid*64 + (mt0+mt)*16 + lg*4 + i];

  // ---- qkv GEMM: rows mh*32..+31, cols = head h x {q,k,v} ----
  f4v acc[3][2][2];
#pragma unroll
  for (int p = 0; p < 3; ++p)
#pragma unroll
    for (int nn = 0; nn < 2; ++nn){ acc[p][nn][0] = fz; acc[p][nn][1] = fz; }
#pragma unroll
  for (int ks = 0; ks < 6; ++ks){
    const int k0 = ks*32;
    const s8v a0 = *(const s8v*)(rawt + (mt0*16+lr)*200 + k0 + lg*8);
    const s8v a1 = *(const s8v*)(rawt + ((mt0+1)*16+lr)*200 + k0 + lg*8);
#pragma unroll
    for (int p = 0; p < 3; ++p)
#pragma unroll
      for (int nn = 0; nn < 2; ++nn){
        const int ocol = p*192 + h*32 + nn*16 + lr;
        const s8v bfr = *(const s8v*)(wqkvF + ocol*192 + k0 + lg*8);
        acc[p][nn][0] = MFMA16(a0, bfr, acc[p][nn][0]);
        acc[p][nn][1] = MFMA16(a1, bfr, acc[p][nn][1]);
      }
  }
#pragma unroll
  for (int p = 0; p < 3; ++p)
#pragma unroll
    for (int nn = 0; nn < 2; ++nn){
      const int ocol = p*192 + h*32 + nn*16 + lr;
      const float s1v = s12[ocol], s2v = s12[576 + ocol];
#pragma unroll
      for (int mt = 0; mt < 2; ++mt)
#pragma unroll
        for (int i = 0; i < 4; ++i){
          const int row = (mt0+mt)*16 + lg*4 + i;
          const float v = st8[mt][i].x*acc[p][nn][mt][i] - st8[mt][i].y*s1v + s2v;
          if (p == 0)      bq[row*40 + nn*16 + lr] = __float2bfloat16(v*scale);
          else if (p == 1) bk[row*40 + nn*16 + lr] = __float2bfloat16(v);
          else {
            const int d = nn*16 + lr;
            *(bf16*)(vtb + ((d*128 + row*2) ^ ((d&7)<<4))) = __float2bfloat16(v);
          }
        }
    }
  __syncthreads();

  // ---- S = q~ k^T + bias6; softmax in regs ----
  f4v sacc[2][4];
#pragma unroll
  for (int mt = 0; mt < 2; ++mt)
#pragma unroll
    for (int nt = 0; nt < 4; ++nt) sacc[mt][nt] = fz;
  {
    const s8v a0 = *(const s8v*)(bq + (mt0*16+lr)*40 + lg*8);
    const s8v a1 = *(const s8v*)(bq + ((mt0+1)*16+lr)*40 + lg*8);
#pragma unroll
    for (int nt = 0; nt < 4; ++nt){
      const s8v bfr = *(const s8v*)(bk + (nt*16+lr)*40 + lg*8);
      sacc[0][nt] = MFMA16(a0, bfr, sacc[0][nt]);
      sacc[1][nt] = MFMA16(a1, bfr, sacc[1][nt]);
    }
  }
  float pvv[2][4][4];
#pragma unroll
  for (int mt = 0; mt < 2; ++mt)
#pragma unroll
    for (int i = 0; i < 4; ++i){
      const int row = (mt0+mt)*16 + lg*4 + i;
      float v[4]; float mx = -1e30f;
#pragma unroll
      for (int nt = 0; nt < 4; ++nt){
        v[nt] = sacc[mt][nt][i] + bias6[h*4096 + row*64 + nt*16 + lr];
        mx = fmaxf(mx, v[nt]);
      }
      mx = fmaxf(mx, __shfl_xor(mx, 1, 16));
      mx = fmaxf(mx, __shfl_xor(mx, 2, 16));
      mx = fmaxf(mx, __shfl_xor(mx, 4, 16));
      mx = fmaxf(mx, __shfl_xor(mx, 8, 16));
      float s = 0.f;
#pragma unroll
      for (int nt = 0; nt < 4; ++nt){ v[nt] = __expf(v[nt]-mx); s += v[nt]; }
      s += __shfl_xor(s, 1, 16);
      s += __shfl_xor(s, 2, 16);
      s += __shfl_xor(s, 4, 16);
      s += __shfl_xor(s, 8, 16);
      const float inv = 1.f/s;
#pragma unroll
      for (int nt = 0; nt < 4; ++nt) pvv[mt][i][nt] = v[nt]*inv;
    }
  __syncthreads();   // bq/bk reads done before P overlays

  // ---- P write + PV ----
#pragma unroll
  for (int mt = 0; mt < 2; ++mt)
#pragma unroll
    for (int i = 0; i < 4; ++i){
      const int row = (mt0+mt)*16 + lg*4 + i;
#pragma unroll
      for (int nt = 0; nt < 4; ++nt)
        bp[row*72 + nt*16 + lr] = __float2bfloat16(pvv[mt][i][nt]);
    }
  f4v oacc[2][2];
#pragma unroll
  for (int mt = 0; mt < 2; ++mt){ oacc[mt][0] = fz; oacc[mt][1] = fz; }
#pragma unroll
  for (int ks2 = 0; ks2 < 2; ++ks2){
    const s8v a0 = *(const s8v*)(bp + (mt0*16+lr)*72 + ks2*32 + lg*8);
    const s8v a1 = *(const s8v*)(bp + ((mt0+1)*16+lr)*72 + ks2*32 + lg*8);
#pragma unroll
    for (int nn = 0; nn < 2; ++nn){
      const int d = nn*16 + lr;
      const s8v bfr = *(const s8v*)(vtb + ((d*128 + (ks2*32+lg*8)*2) ^ ((d&7)<<4)));
      oacc[0][nn] = MFMA16(a0, bfr, oacc[0][nn]);
      oacc[1][nn] = MFMA16(a1, bfr, oacc[1][nn]);
    }
  }
#pragma unroll
  for (int mt = 0; mt < 2; ++mt)
#pragma unroll
    for (int nn = 0; nn < 2; ++nn)
#pragma unroll
      for (int i = 0; i < 4; ++i){
        const int row = (mt0+mt)*16 + lg*4 + i;
        wout[((long)wid*64 + row)*192 + h*32 + nn*16 + lr] = __float2bfloat16(oacc[mt][nn][i]);
      }
}

// ---------------- K5: proj MFMA + combine -> dval in-place (window layout) ----------------
__global__ __launch_bounds__(256,3) void k5_proj(bf16* wout, const bf16* hraw,
                                                 const bf16* wproj, const float* pf,
                                                 const float* amul, const float* cval){
  __shared__ __align__(16) bf16 bufA[64*200];   // wout tile
  __shared__ __align__(16) bf16 bufC[64*200];   // hraw tile
  const int wid = blockIdx.x;
  const int b  = wid >> 10;
  const int tid = threadIdx.x;

  {
    const uint4* hsrc = (const uint4*)(hraw + (long)wid * 12288);
    const uint4* wsrc = (const uint4*)(wout + (long)wid * 12288);
    for (int i2 = tid; i2 < 1536; i2 += 256){
      const int t = i2/24, c8 = (i2%24)*8;
      *(uint4*)(bufC + t*200 + c8) = hsrc[i2];
      *(uint4*)(bufA + t*200 + c8) = wsrc[i2];
    }
  }
  __syncthreads();

  const int wv = tid >> 6, l = tid & 63, lr = l & 15, lg = l >> 4;
  const f4v fz = {0.f,0.f,0.f,0.f};

  f4v acc[3][4];
#pragma unroll
  for (int nt = 0; nt < 3; ++nt)
#pragma unroll
    for (int mt = 0; mt < 4; ++mt) acc[nt][mt] = fz;
#pragma unroll
  for (int ks = 0; ks < 6; ++ks){
    const int k0 = ks*32;
    s8v a[4];
#pragma unroll
    for (int mt = 0; mt < 4; ++mt)
      a[mt] = *(const s8v*)(bufA + (mt*16+lr)*200 + k0 + lg*8);
#pragma unroll
    for (int nt = 0; nt < 3; ++nt){
      const int ocol = (wv*3+nt)*16 + lr;
      const s8v bfr = *(const s8v*)(wproj + ocol*192 + k0 + lg*8);
#pragma unroll
      for (int mt = 0; mt < 4; ++mt) acc[nt][mt] = MFMA16(a[mt], bfr, acc[nt][mt]);
    }
  }
#pragma unroll
  for (int nt = 0; nt < 3; ++nt){
    const int col = (wv*3+nt)*16 + lr;
    const int bc = b*192 + col;
    const float am = amul[bc], cv = cval[bc], pb = pf[P_PROJB + col];
#pragma unroll
    for (int mt = 0; mt < 4; ++mt)
#pragma unroll
      for (int i = 0; i < 4; ++i){
        const int row = mt*16 + lg*4 + i;
        const float hv = __bfloat162float(bufC[row*200 + col]);
        wout[(long)wid*12288 + row*192 + col] =
          __float2bfloat16(am*(acc[nt][mt][i] + pb) + cv*hv);
      }
  }
}

// ---------------- K7: gather + IWT + out-conv MFMA + coalesced store ----------------
template<bool ISF>
__device__ void k7_body(const bf16* dvalw, const bf16* dllw, const bf16* wpo,
                        void* out, char* yp){
  const int blk = blockIdx.x;
  const int b = blk >> 10, hh = (blk >> 1) & 511, half = blk & 1;
  const int h2 = hh >> 1, posH = hh & 1;
  const int th = (h2 + 252) & 255;
  const int wh = th >> 3, wi = th & 7;
  const int tid = threadIdx.x;
  const int j = tid & 7;
#pragma unroll
  for (int pass = 0; pass < 8; ++pass){
    const int p = pass*32 + (tid >> 3);
    const int ww2 = half*256 + p;
    const int w2 = ww2 >> 1, posW = ww2 & 1;
    const int tw = (w2 + 252) & 255;
    const int ww = tw >> 3, wj = tw & 7;
    const int wid = b*1024 + wh*32 + ww;
    const int tok = wi*8 + wj;
    const long dvb = ((long)wid*64 + tok)*192 + j*8;
    const s8v hl8 = *(const s8v*)(dvalw + dvb);
    const s8v lh8 = *(const s8v*)(dvalw + dvb + 64);
    const s8v hh8 = *(const s8v*)(dvalw + dvb + 128);
    const s8v dl8 = *(const s8v*)(dllw + ((long)wid*64 + tok)*64 + j*8);
    const float s1 = posW ? 0.5f : -0.5f;
    const float s2 = posH ? 0.5f : -0.5f;
    const float s3 = posW == posH ? 0.5f : -0.5f;
    float e[8];
#pragma unroll
    for (int q = 0; q < 8; ++q)
      e[q] = 0.5f*bfu((unsigned short)dl8[q]) + s1*bfu((unsigned short)hl8[q])
           + s2*bfu((unsigned short)lh8[q]) + s3*bfu((unsigned short)hh8[q]);
    *(uint4*)(yp + ((p*128 + j*16) ^ ((p&7)<<4))) = pk8(e);
  }
  __syncthreads();
  const int wv = tid >> 6, l = tid & 63, lr = l & 15, lg = l >> 4;
  const f4v fz = {0.f,0.f,0.f,0.f};
  f4v acc[4][4];
#pragma unroll
  for (int mt = 0; mt < 4; ++mt)
#pragma unroll
    for (int nt = 0; nt < 4; ++nt) acc[mt][nt] = fz;
#pragma unroll
  for (int ks = 0; ks < 2; ++ks){
    const int k0 = ks*32;
    s8v a[4];
#pragma unroll
    for (int mt = 0; mt < 4; ++mt)
      a[mt] = *(const s8v*)(wpo + (mt*16+lr)*64 + k0 + lg*8);
#pragma unroll
    for (int nt = 0; nt < 4; ++nt){
      const int prow = wv*64 + nt*16 + lr;
      const s8v bfr = *(const s8v*)(yp + ((prow*128 + (k0+lg*8)*2) ^ ((prow&7)<<4)));
#pragma unroll
      for (int mt = 0; mt < 4; ++mt) acc[mt][nt] = MFMA16(a[mt], bfr, acc[mt][nt]);
    }
  }
  const int px0 = half*256 + wv*64;
#pragma unroll
  for (int mt = 0; mt < 4; ++mt)
#pragma unroll
    for (int nt = 0; nt < 4; ++nt)
#pragma unroll
      for (int i = 0; i < 4; ++i){
        const int c = mt*16 + lg*4 + i;
        const long ob = ((long)(b*64 + c)*512 + hh)*512 + px0 + nt*16 + lr;
        ST<ISF>(out, ob, acc[mt][nt][i]);
      }
}
__global__ __launch_bounds__(256,4) void k7_out(const bf16* dvalw, const bf16* dllw,
                                                const bf16* wpo, void* out, const int* flag){
  __shared__ __align__(16) char yp[32768];
  if (*flag) k7_body<true>(dvalw, dllw, wpo, out, yp);
  else       k7_body<false>(dvalw, dllw, wpo, out, yp);
}

// ---------------- launcher ----------------
extern "C" void kernel_launch(void* const* d_in, const int* in_sizes, int n_in,
                              void* d_out, int out_size, void* d_ws, size_t ws_size,
                              hipStream_t stream){
  char* ws = (char*)d_ws;
  int*   flag = (int*)(ws + WS_FLAG);
  float* pf   = (float*)(ws + WS_PARAMS);
  float* gap  = (float*)(ws + WS_GAP);
  float* amul = (float*)(ws + WS_AMUL);
  float* cval = (float*)(ws + WS_CVAL);
  float2* tstat=(float2*)(ws + WS_TSTAT);
  bf16*  llb  = (bf16*)(ws + WS_LL);
  bf16*  dllw = (bf16*)(ws + WS_DLLW);
  bf16*  wout = (bf16*)(ws + WS_WOUT);
  bf16*  hraw = (bf16*)(ws + WS_HRAW);
  bf16*  wqkvF= (bf16*)(ws + WS_WQKV);
  bf16*  wproj= (bf16*)(ws + WS_WPROJ);
  bf16*  wpw  = (bf16*)(ws + WS_WPW);
  bf16*  wpo  = (bf16*)(ws + WS_WPO);
  float* s12  = (float*)(ws + WS_S12);
  float* bias6= (float*)(ws + WS_BIAS6);
  const int* rpi = (const int*)d_in[16];

  detect_kernel<<<1, 256, 0, stream>>>(d_in[0], flag);

  PP pp;
  const int pidx[15] = {1,2,3,4,5,6,7,8,9,10,11,12,13,14,15};
  const int poff[15] = {P_NORMW,P_NORMB,P_QKVW,P_QKVB,P_PROJW,P_PROJB,P_RPB,
                        P_AUXDW,P_AUXPW,P_CG1,P_CG2,P_PO,P_GM,P_GA,P_GC};
  for (int q = 0; q < 15; q++){
    pp.src[q] = d_in[pidx[q]];
    pp.dst[q] = pf + poff[q];
    pp.n[q]   = in_sizes[pidx[q]];
  }
  convert_params<<<128, 256, 0, stream>>>(pp, flag);
  kw_convert<<<704, 256, 0, stream>>>(pf, rpi, wqkvF, wproj, wpw, wpo, bias6);
  k0d_s12  <<<36,  256, 0, stream>>>(pf, s12);

  k1f_dwt<<<NWIN, 256, 0, stream>>>(d_in[0], llb, hraw, tstat, flag);
  k2_gap <<<128,  256, 0, stream>>>(llb, gap);
  k3_cross<<<1,   256, 0, stream>>>(pf, gap, amul, cval);
  k6f_aux<<<NWIN, 256, 0, stream>>>(llb, pf, wpw, dllw);
  k4_attn<<<NWIN*3, 256, 0, stream>>>(hraw, tstat, wqkvF, s12, bias6, wout);
  k5_proj<<<NWIN, 256, 0, stream>>>(wout, hraw, wproj, pf, amul, cval);
  k7_out <<<2048, 256, 0, stream>>>(wout, dllw, wpo, d_out, flag);
}